// Round 6
// baseline (695.440 us; speedup 1.0000x reference)
//
#include <hip/hip_runtime.h>
#include <math.h>

#define NGRAPH 64
#define NE 524288      // total edges
#define EPG 8192       // edges per graph
#define TSZ 2560       // 64 rows * 40 shorts per LDS tile half

typedef short s16x8 __attribute__((ext_vector_type(8)));
typedef float f32x4 __attribute__((ext_vector_type(4)));

__device__ inline unsigned short f2bf(float f) {
    unsigned int u = __float_as_uint(f);
    return (unsigned short)((u + 0x7FFFu + ((u >> 16) & 1u)) >> 16);
}
__device__ inline float bf2f(unsigned short h) {
    return __uint_as_float((unsigned int)h << 16);
}
// packed split-bf16: low16 = hi part, high16 = lo (residual) part
__device__ inline unsigned int f2pk(float v) {
    unsigned short h = f2bf(v);
    return (unsigned int)h | ((unsigned int)f2bf(v - bf2f(h)) << 16);
}

// ---------------- CSR build (L0: both directions in one launch) ---------------------------
__global__ void edge_count2(const int* __restrict__ keyA, int* __restrict__ cntA,
                            const int* __restrict__ keyB, int* __restrict__ cntB) {
    int e = blockIdx.x * 256 + threadIdx.x;
    if (e >= NE) return;
    if (blockIdx.y == 0) atomicAdd(&cntA[keyA[e]], 1);
    else                 atomicAdd(&cntB[keyB[e]], 1);
}

__device__ inline void scan_body(const int* __restrict__ counts, int* __restrict__ offs,
                                 int* __restrict__ cursor, int nPerGraph,
                                 float* __restrict__ degOut, int* s) {
    const int g = blockIdx.x, t = threadIdx.x;
    int v = (t < nPerGraph) ? counts[g * nPerGraph + t] : 0;
    s[t] = v; __syncthreads();
    for (int d = 1; d < 512; d <<= 1) {
        int u = (t >= d) ? s[t - d] : 0;
        __syncthreads();
        s[t] += u;
        __syncthreads();
    }
    if (t < nPerGraph) {
        int o = g * EPG + s[t] - v;
        offs[g * nPerGraph + t] = o;
        cursor[g * nPerGraph + t] = o;
        if (degOut) degOut[g * nPerGraph + t] = (float)v;
    }
}

__global__ __launch_bounds__(512) void scan_offsets(const int* __restrict__ counts,
        int* __restrict__ offs, int* __restrict__ cursor, int nPerGraph,
        float* __restrict__ degOut) {
    __shared__ int s[512];
    scan_body(counts, offs, cursor, nPerGraph, degOut, s);
}

__global__ __launch_bounds__(512) void scan_offsets2(
        const int* __restrict__ cA, int* __restrict__ oA, int* __restrict__ uA,
        const int* __restrict__ cB, int* __restrict__ oB, int* __restrict__ uB,
        int nPerGraph, float* __restrict__ degB) {
    __shared__ int s[512];
    if (blockIdx.y == 0) scan_body(cA, oA, uA, nPerGraph, nullptr, s);
    else                 scan_body(cB, oB, uB, nPerGraph, degB, s);
}

__global__ void edge_fill(const int* __restrict__ key, const int* __restrict__ payload,
                          const float* __restrict__ mask, int* __restrict__ cursor,
                          int* __restrict__ elist) {
    int e = blockIdx.x * 256 + threadIdx.x;
    if (e < NE && (!mask || mask[e] > 0.f)) {
        int p = atomicAdd(&cursor[key[e]], 1);
        elist[p] = payload[e];
    }
}

__global__ void edge_fill2(const int* __restrict__ kA, const int* __restrict__ pA,
                           int* __restrict__ uA, int* __restrict__ eA,
                           const int* __restrict__ kB, const int* __restrict__ pB,
                           int* __restrict__ uB, int* __restrict__ eB) {
    int e = blockIdx.x * 256 + threadIdx.x;
    if (e >= NE) return;
    if (blockIdx.y == 0) { int p = atomicAdd(&uA[kA[e]], 1); eA[p] = pA[e]; }
    else                 { int p = atomicAdd(&uB[kB[e]], 1); eB[p] = pB[e]; }
}

// ---------------- CSR gather: f32 or packed input, packed output --------------------------
__device__ inline void addpk(float4& acc, uint4 u) {
    acc.x += __uint_as_float(u.x << 16) + __uint_as_float(u.x & 0xffff0000u);
    acc.y += __uint_as_float(u.y << 16) + __uint_as_float(u.y & 0xffff0000u);
    acc.z += __uint_as_float(u.z << 16) + __uint_as_float(u.z & 0xffff0000u);
    acc.w += __uint_as_float(u.w << 16) + __uint_as_float(u.w & 0xffff0000u);
}

__global__ __launch_bounds__(256) void gather_csr(
    const float* __restrict__ xf, const unsigned int* __restrict__ xp, int Fx,
    const int* __restrict__ offs, const int* __restrict__ cnts,
    const int* __restrict__ elist,
    unsigned int* __restrict__ opk,
    int totRows, int rowsPerGraph)
{
    const int gid = (blockIdx.x * 256 + threadIdx.x) >> 5;
    const int lane = threadIdx.x & 31;
    const int csh = (Fx == 256) ? 1 : 0;
    const int rid = gid >> csh;
    const int c0 = (gid & ((1 << csh) - 1)) << 7;
    if (rid >= totRows) return;
    const int row = (rid & 63) * rowsPerGraph + (rid >> 6);
    const int beg = offs[row];
    const int n = cnts[row];
    const long long co = (long long)c0 + (lane << 2);
    float4 acc = make_float4(0.f, 0.f, 0.f, 0.f);
    int j = 0;
    if (xp) {
        for (; j + 4 <= n; j += 4) {
            const int n0 = elist[beg + j], n1 = elist[beg + j + 1];
            const int n2 = elist[beg + j + 2], n3 = elist[beg + j + 3];
            const uint4 u0 = *(const uint4*)&xp[(long long)n0 * Fx + co];
            const uint4 u1 = *(const uint4*)&xp[(long long)n1 * Fx + co];
            const uint4 u2 = *(const uint4*)&xp[(long long)n2 * Fx + co];
            const uint4 u3 = *(const uint4*)&xp[(long long)n3 * Fx + co];
            addpk(acc, u0); addpk(acc, u1); addpk(acc, u2); addpk(acc, u3);
        }
        for (; j < n; ++j)
            addpk(acc, *(const uint4*)&xp[(long long)elist[beg + j] * Fx + co]);
    } else {
        for (; j + 4 <= n; j += 4) {
            const int n0 = elist[beg + j], n1 = elist[beg + j + 1];
            const int n2 = elist[beg + j + 2], n3 = elist[beg + j + 3];
            const float4 v0 = *(const float4*)&xf[(long long)n0 * Fx + co];
            const float4 v1 = *(const float4*)&xf[(long long)n1 * Fx + co];
            const float4 v2 = *(const float4*)&xf[(long long)n2 * Fx + co];
            const float4 v3 = *(const float4*)&xf[(long long)n3 * Fx + co];
            acc.x += v0.x + v1.x + v2.x + v3.x;
            acc.y += v0.y + v1.y + v2.y + v3.y;
            acc.z += v0.z + v1.z + v2.z + v3.z;
            acc.w += v0.w + v1.w + v2.w + v3.w;
        }
        for (; j < n; ++j) {
            const float4 v = *(const float4*)&xf[(long long)elist[beg + j] * Fx + co];
            acc.x += v.x; acc.y += v.y; acc.z += v.z; acc.w += v.w;
        }
    }
    uint4 pk;
    pk.x = f2pk(acc.x); pk.y = f2pk(acc.y); pk.z = f2pk(acc.z); pk.w = f2pk(acc.w);
    *(uint4*)&opk[(long long)row * Fx + co] = pk;
}

// ---------------- all 7 weight converts in ONE launch -------------------------------------
struct WSpec {
    const float* w1; const float* w2; int K1; int K2; int Nn;
    unsigned short* oh; unsigned short* ol;
};

__global__ void wconv_all(WSpec s0, WSpec s1, WSpec s2, WSpec s3, WSpec s4, WSpec s5, WSpec s6) {
    WSpec s;
    switch (blockIdx.y) {
        case 0: s = s0; break; case 1: s = s1; break; case 2: s = s2; break;
        case 3: s = s3; break; case 4: s = s4; break; case 5: s = s5; break;
        default: s = s6; break;
    }
    int idx = blockIdx.x * 256 + threadIdx.x;
    int Kt = s.K1 + s.K2;
    if (idx >= s.Nn * Kt) return;
    int n = idx / Kt, k = idx - n * Kt;
    float v = (k < s.K1) ? s.w1[(long long)k * s.Nn + n] : s.w2[(long long)(k - s.K1) * s.Nn + n];
    unsigned short h = f2bf(v);
    s.oh[idx] = h;
    s.ol[idx] = f2bf(v - __uint_as_float((unsigned int)h << 16));
}

// ---------------- reg-staged double-buffered LDS staging ----------------------------------
// LOAD issues global loads into regs; STORE writes regs to LDS (hi at base, lo at +TSZ).

// row-major 8-dword load (A for gemm_aw); works for packed u32 or f32 planes (same stride)
__device__ inline void loadN8(const unsigned int* __restrict__ base, int ldk, int kcol,
                              int tid, uint4 (&r)[2]) {
    const int rr = tid >> 2, kq = (tid & 3) << 3;
    const unsigned int* p = base + (long long)rr * ldk + kcol + kq;
    r[0] = *(const uint4*)p;
    r[1] = *(const uint4*)(p + 4);
}
__device__ inline void storeN8(short* lds, int tid, uint4 r0, uint4 r1, int pk) {
    const int rr = tid >> 2, kq = (tid & 3) << 3;
    if (!pk) {   // raw f32 bits -> packed per element (identical math to old stageN_split)
        r0.x = f2pk(__uint_as_float(r0.x)); r0.y = f2pk(__uint_as_float(r0.y));
        r0.z = f2pk(__uint_as_float(r0.z)); r0.w = f2pk(__uint_as_float(r0.w));
        r1.x = f2pk(__uint_as_float(r1.x)); r1.y = f2pk(__uint_as_float(r1.y));
        r1.z = f2pk(__uint_as_float(r1.z)); r1.w = f2pk(__uint_as_float(r1.w));
    }
    uint4 hw, lw;
    hw.x = (r0.x & 0xffffu) | (r0.y << 16);
    hw.y = (r0.z & 0xffffu) | (r0.w << 16);
    hw.z = (r1.x & 0xffffu) | (r1.y << 16);
    hw.w = (r1.z & 0xffffu) | (r1.w << 16);
    lw.x = (r0.x >> 16) | (r0.y & 0xffff0000u);
    lw.y = (r0.z >> 16) | (r0.w & 0xffff0000u);
    lw.z = (r1.x >> 16) | (r1.y & 0xffff0000u);
    lw.w = (r1.z >> 16) | (r1.w & 0xffff0000u);
    *(uint4*)(lds + rr * 40 + kq) = hw;
    *(uint4*)(lds + TSZ + rr * 40 + kq) = lw;
}

// weight planes (pre-split u16 hi/lo): pure 16B vector copies
__device__ inline void loadW8(const unsigned short* __restrict__ wh,
                              const unsigned short* __restrict__ wl, int ldk,
                              int n0, int k0, int tid, uint4 (&r)[2]) {
    const int rr = tid >> 2, kq = (tid & 3) << 3;
    r[0] = *(const uint4*)(wh + (long long)(n0 + rr) * ldk + k0 + kq);
    r[1] = *(const uint4*)(wl + (long long)(n0 + rr) * ldk + k0 + kq);
}
__device__ inline void storeW8(short* lds, int tid, const uint4 (&r)[2]) {
    const int rr = tid >> 2, kq = (tid & 3) << 3;
    *(uint4*)(lds + rr * 40 + kq) = r[0];
    *(uint4*)(lds + TSZ + rr * 40 + kq) = r[1];
}

// transposed load from PACKED plane: 8 scattered u32 loads
__device__ inline void loadT8(const unsigned int* __restrict__ P, int ldm, int k0, int m0,
                              int tid, unsigned int (&r)[8]) {
    const int kp = tid >> 4, mc = tid & 15;
    const int k = kp << 1;
    const unsigned int* p0 = P + (long long)(k0 + k) * ldm + m0 + mc;
    const unsigned int* p1 = p0 + ldm;
    #pragma unroll
    for (int i = 0; i < 4; ++i) { r[i] = p0[i << 4]; r[4 + i] = p1[i << 4]; }
}
__device__ inline void storeT8(short* lds, int tid, const unsigned int (&r)[8]) {
    const int kp = tid >> 4, mc = tid & 15;
    const int k = kp << 1;
    #pragma unroll
    for (int i = 0; i < 4; ++i) {
        unsigned int e0 = r[i], e1 = r[4 + i];
        const int o = (mc + (i << 4)) * 40 + k;
        *(unsigned int*)(lds + o) = (e0 & 0xffffu) | (e1 << 16);
        *(unsigned int*)(lds + o + TSZ) = (e0 >> 16) | (e1 & 0xffff0000u);
    }
}
__device__ inline void storeT8_hi(short* lds, int tid, const unsigned int (&r)[8]) {
    const int kp = tid >> 4, mc = tid & 15;
    const int k = kp << 1;
    #pragma unroll
    for (int i = 0; i < 4; ++i)
        *(unsigned int*)(lds + (mc + (i << 4)) * 40 + k) =
            (r[i] & 0xffffu) | (r[4 + i] << 16);
}

__device__ inline void mfma_split(const short* As, const short* Bs, int wm, int wn,
                                  int l15, int quad, f32x4 (&acc)[2][2]) {
    const int ko = quad << 3;
    s16x8 ah[2], al[2], bh[2], bl[2];
    #pragma unroll
    for (int i = 0; i < 2; ++i) {
        const int ra = (wm + (i << 4) + l15) * 40 + ko;
        const int rb = (wn + (i << 4) + l15) * 40 + ko;
        ah[i] = *(const s16x8*)&As[ra];
        al[i] = *(const s16x8*)&As[TSZ + ra];
        bh[i] = *(const s16x8*)&Bs[rb];
        bl[i] = *(const s16x8*)&Bs[TSZ + rb];
    }
    #pragma unroll
    for (int mi = 0; mi < 2; ++mi)
    #pragma unroll
    for (int ni = 0; ni < 2; ++ni) {
        f32x4 c = acc[mi][ni];
        c = __builtin_amdgcn_mfma_f32_16x16x32_bf16(ah[mi], bh[ni], c, 0, 0, 0);
        c = __builtin_amdgcn_mfma_f32_16x16x32_bf16(ah[mi], bl[ni], c, 0, 0, 0);
        c = __builtin_amdgcn_mfma_f32_16x16x32_bf16(al[mi], bh[ni], c, 0, 0, 0);
        acc[mi][ni] = c;
    }
}

__device__ inline void mfma_hi(const short* As, const short* Bs, int wm, int wn,
                               int l15, int quad, f32x4 (&acc)[2][2]) {
    const int ko = quad << 3;
    s16x8 ah[2], bh[2];
    #pragma unroll
    for (int i = 0; i < 2; ++i) {
        ah[i] = *(const s16x8*)&As[(wm + (i << 4) + l15) * 40 + ko];
        bh[i] = *(const s16x8*)&Bs[(wn + (i << 4) + l15) * 40 + ko];
    }
    #pragma unroll
    for (int mi = 0; mi < 2; ++mi)
    #pragma unroll
    for (int ni = 0; ni < 2; ++ni)
        acc[mi][ni] = __builtin_amdgcn_mfma_f32_16x16x32_bf16(ah[mi], bh[ni], acc[mi][ni], 0, 0, 0);
}

// ---------------- G1: flat C = op([A1|A2] @ Wt^T + bias), reg double-buffered -------------
__global__ __launch_bounds__(256) void gemm_aw(
    const unsigned int* __restrict__ A1p, const float* __restrict__ A1f, int K1,
    const unsigned int* __restrict__ A2p, const float* __restrict__ A2f, int K2,
    const unsigned short* __restrict__ Wh, const unsigned short* __restrict__ Wl,
    const float* __restrict__ bias, float* __restrict__ C,
    unsigned int* __restrict__ Cpk,
    int Nn, int doRelu)
{
    __shared__ short As[2 * TSZ], Bs[2 * TSZ];
    const int m0 = blockIdx.y << 6, n0 = blockIdx.x << 6;
    const int tid = threadIdx.x, lane = tid & 63, wv = tid >> 6;
    const int l15 = lane & 15, quad = lane >> 4;
    const int wm = (wv & 1) << 5, wn = (wv >> 1) << 5;
    f32x4 acc[2][2] = {};
    const int Kt = K1 + K2;
    const unsigned int* base1 = A1p ? A1p + (long long)m0 * K1
                                    : (const unsigned int*)(A1f + (long long)m0 * K1);
    const unsigned int* base2 = A2p ? A2p + (long long)m0 * K2
                                    : (const unsigned int*)(A2f + (long long)m0 * K2);
    const int pk1 = A1p != nullptr, pk2 = A2p != nullptr;
    uint4 ra[2], rb[2];
    int curPk = (0 < K1) ? pk1 : pk2;
    loadN8(base1, K1, 0, tid, ra);       // k0=0 always in A1 range (K1>0 in all call sites)
    loadW8(Wh, Wl, Kt, n0, 0, tid, rb);
    for (int k0 = 0; k0 < Kt; k0 += 32) {
        storeN8(As, tid, ra[0], ra[1], curPk);
        storeW8(Bs, tid, rb);
        __syncthreads();
        const int kn = k0 + 32;
        if (kn < Kt) {
            if (kn < K1) { loadN8(base1, K1, kn, tid, ra);      curPk = pk1; }
            else         { loadN8(base2, K2, kn - K1, tid, ra); curPk = pk2; }
            loadW8(Wh, Wl, Kt, n0, kn, tid, rb);
        }
        mfma_split(As, Bs, wm, wn, l15, quad, acc);
        __syncthreads();
    }
    #pragma unroll
    for (int mi = 0; mi < 2; ++mi)
    #pragma unroll
    for (int ni = 0; ni < 2; ++ni) {
        const int col = n0 + wn + (ni << 4) + l15;
        const float bv = bias ? bias[col] : 0.f;
        #pragma unroll
        for (int r = 0; r < 4; ++r) {
            const int row = m0 + wm + (mi << 4) + (quad << 2) + r;
            float v = acc[mi][ni][r] + bv;
            if (doRelu) v = fmaxf(v, 0.f);
            if (C)   C[(long long)row * Nn + col] = v;
            if (Cpk) Cpk[(long long)row * Nn + col] = f2pk(v);
        }
    }
}

// ---------------- G2: batched C = A^T B, TWO jobs per launch, reg double-buffered ---------
struct TTSet {
    const unsigned int* Bp;
    float* C; unsigned int* Cpk; float* fro;
    int Nn; int dual;
    long long sB, sC;
};

__global__ __launch_bounds__(256) void gemm_tt(
    const unsigned int* __restrict__ Ap, int Kd, int Mm, long long sA,
    int zsplit, TTSet t0, TTSet t1)
{
    __shared__ short As[2 * TSZ], Bs[2 * TSZ], A2s[TSZ];
    __shared__ float redf[4];
    const int z = blockIdx.x;
    int nz = blockIdx.z;
    const TTSet tt = (nz < zsplit) ? t0 : t1;
    if (blockIdx.z >= zsplit) nz -= zsplit;
    const unsigned int* Apz = Ap + (long long)z * sA;
    const unsigned int* Bpz = tt.Bp + (long long)z * tt.sB;
    const int m0 = blockIdx.y << 6, n0 = nz << 6;
    const int tid = threadIdx.x, lane = tid & 63, wv = tid >> 6;
    const int l15 = lane & 15, quad = lane >> 4;
    const int wm = (wv & 1) << 5, wn = (wv >> 1) << 5;
    const int fw = tt.dual ? ((m0 < n0) ? 2 : ((m0 == n0) ? 1 : 0)) : 0;
    f32x4 acc[2][2] = {};
    f32x4 accA[2][2] = {};
    unsigned int ra[8], rb[8], rh[8];
    loadT8(Apz, Mm, 0, m0, tid, ra);
    loadT8(Bpz, tt.Nn, 0, n0, tid, rb);
    if (fw) loadT8(Apz, Mm, 0, n0, tid, rh);
    for (int k0 = 0; k0 < Kd; k0 += 32) {
        storeT8(As, tid, ra);
        storeT8(Bs, tid, rb);
        if (fw) storeT8_hi(A2s, tid, rh);
        __syncthreads();
        const int kn = k0 + 32;
        if (kn < Kd) {
            loadT8(Apz, Mm, kn, m0, tid, ra);
            loadT8(Bpz, tt.Nn, kn, n0, tid, rb);
            if (fw) loadT8(Apz, Mm, kn, n0, tid, rh);
        }
        mfma_split(As, Bs, wm, wn, l15, quad, acc);
        if (fw) mfma_hi(As, A2s, wm, wn, l15, quad, accA);
        __syncthreads();
    }
    float* Cp = tt.C ? tt.C + (long long)z * tt.sC : nullptr;
    unsigned int* Ckp = tt.Cpk ? tt.Cpk + (long long)z * tt.sC : nullptr;
    #pragma unroll
    for (int mi = 0; mi < 2; ++mi)
    #pragma unroll
    for (int ni = 0; ni < 2; ++ni) {
        const int col = n0 + wn + (ni << 4) + l15;
        #pragma unroll
        for (int r = 0; r < 4; ++r) {
            const int row = m0 + wm + (mi << 4) + (quad << 2) + r;
            const float v = acc[mi][ni][r];
            if (Cp)  Cp[(long long)row * tt.Nn + col] = v;
            if (Ckp) Ckp[(long long)row * tt.Nn + col] = f2pk(v);
        }
    }
    if (fw) {
        float s = 0.f;
        #pragma unroll
        for (int mi = 0; mi < 2; ++mi)
        #pragma unroll
        for (int ni = 0; ni < 2; ++ni)
        #pragma unroll
        for (int r = 0; r < 4; ++r) s += accA[mi][ni][r] * accA[mi][ni][r];
        s *= (float)fw;
        for (int off = 32; off; off >>= 1) s += __shfl_xor(s, off);
        if (lane == 0) redf[wv] = s;
        __syncthreads();
        if (tid == 0) atomicAdd(&tt.fro[z], redf[0] + redf[1] + redf[2] + redf[3]);
    }
}

// ---------------- G3: batched C = A @ B; reg double-buffered; rscale epilogue -------------
__global__ __launch_bounds__(256) void gemm_nt(
    const unsigned short* __restrict__ Ah, const unsigned short* __restrict__ Al,
    const unsigned int* __restrict__ Bp,
    float* __restrict__ C, unsigned int* __restrict__ Cpk,
    const float* __restrict__ rscale, int rsn,
    int Kd, int Nn, long long sA, long long sB, long long sC)
{
    __shared__ short As[2 * TSZ], Bs[2 * TSZ];
    const int z = blockIdx.x;
    const int m0 = blockIdx.y << 6, n0 = blockIdx.z << 6;
    const unsigned short* Aph = Ah + (long long)z * sA;
    const unsigned short* Apl = Al + (long long)z * sA;
    const unsigned int* Bpz = Bp + (long long)z * sB;
    const int tid = threadIdx.x, lane = tid & 63, wv = tid >> 6;
    const int l15 = lane & 15, quad = lane >> 4;
    const int wm = (wv & 1) << 5, wn = (wv >> 1) << 5;
    f32x4 acc[2][2] = {};
    uint4 ra[2];
    unsigned int rb[8];
    loadW8(Aph, Apl, Kd, m0, 0, tid, ra);
    loadT8(Bpz, Nn, 0, n0, tid, rb);
    for (int k0 = 0; k0 < Kd; k0 += 32) {
        storeW8(As, tid, ra);
        storeT8(Bs, tid, rb);
        __syncthreads();
        const int kn = k0 + 32;
        if (kn < Kd) {
            loadW8(Aph, Apl, Kd, m0, kn, tid, ra);
            loadT8(Bpz, Nn, kn, n0, tid, rb);
        }
        mfma_split(As, Bs, wm, wn, l15, quad, acc);
        __syncthreads();
    }
    #pragma unroll
    for (int mi = 0; mi < 2; ++mi)
    #pragma unroll
    for (int ni = 0; ni < 2; ++ni) {
        const int col = n0 + wn + (ni << 4) + l15;
        #pragma unroll
        for (int r = 0; r < 4; ++r) {
            const int row = m0 + wm + (mi << 4) + (quad << 2) + r;
            float v = acc[mi][ni][r];
            if (rscale) v *= rscale[z * rsn + row];
            if (C)   C[(long long)z * sC + (long long)row * Nn + col] = v;
            if (Cpk) Cpk[(long long)z * sC + (long long)row * Nn + col] = f2pk(v);
        }
    }
}

// ---------------- softmax rows: per-wave row, per-row partials (NO contended atomics) -----
__global__ __launch_bounds__(256) void softmax_rows_wave(
    const float* __restrict__ sm, int L,
    const float* __restrict__ deg,
    float* __restrict__ rowq2, float* __restrict__ rowdq2, int totRows,
    unsigned int* __restrict__ opk)
{
    const int wid = (blockIdx.x * 256 + threadIdx.x) >> 6;
    const int lane = threadIdx.x & 63;
    if (wid >= totRows) return;
    const float* rowp = sm + (long long)wid * L;
    const int nv = L >> 6;
    float v[4];
    if (nv == 4) {
        float4 t = *(const float4*)&rowp[lane << 2];
        v[0] = t.x; v[1] = t.y; v[2] = t.z; v[3] = t.w;
    } else {
        float2 t = *(const float2*)&rowp[lane << 1];
        v[0] = t.x; v[1] = t.y;
    }
    float mx = v[0];
    for (int i = 1; i < nv; ++i) mx = fmaxf(mx, v[i]);
    for (int off = 32; off; off >>= 1) mx = fmaxf(mx, __shfl_xor(mx, off));
    float s = 0.f;
    for (int i = 0; i < nv; ++i) { v[i] = expf(v[i] - mx); s += v[i]; }
    for (int off = 32; off; off >>= 1) s += __shfl_xor(s, off);
    const float inv = 1.f / s;
    float q2 = 0.f;
    for (int i = 0; i < nv; ++i) { float p = v[i] * inv; v[i] = p; q2 += p * p; }
    const long long rb = (long long)wid * L;
    if (nv == 4) {
        uint4 pk;
        pk.x = f2pk(v[0]); pk.y = f2pk(v[1]); pk.z = f2pk(v[2]); pk.w = f2pk(v[3]);
        *(uint4*)&opk[rb + (lane << 2)] = pk;
    } else {
        uint2 pk;
        pk.x = f2pk(v[0]); pk.y = f2pk(v[1]);
        *(uint2*)&opk[rb + (lane << 1)] = pk;
    }
    for (int off = 32; off; off >>= 1) q2 += __shfl_xor(q2, off);
    if (lane == 0) { rowq2[wid] = q2; rowdq2[wid] = deg[wid] * q2; }
}

__global__ __launch_bounds__(256) void reduce2_pergraph(
    const float* __restrict__ a, const float* __restrict__ b, int rowsPerGraph,
    float* __restrict__ outA, float* __restrict__ outB)
{
    __shared__ float redA[4], redB[4];
    const int g = blockIdx.x, t = threadIdx.x;
    float sa = 0.f, sb = 0.f;
    for (int i = t; i < rowsPerGraph; i += 256) {
        sa += a[g * rowsPerGraph + i];
        if (b) sb += b[g * rowsPerGraph + i];
    }
    for (int off = 32; off; off >>= 1) { sa += __shfl_xor(sa, off); sb += __shfl_xor(sb, off); }
    const int wv = t >> 6;
    if ((t & 63) == 0) { redA[wv] = sa; redB[wv] = sb; }
    __syncthreads();
    if (t == 0) {
        outA[g] = redA[0] + redA[1] + redA[2] + redA[3];
        if (outB) outB[g] = redB[0] + redB[1] + redB[2] + redB[3];
    }
}

// ---------------- fused zero-diag + trace + sqrt-deg normalize + split emit ---------------
__global__ __launch_bounds__(1024) void adjnorm(
    const float* __restrict__ adj, int K,
    float* __restrict__ trace_out,
    float* __restrict__ rowsum, float* __restrict__ rscale,
    unsigned short* __restrict__ oh, unsigned short* __restrict__ ol)
{
    __shared__ float dpoolL[256];
    __shared__ float trL;
    const int g = blockIdx.x, tid = threadIdx.x;
    const int wv = tid >> 6, lane = tid & 63;
    if (tid == 0) trL = 0.f;
    __syncthreads();
    const int rowsPerWave = K >> 4;   // 16 waves
    const int nv = K >> 6;
    float trpart = 0.f;
    for (int rr = 0; rr < rowsPerWave; ++rr) {
        const int r = wv * rowsPerWave + rr;
        const float* rowp = adj + (long long)(g * K + r) * K;
        float s = 0.f, dval = 0.f;
        for (int q = 0; q < nv; ++q) {
            int c = lane + (q << 6);
            float v = rowp[c];
            if (c == r) { dval = v; v = 0.f; }
            s += v;
        }
        for (int off = 32; off; off >>= 1) s += __shfl_xor(s, off);
        for (int off = 32; off; off >>= 1) dval += __shfl_xor(dval, off);
        if (lane == 0) { dpoolL[r] = sqrtf(s) + 1e-15f; trpart += dval; }
    }
    if (lane == 0) atomicAdd(&trL, trpart);
    __syncthreads();
    if (tid == 0) trace_out[g] = trL;
    for (int rr = 0; rr < rowsPerWave; ++rr) {
        const int r = wv * rowsPerWave + rr;
        const int wid = g * K + r;
        const float* rowp = adj + (long long)wid * K;
        const float inv_r = 1.f / dpoolL[r];
        float s = 0.f;
        for (int q = 0; q < nv; ++q) {
            int c = lane + (q << 6);
            float a = rowp[c];
            if (c == r) a = 0.f;
            float v = a * inv_r / dpoolL[c];
            s += v;
            unsigned short h = f2bf(v);
            oh[(long long)wid * K + c] = h;
            ol[(long long)wid * K + c] = f2bf(v - bf2f(h));
        }
        for (int off = 32; off; off >>= 1) s += __shfl_xor(s, off);
        if (lane == 0) { rowsum[wid] = s; rscale[wid] = 1.f / fmaxf(s, 1.f); }
    }
}

// ---------------- fused topk: score+rank+select + gather-gate + readout + cnt zero --------
__global__ __launch_bounds__(512) void topk_fused(
    const float* __restrict__ x, const float* __restrict__ p, int n, int k,
    int* __restrict__ new_id, float* __restrict__ outx,
    float* __restrict__ sxsum, int* __restrict__ cntZero)
{
    __shared__ float sc[512];
    __shared__ int pref[512];
    __shared__ int   selL[256];
    __shared__ float gateL[256];
    __shared__ float red[1024];
    const int g = blockIdx.x, tid = threadIdx.x;
    if (cntZero && tid < k) cntZero[g * k + tid] = 0;
    float myScore = 0.f;
    if (tid < n) {
        const float* xr = x + (long long)(g * n + tid) * 128;
        float pn2 = 0.f, d = 0.f;
        #pragma unroll 4
        for (int f = 0; f < 128; f += 4) {
            float4 pv = *(const float4*)&p[f];
            float4 v = *(const float4*)&xr[f];
            pn2 += pv.x * pv.x + pv.y * pv.y + pv.z * pv.z + pv.w * pv.w;
            d += v.x * pv.x + v.y * pv.y + v.z * pv.z + v.w * pv.w;
        }
        myScore = d / (sqrtf(pn2) + 1e-16f);
        sc[tid] = myScore;
    }
    __syncthreads();
    int keep = 0;
    if (tid < n) {
        const float si = myScore;
        int rank = 0;
        for (int j = 0; j < n; j += 4) {
            float4 s4 = *(const float4*)&sc[j];
            rank += (s4.x > si) || (s4.x == si && (j + 0) < tid);
            rank += (s4.y > si) || (s4.y == si && (j + 1) < tid);
            rank += (s4.z > si) || (s4.z == si && (j + 2) < tid);
            rank += (s4.w > si) || (s4.w == si && (j + 3) < tid);
        }
        keep = rank < k;
    }
    pref[tid] = keep;
    __syncthreads();
    for (int d = 1; d < 512; d <<= 1) {
        int u = (tid >= d) ? pref[tid - d] : 0;
        __syncthreads();
        pref[tid] += u;
        __syncthreads();
    }
    if (tid < n) {
        if (keep) {
            int pos = pref[tid] - 1;
            new_id[g * n + tid] = g * k + pos;
            selL[pos] = g * n + tid;
            gateL[pos] = tanhf(myScore);
        } else new_id[g * n + tid] = -1;
    }
    __syncthreads();
    const int f = tid & 127, grp = tid >> 7;     // 4 row-groups x 128 features
    float mx = -INFINITY, sm = 0.f;
    for (int r = grp; r < k; r += 4) {
        float v = x[(long long)selL[r] * 128 + f] * gateL[r];
        outx[(long long)(g * k + r) * 128 + f] = v;
        mx = fmaxf(mx, v); sm += v;
    }
    red[grp * 128 + f] = mx;
    red[512 + grp * 128 + f] = sm;
    __syncthreads();
    if (tid < 128) {
        float m = fmaxf(fmaxf(red[f], red[128 + f]), fmaxf(red[256 + f], red[384 + f]));
        float s2 = red[512 + f] + red[640 + f] + red[768 + f] + red[896 + f];
        sxsum[g * 256 + f] += m;
        sxsum[g * 256 + 128 + f] += s2 / k;
    }
}

__global__ void remap_edges_count(const int* __restrict__ s, const int* __restrict__ d,
                                  const float* __restrict__ m, const int* __restrict__ new_id,
                                  int* __restrict__ so, int* __restrict__ do_,
                                  float* __restrict__ mo, int* __restrict__ counts) {
    int e = blockIdx.x * blockDim.x + threadIdx.x;
    if (e >= NE) return;
    int ns = new_id[s[e]], nd = new_id[d[e]];
    bool v = (ns >= 0) && (nd >= 0) && (m ? (m[e] > 0.f) : true);
    so[e] = v ? ns : 0; do_[e] = v ? nd : 0; mo[e] = v ? 1.f : 0.f;
    if (v) atomicAdd(&counts[nd], 1);
}

// final head: mean_lin fused + mc/o scalar epilogue in block 0
__global__ void final_head(const float* __restrict__ sxsum, const float* __restrict__ w11,
                           const float* __restrict__ b11,
                           const float* __restrict__ xd2, const float* __restrict__ l1w,
                           const float* __restrict__ l1b,
                           const float* __restrict__ w2, const float* __restrict__ b2,
                           const float* __restrict__ accs, float* __restrict__ out) {
    __shared__ float meanv[128];
    __shared__ float sin_[256];
    __shared__ float cat[256];
    __shared__ float rm[2], ro[2];
    int b = blockIdx.x, t = threadIdx.x; // 128
    {
        float s = 0.f;
        for (int n = 0; n < 128; n++) s += xd2[(long long)(b * 128 + n) * 128 + t];
        meanv[t] = s / 128.f;
    }
    if (b == 0) {
        int wvi = t >> 6, lane = t & 63;
        const float* acc = accs + wvi * 256;
        float sqrtk = wvi ? sqrtf(128.f) : 16.f;
        float numv = acc[lane], denv = acc[64 + lane], trv = acc[128 + lane], frov = acc[192 + lane];
        float mcb = numv / (denv + 1e-15f);
        float ssn = sqrtf(frov) + 1e-15f;
        float ob = sqrtf(fmaxf(frov / (ssn * ssn) - 2.f * trv / (ssn * sqrtk) + 1.f, 0.f));
        for (int off = 32; off; off >>= 1) { mcb += __shfl_down(mcb, off); ob += __shfl_down(ob, off); }
        if (lane == 0) { rm[wvi] = mcb; ro[wvi] = ob; }
        __syncthreads();
        if (t == 0) {
            out[640] = -(rm[0] + rm[1]) / 64.f;
            out[641] = (ro[0] + ro[1]) / 64.f;
        }
    }
    sin_[t] = sxsum[b * 256 + t];
    sin_[t + 128] = sxsum[b * 256 + 128 + t];
    __syncthreads();
    float acc = b11[t];
    for (int i = 0; i < 256; i++) acc += sin_[i] * w11[i * 128 + t];
    cat[t] = fmaxf(acc, 0.f);
    float xga = l1b[t];
    for (int i = 0; i < 128; i++) xga += meanv[i] * l1w[i * 128 + t];
    cat[128 + t] = fmaxf(xga, 0.f);
    __syncthreads();
    if (t < 10) {
        float a = b2[t];
        for (int i = 0; i < 256; i++) a += cat[i] * w2[i * 10 + t];
        out[b * 10 + t] = a;
    }
}

// ------------------------------------------------------------------------------------------
extern "C" void kernel_launch(void* const* d_in, const int* in_sizes, int n_in,
                              void* d_out, int out_size, void* d_ws, size_t ws_size,
                              hipStream_t stream) {
    const float* x         = (const float*)d_in[0];
    const int*   src       = (const int*)d_in[1];
    const int*   dst       = (const int*)d_in[2];
    const float* conv0_wr  = (const float*)d_in[3];
    const float* conv0_wrt = (const float*)d_in[4];
    const float* conv0_b   = (const float*)d_in[5];
    const float* sc2_wr    = (const float*)d_in[6];
    const float* sc2_wrt   = (const float*)d_in[7];
    const float* sc2_b     = (const float*)d_in[8];
    const float* sc3_wr    = (const float*)d_in[9];
    const float* sc3_wrt   = (const float*)d_in[10];
    const float* sc3_b     = (const float*)d_in[11];
    const float* sg1_wr    = (const float*)d_in[12];
    const float* sg1_wrt   = (const float*)d_in[13];
    const float* sg1_b     = (const float*)d_in[14];
    const float* sg2_wr    = (const float*)d_in[15];
    const float* sg2_wrt   = (const float*)d_in[16];
    const float* sg2_b     = (const float*)d_in[17];
    const float* pool0_w   = (const float*)d_in[18];
    const float* pool0_b   = (const float*)d_in[19];
    const float* pool1_w   = (const float*)d_in[20];
    const float* pool1_b   = (const float*)d_in[21];
    const float* p1        = (const float*)d_in[22];
    const float* p2        = (const float*)d_in[23];
    const float* p3        = (const float*)d_in[24];
    const float* l11_w     = (const float*)d_in[25];
    const float* l11_b     = (const float*)d_in[26];
    const float* l1_w      = (const float*)d_in[27];
    const float* l1_b      = (const float*)d_in[28];
    const float* l2_w      = (const float*)d_in[29];
    const float* l2_b      = (const float*)d_in[30];
    float* out = (float*)d_out;

    char* w = (char*)d_ws;
    const unsigned long long MBy = 1ull << 20;
    float* x0    = (float*)(w + 0);           // 16 MB
    float* BIG1  = (float*)(w + 16 * MBy);    // 32 MB
    float* BIG2  = (float*)(w + 48 * MBy);    // 32 MB
    float* agg   = (float*)(w + 80 * MBy);    // 16 MB
    float* adj1  = (float*)(w + 104 * MBy);   // 16 MB
    int*   s1    = (int*)(w + 120 * MBy);
    int*   d1    = (int*)(w + 122 * MBy);
    float* m1    = (float*)(w + 124 * MBy);
    int*   s2e   = (int*)(w + 126 * MBy);
    int*   d2e   = (int*)(w + 128 * MBy);
    float* m2e   = (float*)(w + 130 * MBy);
    char*  misc  = w + 132 * MBy;
    float* rowq2  = (float*)(misc);                 // 128 KB (32768 f32)
    float* rowdq2 = (float*)(misc + 128 * 1024);    // 128 KB
    int*   newid = (int*)(misc + 256 * 1024);
    float* deg   = (float*)(misc + 384 * 1024);
    float* rowsum2 = (float*)(misc + 576 * 1024);
    float* rscale2 = (float*)(misc + 640 * 1024);
    float* rowsum3 = (float*)(misc + 736 * 1024);
    float* rscale3 = (float*)(misc + 768 * 1024);
    float* accs    = (float*)(misc + 800 * 1024);
    float* sxsum   = (float*)(misc + 900 * 1024);

    unsigned short* wt_sg1h   = (unsigned short*)(misc + 1024 * 1024);
    unsigned short* wt_sg1l   = wt_sg1h + 32768;
    unsigned short* wt_sg2h   = wt_sg1l + 32768;
    unsigned short* wt_sg2l   = wt_sg2h + 32768;
    unsigned short* wt_pool0h = wt_sg2l + 32768;
    unsigned short* wt_pool0l = wt_pool0h + 32768;
    unsigned short* wt_pool1h = wt_pool0l + 32768;
    unsigned short* wt_pool1l = wt_pool1h + 32768;
    unsigned short* wt_c0h    = wt_pool1l + 32768;
    unsigned short* wt_c0l    = wt_c0h + 32768;
    unsigned short* wt_sc2h   = wt_c0l + 32768;
    unsigned short* wt_sc2l   = wt_sc2h + 32768;
    unsigned short* wt_sc3h   = wt_sc2l + 32768;
    unsigned short* wt_sc3l   = wt_sc3h + 32768;

    float* s_sm  = BIG1;                      // f32 softmax input (pre-softmax scores)
    unsigned int* Tbp = (unsigned int*)BIG2;  // phase A; dead after adj1 GEMM
    float* s2sm  = BIG2 + 4 * 1024 * 1024;                       // +16..24 MiB
    unsigned int* T2p = (unsigned int*)((char*)BIG2 + 24 * MBy); // +24..32 MiB
    float* adj2b = BIG1 + 1024 * 1024;
    float* xd2   = BIG1 + 2 * 1024 * 1024;
    float* sxA   = BIG1 + 3 * 1024 * 1024;
    float* sxE   = BIG1 + 5 * 1024 * 1024;
    float* sxB   = x0;
    float* sxC   = x0 + 2 * 1024 * 1024;
    float* sxD   = x0 + 3 * 1024 * 1024;

    // packed split-bf16 planes (region 136..244 MiB of the workspace)
    unsigned int* s_smp = (unsigned int*)(w + 136 * MBy);  // 32 MiB
    unsigned int* x0p   = (unsigned int*)(w + 168 * MBy);  // 16 MiB
    unsigned int* ox1p  = (unsigned int*)(w + 184 * MBy);  // 8 MiB
    unsigned int* xd1p  = (unsigned int*)(w + 192 * MBy);  // 8 MiB
    unsigned int* s2p   = (unsigned int*)(w + 200 * MBy);  // 8 MiB
    unsigned int* ox2p  = (unsigned int*)(w + 208 * MBy);  // 4 MiB
    unsigned short* a1h = (unsigned short*)(w + 212 * MBy); // 8 MiB
    unsigned short* a1l = (unsigned short*)(w + 220 * MBy); // 8 MiB
    unsigned short* a2h = (unsigned short*)(w + 228 * MBy); // 2 MiB
    unsigned short* a2l = (unsigned short*)(w + 230 * MBy); // 2 MiB
    unsigned int* AXp   = (unsigned int*)(w + 232 * MBy);  // 8 MiB
    unsigned int* AXp2  = (unsigned int*)(w + 240 * MBy);  // 4 MiB

    unsigned int* aggp  = (unsigned int*)agg;
    unsigned int* agg2p = (unsigned int*)agg;
    unsigned int* agg3p = (unsigned int*)agg;

    char* adjc = (char*)adj1;
    int* elA  = (int*)(adjc + 0);
    int* elB  = (int*)(adjc + 2 * MBy);
    int* cntA = (int*)(adjc + 4 * MBy);                  // 128 KB
    int* cntB = (int*)(adjc + 4 * MBy + 128 * 1024);     // contiguous -> one memset
    int* offA = (int*)(adjc + 4 * MBy + 256 * 1024);
    int* curA = (int*)(adjc + 4 * MBy + 384 * 1024);
    int* offB = (int*)(adjc + 4 * MBy + 512 * 1024);
    int* curB = (int*)(adjc + 4 * MBy + 640 * 1024);
    char* aggc = (char*)agg;
    int* elC  = (int*)(aggc + 8 * MBy);
    int* elD  = (int*)(aggc + 10 * MBy);
    int* cntC = (int*)(aggc + 12 * MBy);
    int* offC = (int*)(aggc + 12 * MBy + 256 * 1024);
    int* curC = (int*)(aggc + 12 * MBy + 512 * 1024);
    int* cntD = (int*)(aggc + 13 * MBy);
    int* offD = (int*)(aggc + 13 * MBy + 256 * 1024);
    int* curD = (int*)(aggc + 13 * MBy + 512 * 1024);

    hipMemsetAsync(accs, 0, 520 * sizeof(float), stream);
    hipMemsetAsync(sxsum, 0, 16384 * sizeof(float), stream);
    hipMemsetAsync(cntA, 0, 65536 * sizeof(int), stream);   // cntA + cntB

    {
        WSpec a{sg1_wr, sg1_wrt, 128, 128, 128, wt_sg1h, wt_sg1l};
        WSpec b{sg2_wr, sg2_wrt, 128, 128, 128, wt_sg2h, wt_sg2l};
        WSpec c{pool0_w, nullptr, 128, 0, 256, wt_pool0h, wt_pool0l};
        WSpec d{pool1_w, nullptr, 128, 0, 128, wt_pool1h, wt_pool1l};
        WSpec e{conv0_wr, conv0_wrt, 128, 128, 128, wt_c0h, wt_c0l};
        WSpec f{sc2_wr, sc2_wrt, 128, 128, 128, wt_sc2h, wt_sc2l};
        WSpec g{sc3_wr, sc3_wrt, 128, 128, 128, wt_sc3h, wt_sc3l};
        wconv_all<<<dim3(128, 7), 256, 0, stream>>>(a, b, c, d, e, f, g);
    }

    edge_count2<<<dim3(2048, 2), 256, 0, stream>>>(dst, cntA, src, cntB);
    scan_offsets2<<<dim3(64, 2), 512, 0, stream>>>(cntA, offA, curA, cntB, offB, curB, 512, deg);
    edge_fill2<<<dim3(2048, 2), 256, 0, stream>>>(dst, src, curA, elA, src, dst, curB, elB);

    // ---- conv0: gather (f32 in -> packed out), gemm emits x0 f32 (topk) + x0p packed ----
    gather_csr<<<4096, 256, 0, stream>>>(x, nullptr, 128, offA, cntA, elA, aggp, 32768, 512);
    gemm_aw<<<dim3(2, 512), 256, 0, stream>>>(aggp, nullptr, 128, nullptr, x, 128,
        wt_c0h, wt_c0l, conv0_b, x0, x0p, 128, 1);

    // ---- dense branch, pool 1 ----
    gemm_aw<<<dim3(4, 512), 256, 0, stream>>>(x0p, nullptr, 128, nullptr, nullptr, 0,
        wt_pool0h, wt_pool0l, pool0_b, s_sm, nullptr, 256, 0);
    softmax_rows_wave<<<8192, 256, 0, stream>>>(s_sm, 256, deg, rowq2, rowdq2, 32768, s_smp);
    reduce2_pergraph<<<64, 256, 0, stream>>>(rowq2, rowdq2, 512, accs + 128, accs + 64);
    gather_csr<<<8192, 256, 0, stream>>>(nullptr, s_smp, 256, offB, cntB, elB, Tbp, 32768, 512);
    {   // outx1 (z 0..1) + adj1 (z 2..5) in ONE launch
        TTSet t0{x0p, nullptr, ox1p, nullptr, 128, 0, 512 * 128, 256 * 128};
        TTSet t1{Tbp, adj1, nullptr, accs + 192, 256, 1, 512 * 256, 256 * 256};
        gemm_tt<<<dim3(64, 4, 6), 256, 0, stream>>>(s_smp, 512, 256, 512 * 256, 2, t0, t1);
    }
    adjnorm<<<64, 1024, 0, stream>>>(adj1, 256, accs + 0, rowsum2, rscale2, a1h, a1l);
    // sage1 (rscale fused into gemm_nt epilogue -> AXp packed)
    gemm_nt<<<dim3(64, 4, 2), 256, 0, stream>>>(a1h, a1l, ox1p, nullptr, AXp, rscale2, 256,
        256, 128, 256 * 256, 256 * 128, 256 * 128);
    gemm_aw<<<dim3(2, 256), 256, 0, stream>>>(AXp, nullptr, 128, ox1p, nullptr, 128,
        wt_sg1h, wt_sg1l, sg1_b, nullptr, xd1p, 128, 1);
    // pool 2
    gemm_aw<<<dim3(2, 256), 256, 0, stream>>>(xd1p, nullptr, 128, nullptr, nullptr, 0,
        wt_pool1h, wt_pool1l, pool1_b, s2sm, nullptr, 128, 0);
    softmax_rows_wave<<<4096, 256, 0, stream>>>(s2sm, 128, rowsum2, rowq2, rowdq2, 16384, s2p);
    reduce2_pergraph<<<64, 256, 0, stream>>>(rowq2, rowdq2, 256, accs + 384, accs + 320);
    gemm_nt<<<dim3(64, 4, 2), 256, 0, stream>>>(a1h, a1l, s2p, nullptr, T2p, nullptr, 0,
        256, 128, 256 * 256, 256 * 128, 256 * 128);
    {   // outx2 (z 0..1) + adj2 (z 2..3) in ONE launch
        TTSet t0{xd1p, nullptr, ox2p, nullptr, 128, 0, 256 * 128, 128 * 128};
        TTSet t1{T2p, adj2b, nullptr, accs + 448, 128, 1, 256 * 128, 128 * 128};
        gemm_tt<<<dim3(64, 2, 4), 256, 0, stream>>>(s2p, 256, 128, 256 * 128, 2, t0, t1);
    }
    adjnorm<<<64, 1024, 0, stream>>>(adj2b, 128, accs + 256, rowsum3, rscale3, a2h, a2l);
    // sage2 + head
    gemm_nt<<<dim3(64, 2, 2), 256, 0, stream>>>(a2h, a2l, ox2p, nullptr, AXp2, rscale3, 128,
        128, 128, 128 * 128, 128 * 128, 128 * 128);
    gemm_aw<<<dim3(2, 128), 256, 0, stream>>>(AXp2, nullptr, 128, ox2p, nullptr, 128,
        wt_sg2h, wt_sg2l, sg2_b, xd2, nullptr, 128, 0);

    // ---- sparse branch (topk fused with gather-gate + readout + cnt zeroing) ----
    topk_fused<<<64, 512, 0, stream>>>(x0, p1, 512, 256, newid, sxA, sxsum, cntC);
    remap_edges_count<<<2048, 256, 0, stream>>>(src, dst, nullptr, newid, s1, d1, m1, cntC);
    scan_offsets<<<64, 512, 0, stream>>>(cntC, offC, curC, 256, nullptr);
    edge_fill<<<2048, 256, 0, stream>>>(d1, s1, m1, curC, elC);
    gather_csr<<<2048, 256, 0, stream>>>(sxA, nullptr, 128, offC, cntC, elC, agg2p, 16384, 256);
    gemm_aw<<<dim3(2, 256), 256, 0, stream>>>(agg2p, nullptr, 128, nullptr, sxA, 128,
        wt_sc2h, wt_sc2l, sc2_b, sxB, nullptr, 128, 1);
    topk_fused<<<64, 512, 0, stream>>>(sxB, p2, 256, 128, newid, sxC, sxsum, cntD);
    remap_edges_count<<<2048, 256, 0, stream>>>(s1, d1, m1, newid, s2e, d2e, m2e, cntD);
    scan_offsets<<<64, 512, 0, stream>>>(cntD, offD, curD, 128, nullptr);
    edge_fill<<<2048, 256, 0, stream>>>(d2e, s2e, m2e, curD, elD);
    gather_csr<<<1024, 256, 0, stream>>>(sxC, nullptr, 128, offD, cntD, elD, agg3p, 8192, 128);
    gemm_aw<<<dim3(2, 128), 256, 0, stream>>>(agg3p, nullptr, 128, nullptr, sxC, 128,
        wt_sc3h, wt_sc3l, sc3_b, sxD, nullptr, 128, 1);
    topk_fused<<<64, 512, 0, stream>>>(sxD, p3, 128, 64, newid, sxE, sxsum, nullptr);

    final_head<<<64, 128, 0, stream>>>(sxsum, l11_w, l11_b, xd2, l1_w, l1_b,
        l2_w, l2_b, accs, out);
}

// Round 7
// 645.549 us; speedup vs baseline: 1.0773x; 1.0773x over previous
//
#include <hip/hip_runtime.h>
#include <math.h>

#define NGRAPH 64
#define NE 524288      // total edges
#define EPG 8192       // edges per graph
#define TSZ 2560       // 64 rows * 40 shorts per LDS tile half

typedef short s16x8 __attribute__((ext_vector_type(8)));
typedef float f32x4 __attribute__((ext_vector_type(4)));

__device__ inline unsigned short f2bf(float f) {
    unsigned int u = __float_as_uint(f);
    return (unsigned short)((u + 0x7FFFu + ((u >> 16) & 1u)) >> 16);
}
__device__ inline float bf2f(unsigned short h) {
    return __uint_as_float((unsigned int)h << 16);
}
// packed split-bf16: low16 = hi part, high16 = lo (residual) part
__device__ inline unsigned int f2pk(float v) {
    unsigned short h = f2bf(v);
    return (unsigned int)h | ((unsigned int)f2bf(v - bf2f(h)) << 16);
}

// ---------------- CSR build (L0: both directions in one launch) ---------------------------
__global__ void edge_count2(const int* __restrict__ keyA, int* __restrict__ cntA,
                            const int* __restrict__ keyB, int* __restrict__ cntB) {
    int e = blockIdx.x * 256 + threadIdx.x;
    if (e >= NE) return;
    if (blockIdx.y == 0) atomicAdd(&cntA[keyA[e]], 1);
    else                 atomicAdd(&cntB[keyB[e]], 1);
}

__device__ inline void scan_body(const int* __restrict__ counts, int* __restrict__ offs,
                                 int* __restrict__ cursor, int nPerGraph,
                                 float* __restrict__ degOut, int* s) {
    const int g = blockIdx.x, t = threadIdx.x;
    int v = (t < nPerGraph) ? counts[g * nPerGraph + t] : 0;
    s[t] = v; __syncthreads();
    for (int d = 1; d < 512; d <<= 1) {
        int u = (t >= d) ? s[t - d] : 0;
        __syncthreads();
        s[t] += u;
        __syncthreads();
    }
    if (t < nPerGraph) {
        int o = g * EPG + s[t] - v;
        offs[g * nPerGraph + t] = o;
        cursor[g * nPerGraph + t] = o;
        if (degOut) degOut[g * nPerGraph + t] = (float)v;
    }
}

__global__ __launch_bounds__(512) void scan_offsets(const int* __restrict__ counts,
        int* __restrict__ offs, int* __restrict__ cursor, int nPerGraph,
        float* __restrict__ degOut) {
    __shared__ int s[512];
    scan_body(counts, offs, cursor, nPerGraph, degOut, s);
}

__global__ __launch_bounds__(512) void scan_offsets2(
        const int* __restrict__ cA, int* __restrict__ oA, int* __restrict__ uA,
        const int* __restrict__ cB, int* __restrict__ oB, int* __restrict__ uB,
        int nPerGraph, float* __restrict__ degB) {
    __shared__ int s[512];
    if (blockIdx.y == 0) scan_body(cA, oA, uA, nPerGraph, nullptr, s);
    else                 scan_body(cB, oB, uB, nPerGraph, degB, s);
}

__global__ void edge_fill(const int* __restrict__ key, const int* __restrict__ payload,
                          const float* __restrict__ mask, int* __restrict__ cursor,
                          int* __restrict__ elist) {
    int e = blockIdx.x * 256 + threadIdx.x;
    if (e < NE && (!mask || mask[e] > 0.f)) {
        int p = atomicAdd(&cursor[key[e]], 1);
        elist[p] = payload[e];
    }
}

__global__ void edge_fill2(const int* __restrict__ kA, const int* __restrict__ pA,
                           int* __restrict__ uA, int* __restrict__ eA,
                           const int* __restrict__ kB, const int* __restrict__ pB,
                           int* __restrict__ uB, int* __restrict__ eB) {
    int e = blockIdx.x * 256 + threadIdx.x;
    if (e >= NE) return;
    if (blockIdx.y == 0) { int p = atomicAdd(&uA[kA[e]], 1); eA[p] = pA[e]; }
    else                 { int p = atomicAdd(&uB[kB[e]], 1); eB[p] = pB[e]; }
}

// ---------------- CSR gather: f32 or packed input, packed output --------------------------
__device__ inline void addpk(float4& acc, uint4 u) {
    acc.x += __uint_as_float(u.x << 16) + __uint_as_float(u.x & 0xffff0000u);
    acc.y += __uint_as_float(u.y << 16) + __uint_as_float(u.y & 0xffff0000u);
    acc.z += __uint_as_float(u.z << 16) + __uint_as_float(u.z & 0xffff0000u);
    acc.w += __uint_as_float(u.w << 16) + __uint_as_float(u.w & 0xffff0000u);
}

__global__ __launch_bounds__(256) void gather_csr(
    const float* __restrict__ xf, const unsigned int* __restrict__ xp, int Fx,
    const int* __restrict__ offs, const int* __restrict__ cnts,
    const int* __restrict__ elist,
    unsigned int* __restrict__ opk,
    int totRows, int rowsPerGraph)
{
    const int gid = (blockIdx.x * 256 + threadIdx.x) >> 5;
    const int lane = threadIdx.x & 31;
    const int csh = (Fx == 256) ? 1 : 0;
    const int rid = gid >> csh;
    const int c0 = (gid & ((1 << csh) - 1)) << 7;
    if (rid >= totRows) return;
    const int row = (rid & 63) * rowsPerGraph + (rid >> 6);
    const int beg = offs[row];
    const int n = cnts[row];
    const long long co = (long long)c0 + (lane << 2);
    float4 acc = make_float4(0.f, 0.f, 0.f, 0.f);
    int j = 0;
    if (xp) {
        for (; j + 4 <= n; j += 4) {
            const int n0 = elist[beg + j], n1 = elist[beg + j + 1];
            const int n2 = elist[beg + j + 2], n3 = elist[beg + j + 3];
            const uint4 u0 = *(const uint4*)&xp[(long long)n0 * Fx + co];
            const uint4 u1 = *(const uint4*)&xp[(long long)n1 * Fx + co];
            const uint4 u2 = *(const uint4*)&xp[(long long)n2 * Fx + co];
            const uint4 u3 = *(const uint4*)&xp[(long long)n3 * Fx + co];
            addpk(acc, u0); addpk(acc, u1); addpk(acc, u2); addpk(acc, u3);
        }
        for (; j < n; ++j)
            addpk(acc, *(const uint4*)&xp[(long long)elist[beg + j] * Fx + co]);
    } else {
        for (; j + 4 <= n; j += 4) {
            const int n0 = elist[beg + j], n1 = elist[beg + j + 1];
            const int n2 = elist[beg + j + 2], n3 = elist[beg + j + 3];
            const float4 v0 = *(const float4*)&xf[(long long)n0 * Fx + co];
            const float4 v1 = *(const float4*)&xf[(long long)n1 * Fx + co];
            const float4 v2 = *(const float4*)&xf[(long long)n2 * Fx + co];
            const float4 v3 = *(const float4*)&xf[(long long)n3 * Fx + co];
            acc.x += v0.x + v1.x + v2.x + v3.x;
            acc.y += v0.y + v1.y + v2.y + v3.y;
            acc.z += v0.z + v1.z + v2.z + v3.z;
            acc.w += v0.w + v1.w + v2.w + v3.w;
        }
        for (; j < n; ++j) {
            const float4 v = *(const float4*)&xf[(long long)elist[beg + j] * Fx + co];
            acc.x += v.x; acc.y += v.y; acc.z += v.z; acc.w += v.w;
        }
    }
    uint4 pk;
    pk.x = f2pk(acc.x); pk.y = f2pk(acc.y); pk.z = f2pk(acc.z); pk.w = f2pk(acc.w);
    *(uint4*)&opk[(long long)row * Fx + co] = pk;
}

// ---------------- all 7 weight converts in ONE launch -------------------------------------
struct WSpec {
    const float* w1; const float* w2; int K1; int K2; int Nn;
    unsigned short* oh; unsigned short* ol;
};

__global__ void wconv_all(WSpec s0, WSpec s1, WSpec s2, WSpec s3, WSpec s4, WSpec s5, WSpec s6) {
    WSpec s;
    switch (blockIdx.y) {
        case 0: s = s0; break; case 1: s = s1; break; case 2: s = s2; break;
        case 3: s = s3; break; case 4: s = s4; break; case 5: s = s5; break;
        default: s = s6; break;
    }
    int idx = blockIdx.x * 256 + threadIdx.x;
    int Kt = s.K1 + s.K2;
    if (idx >= s.Nn * Kt) return;
    int n = idx / Kt, k = idx - n * Kt;
    float v = (k < s.K1) ? s.w1[(long long)k * s.Nn + n] : s.w2[(long long)(k - s.K1) * s.Nn + n];
    unsigned short h = f2bf(v);
    s.oh[idx] = h;
    s.ol[idx] = f2bf(v - __uint_as_float((unsigned int)h << 16));
}

// ---------------- staging (hi at base, lo at base+TSZ) ------------------------------------
// direct single-buffered stages (for coalesced-A kernels: gemm_aw, gemm_nt)
__device__ inline void stageN_split(const float* __restrict__ src, int ldk, int k0,
                                    short* lds, int tid) {
    const int r = tid >> 2, kq = (tid & 3) << 3;
    const float* p = src + (long long)r * ldk + k0 + kq;
    float v[8];
    *(float4*)v = *(const float4*)p;
    *(float4*)(v + 4) = *(const float4*)(p + 4);
    s16x8 hv, lv;
    #pragma unroll
    for (int i = 0; i < 8; ++i) {
        unsigned short h = f2bf(v[i]);
        float hf = __uint_as_float((unsigned int)h << 16);
        hv[i] = (short)h;
        lv[i] = (short)f2bf(v[i] - hf);
    }
    *(s16x8*)(lds + r * 40 + kq) = hv;
    *(s16x8*)(lds + TSZ + r * 40 + kq) = lv;
}

__device__ inline void stageN_pk(const unsigned int* __restrict__ src, int ldk, int k0,
                                 short* lds, int tid) {
    const int r = tid >> 2, kq = (tid & 3) << 3;
    const unsigned int* p = src + (long long)r * ldk + k0 + kq;
    uint4 a = *(const uint4*)p;
    uint4 b = *(const uint4*)(p + 4);
    uint4 hw, lw;
    hw.x = (a.x & 0xffffu) | (a.y << 16);
    hw.y = (a.z & 0xffffu) | (a.w << 16);
    hw.z = (b.x & 0xffffu) | (b.y << 16);
    hw.w = (b.z & 0xffffu) | (b.w << 16);
    lw.x = (a.x >> 16) | (a.y & 0xffff0000u);
    lw.y = (a.z >> 16) | (a.w & 0xffff0000u);
    lw.z = (b.x >> 16) | (b.y & 0xffff0000u);
    lw.w = (b.z >> 16) | (b.w & 0xffff0000u);
    *(uint4*)(lds + r * 40 + kq) = hw;
    *(uint4*)(lds + TSZ + r * 40 + kq) = lw;
}

__device__ inline void stageT_pk(const unsigned int* __restrict__ P,
                                 int ldm, int k0, int m0, short* lds, int tid) {
    const int kp = tid >> 4, mc = tid & 15;
    const int k = kp << 1;
    const unsigned int* p0 = P + (long long)(k0 + k) * ldm + m0 + mc;
    const unsigned int* p1 = p0 + ldm;
    #pragma unroll
    for (int i = 0; i < 4; ++i) {
        unsigned int e0 = p0[i << 4], e1 = p1[i << 4];
        const int o = (mc + (i << 4)) * 40 + k;
        *(unsigned int*)(lds + o) = (e0 & 0xffffu) | (e1 << 16);
        *(unsigned int*)(lds + o + TSZ) = (e0 >> 16) | (e1 & 0xffff0000u);
    }
}

__device__ inline void stageW_split(const unsigned short* __restrict__ wh,
                                    const unsigned short* __restrict__ wl, int ldk,
                                    int n0, int k0, short* lds, int tid) {
    const int r = tid >> 2, kq = (tid & 3) << 3;
    *(s16x8*)(lds + r * 40 + kq) = *(const s16x8*)(wh + (long long)(n0 + r) * ldk + k0 + kq);
    *(s16x8*)(lds + TSZ + r * 40 + kq) = *(const s16x8*)(wl + (long long)(n0 + r) * ldk + k0 + kq);
}

// reg-staged double-buffer helpers (for the scattered-load gemm_tt only)
__device__ inline void loadT8(const unsigned int* __restrict__ P, int ldm, int k0, int m0,
                              int tid, unsigned int (&r)[8]) {
    const int kp = tid >> 4, mc = tid & 15;
    const int k = kp << 1;
    const unsigned int* p0 = P + (long long)(k0 + k) * ldm + m0 + mc;
    const unsigned int* p1 = p0 + ldm;
    #pragma unroll
    for (int i = 0; i < 4; ++i) { r[i] = p0[i << 4]; r[4 + i] = p1[i << 4]; }
}
__device__ inline void storeT8(short* lds, int tid, const unsigned int (&r)[8]) {
    const int kp = tid >> 4, mc = tid & 15;
    const int k = kp << 1;
    #pragma unroll
    for (int i = 0; i < 4; ++i) {
        unsigned int e0 = r[i], e1 = r[4 + i];
        const int o = (mc + (i << 4)) * 40 + k;
        *(unsigned int*)(lds + o) = (e0 & 0xffffu) | (e1 << 16);
        *(unsigned int*)(lds + o + TSZ) = (e0 >> 16) | (e1 & 0xffff0000u);
    }
}
__device__ inline void storeT8_hi(short* lds, int tid, const unsigned int (&r)[8]) {
    const int kp = tid >> 4, mc = tid & 15;
    const int k = kp << 1;
    #pragma unroll
    for (int i = 0; i < 4; ++i)
        *(unsigned int*)(lds + (mc + (i << 4)) * 40 + k) =
            (r[i] & 0xffffu) | (r[4 + i] << 16);
}

__device__ inline void mfma_split(const short* As, const short* Bs, int wm, int wn,
                                  int l15, int quad, f32x4 (&acc)[2][2]) {
    const int ko = quad << 3;
    s16x8 ah[2], al[2], bh[2], bl[2];
    #pragma unroll
    for (int i = 0; i < 2; ++i) {
        const int ra = (wm + (i << 4) + l15) * 40 + ko;
        const int rb = (wn + (i << 4) + l15) * 40 + ko;
        ah[i] = *(const s16x8*)&As[ra];
        al[i] = *(const s16x8*)&As[TSZ + ra];
        bh[i] = *(const s16x8*)&Bs[rb];
        bl[i] = *(const s16x8*)&Bs[TSZ + rb];
    }
    #pragma unroll
    for (int mi = 0; mi < 2; ++mi)
    #pragma unroll
    for (int ni = 0; ni < 2; ++ni) {
        f32x4 c = acc[mi][ni];
        c = __builtin_amdgcn_mfma_f32_16x16x32_bf16(ah[mi], bh[ni], c, 0, 0, 0);
        c = __builtin_amdgcn_mfma_f32_16x16x32_bf16(ah[mi], bl[ni], c, 0, 0, 0);
        c = __builtin_amdgcn_mfma_f32_16x16x32_bf16(al[mi], bh[ni], c, 0, 0, 0);
        acc[mi][ni] = c;
    }
}

__device__ inline void mfma_hi(const short* As, const short* Bs, int wm, int wn,
                               int l15, int quad, f32x4 (&acc)[2][2]) {
    const int ko = quad << 3;
    s16x8 ah[2], bh[2];
    #pragma unroll
    for (int i = 0; i < 2; ++i) {
        ah[i] = *(const s16x8*)&As[(wm + (i << 4) + l15) * 40 + ko];
        bh[i] = *(const s16x8*)&Bs[(wn + (i << 4) + l15) * 40 + ko];
    }
    #pragma unroll
    for (int mi = 0; mi < 2; ++mi)
    #pragma unroll
    for (int ni = 0; ni < 2; ++ni)
        acc[mi][ni] = __builtin_amdgcn_mfma_f32_16x16x32_bf16(ah[mi], bh[ni], acc[mi][ni], 0, 0, 0);
}

// ---------------- G1: flat C = op([A1|A2] @ Wt^T + bias), direct staging ------------------
__global__ __launch_bounds__(256) void gemm_aw(
    const unsigned int* __restrict__ A1p, const float* __restrict__ A1f, int K1,
    const unsigned int* __restrict__ A2p, const float* __restrict__ A2f, int K2,
    const unsigned short* __restrict__ Wh, const unsigned short* __restrict__ Wl,
    const float* __restrict__ bias, float* __restrict__ C,
    unsigned int* __restrict__ Cpk,
    int Nn, int doRelu)
{
    __shared__ short As[2 * TSZ], Bs[2 * TSZ];
    const int m0 = blockIdx.y << 6, n0 = blockIdx.x << 6;
    const int tid = threadIdx.x, lane = tid & 63, wv = tid >> 6;
    const int l15 = lane & 15, quad = lane >> 4;
    const int wm = (wv & 1) << 5, wn = (wv >> 1) << 5;
    f32x4 acc[2][2] = {};
    const int Kt = K1 + K2;
    for (int k0 = 0; k0 < Kt; k0 += 32) {
        if (k0 < K1) {
            if (A1p) stageN_pk(A1p + (long long)m0 * K1, K1, k0, As, tid);
            else     stageN_split(A1f + (long long)m0 * K1, K1, k0, As, tid);
        } else {
            if (A2p) stageN_pk(A2p + (long long)m0 * K2, K2, k0 - K1, As, tid);
            else     stageN_split(A2f + (long long)m0 * K2, K2, k0 - K1, As, tid);
        }
        stageW_split(Wh, Wl, Kt, n0, k0, Bs, tid);
        __syncthreads();
        mfma_split(As, Bs, wm, wn, l15, quad, acc);
        __syncthreads();
    }
    #pragma unroll
    for (int mi = 0; mi < 2; ++mi)
    #pragma unroll
    for (int ni = 0; ni < 2; ++ni) {
        const int col = n0 + wn + (ni << 4) + l15;
        const float bv = bias ? bias[col] : 0.f;
        #pragma unroll
        for (int r = 0; r < 4; ++r) {
            const int row = m0 + wm + (mi << 4) + (quad << 2) + r;
            float v = acc[mi][ni][r] + bv;
            if (doRelu) v = fmaxf(v, 0.f);
            if (C)   C[(long long)row * Nn + col] = v;
            if (Cpk) Cpk[(long long)row * Nn + col] = f2pk(v);
        }
    }
}

// ---------------- G2: batched C = A^T B, TWO jobs per launch, reg double-buffered ---------
struct TTSet {
    const unsigned int* Bp;
    float* C; unsigned int* Cpk; float* fro;
    int Nn; int dual;
    long long sB, sC;
};

__global__ __launch_bounds__(256) void gemm_tt(
    const unsigned int* __restrict__ Ap, int Kd, int Mm, long long sA,
    int zsplit, TTSet t0, TTSet t1)
{
    __shared__ short As[2 * TSZ], Bs[2 * TSZ], A2s[TSZ];
    __shared__ float redf[4];
    const int z = blockIdx.x;
    int nz = blockIdx.z;
    const TTSet tt = (nz < zsplit) ? t0 : t1;
    if (blockIdx.z >= zsplit) nz -= zsplit;
    const unsigned int* Apz = Ap + (long long)z * sA;
    const unsigned int* Bpz = tt.Bp + (long long)z * tt.sB;
    const int m0 = blockIdx.y << 6, n0 = nz << 6;
    const int tid = threadIdx.x, lane = tid & 63, wv = tid >> 6;
    const int l15 = lane & 15, quad = lane >> 4;
    const int wm = (wv & 1) << 5, wn = (wv >> 1) << 5;
    const int fw = tt.dual ? ((m0 < n0) ? 2 : ((m0 == n0) ? 1 : 0)) : 0;
    f32x4 acc[2][2] = {};
    f32x4 accA[2][2] = {};
    unsigned int ra[8], rb[8], rh[8];
    loadT8(Apz, Mm, 0, m0, tid, ra);
    loadT8(Bpz, tt.Nn, 0, n0, tid, rb);
    if (fw) loadT8(Apz, Mm, 0, n0, tid, rh);
    for (int k0 = 0; k0 < Kd; k0 += 32) {
        storeT8(As, tid, ra);
        storeT8(Bs, tid, rb);
        if (fw) storeT8_hi(A2s, tid, rh);
        __syncthreads();
        const int kn = k0 + 32;
        if (kn < Kd) {
            loadT8(Apz, Mm, kn, m0, tid, ra);
            loadT8(Bpz, tt.Nn, kn, n0, tid, rb);
            if (fw) loadT8(Apz, Mm, kn, n0, tid, rh);
        }
        mfma_split(As, Bs, wm, wn, l15, quad, acc);
        if (fw) mfma_hi(As, A2s, wm, wn, l15, quad, accA);
        __syncthreads();
    }
    float* Cp = tt.C ? tt.C + (long long)z * tt.sC : nullptr;
    unsigned int* Ckp = tt.Cpk ? tt.Cpk + (long long)z * tt.sC : nullptr;
    #pragma unroll
    for (int mi = 0; mi < 2; ++mi)
    #pragma unroll
    for (int ni = 0; ni < 2; ++ni) {
        const int col = n0 + wn + (ni << 4) + l15;
        #pragma unroll
        for (int r = 0; r < 4; ++r) {
            const int row = m0 + wm + (mi << 4) + (quad << 2) + r;
            const float v = acc[mi][ni][r];
            if (Cp)  Cp[(long long)row * tt.Nn + col] = v;
            if (Ckp) Ckp[(long long)row * tt.Nn + col] = f2pk(v);
        }
    }
    if (fw) {
        float s = 0.f;
        #pragma unroll
        for (int mi = 0; mi < 2; ++mi)
        #pragma unroll
        for (int ni = 0; ni < 2; ++ni)
        #pragma unroll
        for (int r = 0; r < 4; ++r) s += accA[mi][ni][r] * accA[mi][ni][r];
        s *= (float)fw;
        for (int off = 32; off; off >>= 1) s += __shfl_xor(s, off);
        if (lane == 0) redf[wv] = s;
        __syncthreads();
        if (tid == 0) atomicAdd(&tt.fro[z], redf[0] + redf[1] + redf[2] + redf[3]);
    }
}

// ---------------- G3: batched C = A @ B; direct staging; rscale epilogue ------------------
__global__ __launch_bounds__(256) void gemm_nt(
    const unsigned short* __restrict__ Ah, const unsigned short* __restrict__ Al,
    const unsigned int* __restrict__ Bp,
    float* __restrict__ C, unsigned int* __restrict__ Cpk,
    const float* __restrict__ rscale, int rsn,
    int Kd, int Nn, long long sA, long long sB, long long sC)
{
    __shared__ short As[2 * TSZ], Bs[2 * TSZ];
    const int z = blockIdx.x;
    const int m0 = blockIdx.y << 6, n0 = blockIdx.z << 6;
    const unsigned short* Aph = Ah + (long long)z * sA;
    const unsigned short* Apl = Al + (long long)z * sA;
    const unsigned int* Bpz = Bp + (long long)z * sB;
    const int tid = threadIdx.x, lane = tid & 63, wv = tid >> 6;
    const int l15 = lane & 15, quad = lane >> 4;
    const int wm = (wv & 1) << 5, wn = (wv >> 1) << 5;
    f32x4 acc[2][2] = {};
    for (int k0 = 0; k0 < Kd; k0 += 32) {
        stageW_split(Aph, Apl, Kd, m0, k0, As, tid);   // row-major pre-split A: pure 16B copies
        stageT_pk(Bpz, Nn, k0, n0, Bs, tid);
        __syncthreads();
        mfma_split(As, Bs, wm, wn, l15, quad, acc);
        __syncthreads();
    }
    #pragma unroll
    for (int mi = 0; mi < 2; ++mi)
    #pragma unroll
    for (int ni = 0; ni < 2; ++ni) {
        const int col = n0 + wn + (ni << 4) + l15;
        #pragma unroll
        for (int r = 0; r < 4; ++r) {
            const int row = m0 + wm + (mi << 4) + (quad << 2) + r;
            float v = acc[mi][ni][r];
            if (rscale) v *= rscale[z * rsn + row];
            if (C)   C[(long long)z * sC + (long long)row * Nn + col] = v;
            if (Cpk) Cpk[(long long)z * sC + (long long)row * Nn + col] = f2pk(v);
        }
    }
}

// ---------------- softmax rows: per-wave row, per-row partials (NO contended atomics) -----
__global__ __launch_bounds__(256) void softmax_rows_wave(
    const float* __restrict__ sm, int L,
    const float* __restrict__ deg,
    float* __restrict__ rowq2, float* __restrict__ rowdq2, int totRows,
    unsigned int* __restrict__ opk)
{
    const int wid = (blockIdx.x * 256 + threadIdx.x) >> 6;
    const int lane = threadIdx.x & 63;
    if (wid >= totRows) return;
    const float* rowp = sm + (long long)wid * L;
    const int nv = L >> 6;
    float v[4];
    if (nv == 4) {
        float4 t = *(const float4*)&rowp[lane << 2];
        v[0] = t.x; v[1] = t.y; v[2] = t.z; v[3] = t.w;
    } else {
        float2 t = *(const float2*)&rowp[lane << 1];
        v[0] = t.x; v[1] = t.y;
    }
    float mx = v[0];
    for (int i = 1; i < nv; ++i) mx = fmaxf(mx, v[i]);
    for (int off = 32; off; off >>= 1) mx = fmaxf(mx, __shfl_xor(mx, off));
    float s = 0.f;
    for (int i = 0; i < nv; ++i) { v[i] = expf(v[i] - mx); s += v[i]; }
    for (int off = 32; off; off >>= 1) s += __shfl_xor(s, off);
    const float inv = 1.f / s;
    float q2 = 0.f;
    for (int i = 0; i < nv; ++i) { float p = v[i] * inv; v[i] = p; q2 += p * p; }
    const long long rb = (long long)wid * L;
    if (nv == 4) {
        uint4 pk;
        pk.x = f2pk(v[0]); pk.y = f2pk(v[1]); pk.z = f2pk(v[2]); pk.w = f2pk(v[3]);
        *(uint4*)&opk[rb + (lane << 2)] = pk;
    } else {
        uint2 pk;
        pk.x = f2pk(v[0]); pk.y = f2pk(v[1]);
        *(uint2*)&opk[rb + (lane << 1)] = pk;
    }
    for (int off = 32; off; off >>= 1) q2 += __shfl_xor(q2, off);
    if (lane == 0) { rowq2[wid] = q2; rowdq2[wid] = deg[wid] * q2; }
}

__global__ __launch_bounds__(256) void reduce2_pergraph(
    const float* __restrict__ a, const float* __restrict__ b, int rowsPerGraph,
    float* __restrict__ outA, float* __restrict__ outB)
{
    __shared__ float redA[4], redB[4];
    const int g = blockIdx.x, t = threadIdx.x;
    float sa = 0.f, sb = 0.f;
    for (int i = t; i < rowsPerGraph; i += 256) {
        sa += a[g * rowsPerGraph + i];
        if (b) sb += b[g * rowsPerGraph + i];
    }
    for (int off = 32; off; off >>= 1) { sa += __shfl_xor(sa, off); sb += __shfl_xor(sb, off); }
    const int wv = t >> 6;
    if ((t & 63) == 0) { redA[wv] = sa; redB[wv] = sb; }
    __syncthreads();
    if (t == 0) {
        outA[g] = redA[0] + redA[1] + redA[2] + redA[3];
        if (outB) outB[g] = redB[0] + redB[1] + redB[2] + redB[3];
    }
}

// ---------------- fused zero-diag + trace + sqrt-deg normalize + split emit ---------------
__global__ __launch_bounds__(1024) void adjnorm(
    const float* __restrict__ adj, int K,
    float* __restrict__ trace_out,
    float* __restrict__ rowsum, float* __restrict__ rscale,
    unsigned short* __restrict__ oh, unsigned short* __restrict__ ol)
{
    __shared__ float dpoolL[256];
    __shared__ float trL;
    const int g = blockIdx.x, tid = threadIdx.x;
    const int wv = tid >> 6, lane = tid & 63;
    if (tid == 0) trL = 0.f;
    __syncthreads();
    const int rowsPerWave = K >> 4;   // 16 waves
    const int nv = K >> 6;
    float trpart = 0.f;
    for (int rr = 0; rr < rowsPerWave; ++rr) {
        const int r = wv * rowsPerWave + rr;
        const float* rowp = adj + (long long)(g * K + r) * K;
        float s = 0.f, dval = 0.f;
        for (int q = 0; q < nv; ++q) {
            int c = lane + (q << 6);
            float v = rowp[c];
            if (c == r) { dval = v; v = 0.f; }
            s += v;
        }
        for (int off = 32; off; off >>= 1) s += __shfl_xor(s, off);
        for (int off = 32; off; off >>= 1) dval += __shfl_xor(dval, off);
        if (lane == 0) { dpoolL[r] = sqrtf(s) + 1e-15f; trpart += dval; }
    }
    if (lane == 0) atomicAdd(&trL, trpart);
    __syncthreads();
    if (tid == 0) trace_out[g] = trL;
    for (int rr = 0; rr < rowsPerWave; ++rr) {
        const int r = wv * rowsPerWave + rr;
        const int wid = g * K + r;
        const float* rowp = adj + (long long)wid * K;
        const float inv_r = 1.f / dpoolL[r];
        float s = 0.f;
        for (int q = 0; q < nv; ++q) {
            int c = lane + (q << 6);
            float a = rowp[c];
            if (c == r) a = 0.f;
            float v = a * inv_r / dpoolL[c];
            s += v;
            unsigned short h = f2bf(v);
            oh[(long long)wid * K + c] = h;
            ol[(long long)wid * K + c] = f2bf(v - bf2f(h));
        }
        for (int off = 32; off; off >>= 1) s += __shfl_xor(s, off);
        if (lane == 0) { rowsum[wid] = s; rscale[wid] = 1.f / fmaxf(s, 1.f); }
    }
}

// ---------------- fused topk: score+rank+select + gather-gate + readout + cnt zero --------
__global__ __launch_bounds__(512) void topk_fused(
    const float* __restrict__ x, const float* __restrict__ p, int n, int k,
    int* __restrict__ new_id, float* __restrict__ outx,
    float* __restrict__ sxsum, int* __restrict__ cntZero)
{
    __shared__ float sc[512];
    __shared__ int pref[512];
    __shared__ int   selL[256];
    __shared__ float gateL[256];
    __shared__ float red[1024];
    const int g = blockIdx.x, tid = threadIdx.x;
    if (cntZero && tid < k) cntZero[g * k + tid] = 0;
    float myScore = 0.f;
    if (tid < n) {
        const float* xr = x + (long long)(g * n + tid) * 128;
        float pn2 = 0.f, d = 0.f;
        #pragma unroll 4
        for (int f = 0; f < 128; f += 4) {
            float4 pv = *(const float4*)&p[f];
            float4 v = *(const float4*)&xr[f];
            pn2 += pv.x * pv.x + pv.y * pv.y + pv.z * pv.z + pv.w * pv.w;
            d += v.x * pv.x + v.y * pv.y + v.z * pv.z + v.w * pv.w;
        }
        myScore = d / (sqrtf(pn2) + 1e-16f);
        sc[tid] = myScore;
    }
    __syncthreads();
    int keep = 0;
    if (tid < n) {
        const float si = myScore;
        int rank = 0;
        for (int j = 0; j < n; j += 4) {
            float4 s4 = *(const float4*)&sc[j];
            rank += (s4.x > si) || (s4.x == si && (j + 0) < tid);
            rank += (s4.y > si) || (s4.y == si && (j + 1) < tid);
            rank += (s4.z > si) || (s4.z == si && (j + 2) < tid);
            rank += (s4.w > si) || (s4.w == si && (j + 3) < tid);
        }
        keep = rank < k;
    }
    pref[tid] = keep;
    __syncthreads();
    for (int d = 1; d < 512; d <<= 1) {
        int u = (tid >= d) ? pref[tid - d] : 0;
        __syncthreads();
        pref[tid] += u;
        __syncthreads();
    }
    if (tid < n) {
        if (keep) {
            int pos = pref[tid] - 1;
            new_id[g * n + tid] = g * k + pos;
            selL[pos] = g * n + tid;
            gateL[pos] = tanhf(myScore);
        } else new_id[g * n + tid] = -1;
    }
    __syncthreads();
    const int f = tid & 127, grp = tid >> 7;     // 4 row-groups x 128 features
    float mx = -INFINITY, sm = 0.f;
    for (int r = grp; r < k; r += 4) {
        float v = x[(long long)selL[r] * 128 + f] * gateL[r];
        outx[(long long)(g * k + r) * 128 + f] = v;
        mx = fmaxf(mx, v); sm += v;
    }
    red[grp * 128 + f] = mx;
    red[512 + grp * 128 + f] = sm;
    __syncthreads();
    if (tid < 128) {
        float m = fmaxf(fmaxf(red[f], red[128 + f]), fmaxf(red[256 + f], red[384 + f]));
        float s2 = red[512 + f] + red[640 + f] + red[768 + f] + red[896 + f];
        sxsum[g * 256 + f] += m;
        sxsum[g * 256 + 128 + f] += s2 / k;
    }
}

__global__ void remap_edges_count(const int* __restrict__ s, const int* __restrict__ d,
                                  const float* __restrict__ m, const int* __restrict__ new_id,
                                  int* __restrict__ so, int* __restrict__ do_,
                                  float* __restrict__ mo, int* __restrict__ counts) {
    int e = blockIdx.x * blockDim.x + threadIdx.x;
    if (e >= NE) return;
    int ns = new_id[s[e]], nd = new_id[d[e]];
    bool v = (ns >= 0) && (nd >= 0) && (m ? (m[e] > 0.f) : true);
    so[e] = v ? ns : 0; do_[e] = v ? nd : 0; mo[e] = v ? 1.f : 0.f;
    if (v) atomicAdd(&counts[nd], 1);
}

// final head: mean_lin fused + mc/o scalar epilogue in block 0
__global__ void final_head(const float* __restrict__ sxsum, const float* __restrict__ w11,
                           const float* __restrict__ b11,
                           const float* __restrict__ xd2, const float* __restrict__ l1w,
                           const float* __restrict__ l1b,
                           const float* __restrict__ w2, const float* __restrict__ b2,
                           const float* __restrict__ accs, float* __restrict__ out) {
    __shared__ float meanv[128];
    __shared__ float sin_[256];
    __shared__ float cat[256];
    __shared__ float rm[2], ro[2];
    int b = blockIdx.x, t = threadIdx.x; // 128
    {
        float s = 0.f;
        for (int n = 0; n < 128; n++) s += xd2[(long long)(b * 128 + n) * 128 + t];
        meanv[t] = s / 128.f;
    }
    if (b == 0) {
        int wvi = t >> 6, lane = t & 63;
        const float* acc = accs + wvi * 256;
        float sqrtk = wvi ? sqrtf(128.f) : 16.f;
        float numv = acc[lane], denv = acc[64 + lane], trv = acc[128 + lane], frov = acc[192 + lane];
        float mcb = numv / (denv + 1e-15f);
        float ssn = sqrtf(frov) + 1e-15f;
        float ob = sqrtf(fmaxf(frov / (ssn * ssn) - 2.f * trv / (ssn * sqrtk) + 1.f, 0.f));
        for (int off = 32; off; off >>= 1) { mcb += __shfl_down(mcb, off); ob += __shfl_down(ob, off); }
        if (lane == 0) { rm[wvi] = mcb; ro[wvi] = ob; }
        __syncthreads();
        if (t == 0) {
            out[640] = -(rm[0] + rm[1]) / 64.f;
            out[641] = (ro[0] + ro[1]) / 64.f;
        }
    }
    sin_[t] = sxsum[b * 256 + t];
    sin_[t + 128] = sxsum[b * 256 + 128 + t];
    __syncthreads();
    float acc = b11[t];
    for (int i = 0; i < 256; i++) acc += sin_[i] * w11[i * 128 + t];
    cat[t] = fmaxf(acc, 0.f);
    float xga = l1b[t];
    for (int i = 0; i < 128; i++) xga += meanv[i] * l1w[i * 128 + t];
    cat[128 + t] = fmaxf(xga, 0.f);
    __syncthreads();
    if (t < 10) {
        float a = b2[t];
        for (int i = 0; i < 256; i++) a += cat[i] * w2[i * 10 + t];
        out[b * 10 + t] = a;
    }
}

// ------------------------------------------------------------------------------------------
extern "C" void kernel_launch(void* const* d_in, const int* in_sizes, int n_in,
                              void* d_out, int out_size, void* d_ws, size_t ws_size,
                              hipStream_t stream) {
    const float* x         = (const float*)d_in[0];
    const int*   src       = (const int*)d_in[1];
    const int*   dst       = (const int*)d_in[2];
    const float* conv0_wr  = (const float*)d_in[3];
    const float* conv0_wrt = (const float*)d_in[4];
    const float* conv0_b   = (const float*)d_in[5];
    const float* sc2_wr    = (const float*)d_in[6];
    const float* sc2_wrt   = (const float*)d_in[7];
    const float* sc2_b     = (const float*)d_in[8];
    const float* sc3_wr    = (const float*)d_in[9];
    const float* sc3_wrt   = (const float*)d_in[10];
    const float* sc3_b     = (const float*)d_in[11];
    const float* sg1_wr    = (const float*)d_in[12];
    const float* sg1_wrt   = (const float*)d_in[13];
    const float* sg1_b     = (const float*)d_in[14];
    const float* sg2_wr    = (const float*)d_in[15];
    const float* sg2_wrt   = (const float*)d_in[16];
    const float* sg2_b     = (const float*)d_in[17];
    const float* pool0_w   = (const float*)d_in[18];
    const float* pool0_b   = (const float*)d_in[19];
    const float* pool1_w   = (const float*)d_in[20];
    const float* pool1_b   = (const float*)d_in[21];
    const float* p1        = (const float*)d_in[22];
    const float* p2        = (const float*)d_in[23];
    const float* p3        = (const float*)d_in[24];
    const float* l11_w     = (const float*)d_in[25];
    const float* l11_b     = (const float*)d_in[26];
    const float* l1_w      = (const float*)d_in[27];
    const float* l1_b      = (const float*)d_in[28];
    const float* l2_w      = (const float*)d_in[29];
    const float* l2_b      = (const float*)d_in[30];
    float* out = (float*)d_out;

    char* w = (char*)d_ws;
    const unsigned long long MBy = 1ull << 20;
    float* x0    = (float*)(w + 0);           // 16 MB
    float* BIG1  = (float*)(w + 16 * MBy);    // 32 MB
    float* BIG2  = (float*)(w + 48 * MBy);    // 32 MB
    float* agg   = (float*)(w + 80 * MBy);    // 16 MB
    float* adj1  = (float*)(w + 104 * MBy);   // 16 MB
    int*   s1    = (int*)(w + 120 * MBy);
    int*   d1    = (int*)(w + 122 * MBy);
    float* m1    = (float*)(w + 124 * MBy);
    int*   s2e   = (int*)(w + 126 * MBy);
    int*   d2e   = (int*)(w + 128 * MBy);
    float* m2e   = (float*)(w + 130 * MBy);
    char*  misc  = w + 132 * MBy;
    float* rowq2  = (float*)(misc);                 // 128 KB (32768 f32)
    float* rowdq2 = (float*)(misc + 128 * 1024);    // 128 KB
    int*   newid = (int*)(misc + 256 * 1024);
    float* deg   = (float*)(misc + 384 * 1024);
    float* rowsum2 = (float*)(misc + 576 * 1024);
    float* rscale2 = (float*)(misc + 640 * 1024);
    float* rowsum3 = (float*)(misc + 736 * 1024);
    float* rscale3 = (float*)(misc + 768 * 1024);
    float* accs    = (float*)(misc + 800 * 1024);
    float* sxsum   = (float*)(misc + 900 * 1024);

    unsigned short* wt_sg1h   = (unsigned short*)(misc + 1024 * 1024);
    unsigned short* wt_sg1l   = wt_sg1h + 32768;
    unsigned short* wt_sg2h   = wt_sg1l + 32768;
    unsigned short* wt_sg2l   = wt_sg2h + 32768;
    unsigned short* wt_pool0h = wt_sg2l + 32768;
    unsigned short* wt_pool0l = wt_pool0h + 32768;
    unsigned short* wt_pool1h = wt_pool0l + 32768;
    unsigned short* wt_pool1l = wt_pool1h + 32768;
    unsigned short* wt_c0h    = wt_pool1l + 32768;
    unsigned short* wt_c0l    = wt_c0h + 32768;
    unsigned short* wt_sc2h   = wt_c0l + 32768;
    unsigned short* wt_sc2l   = wt_sc2h + 32768;
    unsigned short* wt_sc3h   = wt_sc2l + 32768;
    unsigned short* wt_sc3l   = wt_sc3h + 32768;

    float* s_sm  = BIG1;                      // f32 softmax input (pre-softmax scores)
    unsigned int* Tbp = (unsigned int*)BIG2;  // phase A; dead after adj1 GEMM
    float* s2sm  = BIG2 + 4 * 1024 * 1024;                       // +16..24 MiB
    unsigned int* T2p = (unsigned int*)((char*)BIG2 + 24 * MBy); // +24..32 MiB
    float* adj2b = BIG1 + 1024 * 1024;
    float* xd2   = BIG1 + 2 * 1024 * 1024;
    float* sxA   = BIG1 + 3 * 1024 * 1024;
    float* sxE   = BIG1 + 5 * 1024 * 1024;
    float* sxB   = x0;
    float* sxC   = x0 + 2 * 1024 * 1024;
    float* sxD   = x0 + 3 * 1024 * 1024;

    // packed split-bf16 planes (region 136..244 MiB of the workspace)
    unsigned int* s_smp = (unsigned int*)(w + 136 * MBy);  // 32 MiB
    unsigned int* x0p   = (unsigned int*)(w + 168 * MBy);  // 16 MiB
    unsigned int* ox1p  = (unsigned int*)(w + 184 * MBy);  // 8 MiB
    unsigned int* xd1p  = (unsigned int*)(w + 192 * MBy);  // 8 MiB
    unsigned int* s2p   = (unsigned int*)(w + 200 * MBy);  // 8 MiB
    unsigned int* ox2p  = (unsigned int*)(w + 208 * MBy);  // 4 MiB
    unsigned short* a1h = (unsigned short*)(w + 212 * MBy); // 8 MiB
    unsigned short* a1l = (unsigned short*)(w + 220 * MBy); // 8 MiB
    unsigned short* a2h = (unsigned short*)(w + 228 * MBy); // 2 MiB
    unsigned short* a2l = (unsigned short*)(w + 230 * MBy); // 2 MiB
    unsigned int* AXp   = (unsigned int*)(w + 232 * MBy);  // 8 MiB
    unsigned int* AXp2  = (unsigned int*)(w + 240 * MBy);  // 4 MiB

    unsigned int* aggp  = (unsigned int*)agg;
    unsigned int* agg2p = (unsigned int*)agg;
    unsigned int* agg3p = (unsigned int*)agg;

    char* adjc = (char*)adj1;
    int* elA  = (int*)(adjc + 0);
    int* elB  = (int*)(adjc + 2 * MBy);
    int* cntA = (int*)(adjc + 4 * MBy);                  // 128 KB
    int* cntB = (int*)(adjc + 4 * MBy + 128 * 1024);     // contiguous -> one memset
    int* offA = (int*)(adjc + 4 * MBy + 256 * 1024);
    int* curA = (int*)(adjc + 4 * MBy + 384 * 1024);
    int* offB = (int*)(adjc + 4 * MBy + 512 * 1024);
    int* curB = (int*)(adjc + 4 * MBy + 640 * 1024);
    char* aggc = (char*)agg;
    int* elC  = (int*)(aggc + 8 * MBy);
    int* elD  = (int*)(aggc + 10 * MBy);
    int* cntC = (int*)(aggc + 12 * MBy);
    int* offC = (int*)(aggc + 12 * MBy + 256 * 1024);
    int* curC = (int*)(aggc + 12 * MBy + 512 * 1024);
    int* cntD = (int*)(aggc + 13 * MBy);
    int* offD = (int*)(aggc + 13 * MBy + 256 * 1024);
    int* curD = (int*)(aggc + 13 * MBy + 512 * 1024);

    hipMemsetAsync(accs, 0, 520 * sizeof(float), stream);
    hipMemsetAsync(sxsum, 0, 16384 * sizeof(float), stream);
    hipMemsetAsync(cntA, 0, 65536 * sizeof(int), stream);   // cntA + cntB

    {
        WSpec a{sg1_wr, sg1_wrt, 128, 128, 128, wt_sg1h, wt_sg1l};
        WSpec b{sg2_wr, sg2_wrt, 128, 128, 128, wt_sg2h, wt_sg2l};
        WSpec c{pool0_w, nullptr, 128, 0, 256, wt_pool0h, wt_pool0l};
        WSpec d{pool1_w, nullptr, 128, 0, 128, wt_pool1h, wt_pool1l};
        WSpec e{conv0_wr, conv0_wrt, 128, 128, 128, wt_c0h, wt_c0l};
        WSpec f{sc2_wr, sc2_wrt, 128, 128, 128, wt_sc2h, wt_sc2l};
        WSpec g{sc3_wr, sc3_wrt, 128, 128, 128, wt_sc3h, wt_sc3l};
        wconv_all<<<dim3(128, 7), 256, 0, stream>>>(a, b, c, d, e, f, g);
    }

    edge_count2<<<dim3(2048, 2), 256, 0, stream>>>(dst, cntA, src, cntB);
    scan_offsets2<<<dim3(64, 2), 512, 0, stream>>>(cntA, offA, curA, cntB, offB, curB, 512, deg);
    edge_fill2<<<dim3(2048, 2), 256, 0, stream>>>(dst, src, curA, elA, src, dst, curB, elB);

    // ---- conv0: gather (f32 in -> packed out), gemm emits x0 f32 (topk) + x0p packed ----
    gather_csr<<<4096, 256, 0, stream>>>(x, nullptr, 128, offA, cntA, elA, aggp, 32768, 512);
    gemm_aw<<<dim3(2, 512), 256, 0, stream>>>(aggp, nullptr, 128, nullptr, x, 128,
        wt_c0h, wt_c0l, conv0_b, x0, x0p, 128, 1);

    // ---- dense branch, pool 1 ----
    gemm_aw<<<dim3(4, 512), 256, 0, stream>>>(x0p, nullptr, 128, nullptr, nullptr, 0,
        wt_pool0h, wt_pool0l, pool0_b, s_sm, nullptr, 256, 0);
    softmax_rows_wave<<<8192, 256, 0, stream>>>(s_sm, 256, deg, rowq2, rowdq2, 32768, s_smp);
    reduce2_pergraph<<<64, 256, 0, stream>>>(rowq2, rowdq2, 512, accs + 128, accs + 64);
    gather_csr<<<8192, 256, 0, stream>>>(nullptr, s_smp, 256, offB, cntB, elB, Tbp, 32768, 512);
    {   // outx1 (z 0..1) + adj1 (z 2..5) in ONE launch
        TTSet t0{x0p, nullptr, ox1p, nullptr, 128, 0, 512 * 128, 256 * 128};
        TTSet t1{Tbp, adj1, nullptr, accs + 192, 256, 1, 512 * 256, 256 * 256};
        gemm_tt<<<dim3(64, 4, 6), 256, 0, stream>>>(s_smp, 512, 256, 512 * 256, 2, t0, t1);
    }
    adjnorm<<<64, 1024, 0, stream>>>(adj1, 256, accs + 0, rowsum2, rscale2, a1h, a1l);
    // sage1 (rscale fused into gemm_nt epilogue -> AXp packed)
    gemm_nt<<<dim3(64, 4, 2), 256, 0, stream>>>(a1h, a1l, ox1p, nullptr, AXp, rscale2, 256,
        256, 128, 256 * 256, 256 * 128, 256 * 128);
    gemm_aw<<<dim3(2, 256), 256, 0, stream>>>(AXp, nullptr, 128, ox1p, nullptr, 128,
        wt_sg1h, wt_sg1l, sg1_b, nullptr, xd1p, 128, 1);
    // pool 2
    gemm_aw<<<dim3(2, 256), 256, 0, stream>>>(xd1p, nullptr, 128, nullptr, nullptr, 0,
        wt_pool1h, wt_pool1l, pool1_b, s2sm, nullptr, 128, 0);
    softmax_rows_wave<<<4096, 256, 0, stream>>>(s2sm, 128, rowsum2, rowq2, rowdq2, 16384, s2p);
    reduce2_pergraph<<<64, 256, 0, stream>>>(rowq2, rowdq2, 256, accs + 384, accs + 320);
    gemm_nt<<<dim3(64, 4, 2), 256, 0, stream>>>(a1h, a1l, s2p, nullptr, T2p, nullptr, 0,
        256, 128, 256 * 256, 256 * 128, 256 * 128);
    {   // outx2 (z 0..1) + adj2 (z 2..3) in ONE launch
        TTSet t0{xd1p, nullptr, ox2p, nullptr, 128, 0, 256 * 128, 128 * 128};
        TTSet t1{T2p, adj2b, nullptr, accs + 448, 128, 1, 256 * 128, 128 * 128};
        gemm_tt<<<dim3(64, 2, 4), 256, 0, stream>>>(s2p, 256, 128, 256 * 128, 2, t0, t1);
    }
    adjnorm<<<64, 1024, 0, stream>>>(adj2b, 128, accs + 256, rowsum3, rscale3, a2h, a2l);
    // sage2 + head
    gemm_nt<<<dim3(64, 2, 2), 256, 0, stream>>>(a2h, a2l, ox2p, nullptr, AXp2, rscale3, 128,
        128, 128, 128 * 128, 128 * 128, 128 * 128);
    gemm_aw<<<dim3(2, 128), 256, 0, stream>>>(AXp2, nullptr, 128, ox2p, nullptr, 128,
        wt_sg2h, wt_sg2l, sg2_b, xd2, nullptr, 128, 0);

    // ---- sparse branch (topk fused with gather-gate + readout + cnt zeroing) ----
    topk_fused<<<64, 512, 0, stream>>>(x0, p1, 512, 256, newid, sxA, sxsum, cntC);
    remap_edges_count<<<2048, 256, 0, stream>>>(src, dst, nullptr, newid, s1, d1, m1, cntC);
    scan_offsets<<<64, 512, 0, stream>>>(cntC, offC, curC, 256, nullptr);
    edge_fill<<<2048, 256, 0, stream>>>(d1, s1, m1, curC, elC);
    gather_csr<<<2048, 256, 0, stream>>>(sxA, nullptr, 128, offC, cntC, elC, agg2p, 16384, 256);
    gemm_aw<<<dim3(2, 256), 256, 0, stream>>>(agg2p, nullptr, 128, nullptr, sxA, 128,
        wt_sc2h, wt_sc2l, sc2_b, sxB, nullptr, 128, 1);
    topk_fused<<<64, 512, 0, stream>>>(sxB, p2, 256, 128, newid, sxC, sxsum, cntD);
    remap_edges_count<<<2048, 256, 0, stream>>>(s1, d1, m1, newid, s2e, d2e, m2e, cntD);
    scan_offsets<<<64, 512, 0, stream>>>(cntD, offD, curD, 128, nullptr);
    edge_fill<<<2048, 256, 0, stream>>>(d2e, s2e, m2e, curD, elD);
    gather_csr<<<1024, 256, 0, stream>>>(sxC, nullptr, 128, offD, cntD, elD, agg3p, 8192, 128);
    gemm_aw<<<dim3(2, 128), 256, 0, stream>>>(agg3p, nullptr, 128, nullptr, sxC, 128,
        wt_sc3h, wt_sc3l, sc3_b, sxD, nullptr, 128, 1);
    topk_fused<<<64, 512, 0, stream>>>(sxD, p3, 128, 64, newid, sxE, sxsum, nullptr);

    final_head<<<64, 128, 0, stream>>>(sxsum, l11_w, l11_b, xd2, l1_w, l1_b,
        l2_w, l2_b, accs, out);
}

// Round 8
// 629.245 us; speedup vs baseline: 1.1052x; 1.0259x over previous
//
#include <hip/hip_runtime.h>
#include <math.h>

#define NGRAPH 64
#define NE 524288      // total edges
#define EPG 8192       // edges per graph
#define TSZ 2560       // 64 rows * 40 shorts per LDS tile half

typedef short s16x8 __attribute__((ext_vector_type(8)));
typedef float f32x4 __attribute__((ext_vector_type(4)));

__device__ inline unsigned short f2bf(float f) {
    unsigned int u = __float_as_uint(f);
    return (unsigned short)((u + 0x7FFFu + ((u >> 16) & 1u)) >> 16);
}
__device__ inline float bf2f(unsigned short h) {
    return __uint_as_float((unsigned int)h << 16);
}
// packed split-bf16: low16 = hi part, high16 = lo (residual) part
__device__ inline unsigned int f2pk(float v) {
    unsigned short h = f2bf(v);
    return (unsigned int)h | ((unsigned int)f2bf(v - bf2f(h)) << 16);
}

// ---------------- CSR build (L0: both directions in one launch) ---------------------------
__global__ void edge_count2(const int* __restrict__ keyA, int* __restrict__ cntA,
                            const int* __restrict__ keyB, int* __restrict__ cntB) {
    int e = blockIdx.x * 256 + threadIdx.x;
    if (e >= NE) return;
    if (blockIdx.y == 0) atomicAdd(&cntA[keyA[e]], 1);
    else                 atomicAdd(&cntB[keyB[e]], 1);
}

__device__ inline void scan_body(const int* __restrict__ counts, int* __restrict__ offs,
                                 int* __restrict__ cursor, int nPerGraph,
                                 float* __restrict__ degOut, int* s) {
    const int g = blockIdx.x, t = threadIdx.x;
    int v = (t < nPerGraph) ? counts[g * nPerGraph + t] : 0;
    s[t] = v; __syncthreads();
    for (int d = 1; d < 512; d <<= 1) {
        int u = (t >= d) ? s[t - d] : 0;
        __syncthreads();
        s[t] += u;
        __syncthreads();
    }
    if (t < nPerGraph) {
        int o = g * EPG + s[t] - v;
        offs[g * nPerGraph + t] = o;
        cursor[g * nPerGraph + t] = o;
        if (degOut) degOut[g * nPerGraph + t] = (float)v;
    }
}

__global__ __launch_bounds__(512) void scan_offsets(const int* __restrict__ counts,
        int* __restrict__ offs, int* __restrict__ cursor, int nPerGraph,
        float* __restrict__ degOut) {
    __shared__ int s[512];
    scan_body(counts, offs, cursor, nPerGraph, degOut, s);
}

__global__ __launch_bounds__(512) void scan_offsets2(
        const int* __restrict__ cA, int* __restrict__ oA, int* __restrict__ uA,
        const int* __restrict__ cB, int* __restrict__ oB, int* __restrict__ uB,
        int nPerGraph, float* __restrict__ degB) {
    __shared__ int s[512];
    if (blockIdx.y == 0) scan_body(cA, oA, uA, nPerGraph, nullptr, s);
    else                 scan_body(cB, oB, uB, nPerGraph, degB, s);
}

__global__ void edge_fill(const int* __restrict__ key, const int* __restrict__ payload,
                          const float* __restrict__ mask, int* __restrict__ cursor,
                          int* __restrict__ elist) {
    int e = blockIdx.x * 256 + threadIdx.x;
    if (e < NE && (!mask || mask[e] > 0.f)) {
        int p = atomicAdd(&cursor[key[e]], 1);
        elist[p] = payload[e];
    }
}

__global__ void edge_fill2(const int* __restrict__ kA, const int* __restrict__ pA,
                           int* __restrict__ uA, int* __restrict__ eA,
                           const int* __restrict__ kB, const int* __restrict__ pB,
                           int* __restrict__ uB, int* __restrict__ eB) {
    int e = blockIdx.x * 256 + threadIdx.x;
    if (e >= NE) return;
    if (blockIdx.y == 0) { int p = atomicAdd(&uA[kA[e]], 1); eA[p] = pA[e]; }
    else                 { int p = atomicAdd(&uB[kB[e]], 1); eB[p] = pB[e]; }
}

// ---------------- CSR gather: f32 or packed input, packed output --------------------------
__device__ inline void addpk(float4& acc, uint4 u) {
    acc.x += __uint_as_float(u.x << 16) + __uint_as_float(u.x & 0xffff0000u);
    acc.y += __uint_as_float(u.y << 16) + __uint_as_float(u.y & 0xffff0000u);
    acc.z += __uint_as_float(u.z << 16) + __uint_as_float(u.z & 0xffff0000u);
    acc.w += __uint_as_float(u.w << 16) + __uint_as_float(u.w & 0xffff0000u);
}

__global__ __launch_bounds__(256) void gather_csr(
    const float* __restrict__ xf, const unsigned int* __restrict__ xp, int Fx,
    const int* __restrict__ offs, const int* __restrict__ cnts,
    const int* __restrict__ elist,
    unsigned int* __restrict__ opk,
    int totRows, int rowsPerGraph)
{
    const int gid = (blockIdx.x * 256 + threadIdx.x) >> 5;
    const int lane = threadIdx.x & 31;
    const int csh = (Fx == 256) ? 1 : 0;
    const int rid = gid >> csh;
    const int c0 = (gid & ((1 << csh) - 1)) << 7;
    if (rid >= totRows) return;
    const int row = (rid & 63) * rowsPerGraph + (rid >> 6);
    const int beg = offs[row];
    const int n = cnts[row];
    const long long co = (long long)c0 + (lane << 2);
    float4 acc = make_float4(0.f, 0.f, 0.f, 0.f);
    int j = 0;
    if (xp) {
        for (; j + 4 <= n; j += 4) {
            const int n0 = elist[beg + j], n1 = elist[beg + j + 1];
            const int n2 = elist[beg + j + 2], n3 = elist[beg + j + 3];
            const uint4 u0 = *(const uint4*)&xp[(long long)n0 * Fx + co];
            const uint4 u1 = *(const uint4*)&xp[(long long)n1 * Fx + co];
            const uint4 u2 = *(const uint4*)&xp[(long long)n2 * Fx + co];
            const uint4 u3 = *(const uint4*)&xp[(long long)n3 * Fx + co];
            addpk(acc, u0); addpk(acc, u1); addpk(acc, u2); addpk(acc, u3);
        }
        for (; j < n; ++j)
            addpk(acc, *(const uint4*)&xp[(long long)elist[beg + j] * Fx + co]);
    } else {
        for (; j + 4 <= n; j += 4) {
            const int n0 = elist[beg + j], n1 = elist[beg + j + 1];
            const int n2 = elist[beg + j + 2], n3 = elist[beg + j + 3];
            const float4 v0 = *(const float4*)&xf[(long long)n0 * Fx + co];
            const float4 v1 = *(const float4*)&xf[(long long)n1 * Fx + co];
            const float4 v2 = *(const float4*)&xf[(long long)n2 * Fx + co];
            const float4 v3 = *(const float4*)&xf[(long long)n3 * Fx + co];
            acc.x += v0.x + v1.x + v2.x + v3.x;
            acc.y += v0.y + v1.y + v2.y + v3.y;
            acc.z += v0.z + v1.z + v2.z + v3.z;
            acc.w += v0.w + v1.w + v2.w + v3.w;
        }
        for (; j < n; ++j) {
            const float4 v = *(const float4*)&xf[(long long)elist[beg + j] * Fx + co];
            acc.x += v.x; acc.y += v.y; acc.z += v.z; acc.w += v.w;
        }
    }
    uint4 pk;
    pk.x = f2pk(acc.x); pk.y = f2pk(acc.y); pk.z = f2pk(acc.z); pk.w = f2pk(acc.w);
    *(uint4*)&opk[(long long)row * Fx + co] = pk;
}

// ---------------- all 7 weight converts in ONE launch -------------------------------------
struct WSpec {
    const float* w1; const float* w2; int K1; int K2; int Nn;
    unsigned short* oh; unsigned short* ol;
};

__global__ void wconv_all(WSpec s0, WSpec s1, WSpec s2, WSpec s3, WSpec s4, WSpec s5, WSpec s6) {
    WSpec s;
    switch (blockIdx.y) {
        case 0: s = s0; break; case 1: s = s1; break; case 2: s = s2; break;
        case 3: s = s3; break; case 4: s = s4; break; case 5: s = s5; break;
        default: s = s6; break;
    }
    int idx = blockIdx.x * 256 + threadIdx.x;
    int Kt = s.K1 + s.K2;
    if (idx >= s.Nn * Kt) return;
    int n = idx / Kt, k = idx - n * Kt;
    float v = (k < s.K1) ? s.w1[(long long)k * s.Nn + n] : s.w2[(long long)(k - s.K1) * s.Nn + n];
    unsigned short h = f2bf(v);
    s.oh[idx] = h;
    s.ol[idx] = f2bf(v - __uint_as_float((unsigned int)h << 16));
}

// ---------------- staging (hi at base, lo at base+TSZ) ------------------------------------
__device__ inline void stageN_split(const float* __restrict__ src, int ldk, int k0,
                                    short* lds, int tid) {
    const int r = tid >> 2, kq = (tid & 3) << 3;
    const float* p = src + (long long)r * ldk + k0 + kq;
    float v[8];
    *(float4*)v = *(const float4*)p;
    *(float4*)(v + 4) = *(const float4*)(p + 4);
    s16x8 hv, lv;
    #pragma unroll
    for (int i = 0; i < 8; ++i) {
        unsigned short h = f2bf(v[i]);
        float hf = __uint_as_float((unsigned int)h << 16);
        hv[i] = (short)h;
        lv[i] = (short)f2bf(v[i] - hf);
    }
    *(s16x8*)(lds + r * 40 + kq) = hv;
    *(s16x8*)(lds + TSZ + r * 40 + kq) = lv;
}

__device__ inline void stageN_pk(const unsigned int* __restrict__ src, int ldk, int k0,
                                 short* lds, int tid) {
    const int r = tid >> 2, kq = (tid & 3) << 3;
    const unsigned int* p = src + (long long)r * ldk + k0 + kq;
    uint4 a = *(const uint4*)p;
    uint4 b = *(const uint4*)(p + 4);
    uint4 hw, lw;
    hw.x = (a.x & 0xffffu) | (a.y << 16);
    hw.y = (a.z & 0xffffu) | (a.w << 16);
    hw.z = (b.x & 0xffffu) | (b.y << 16);
    hw.w = (b.z & 0xffffu) | (b.w << 16);
    lw.x = (a.x >> 16) | (a.y & 0xffff0000u);
    lw.y = (a.z >> 16) | (a.w & 0xffff0000u);
    lw.z = (b.x >> 16) | (b.y & 0xffff0000u);
    lw.w = (b.z >> 16) | (b.w & 0xffff0000u);
    *(uint4*)(lds + r * 40 + kq) = hw;
    *(uint4*)(lds + TSZ + r * 40 + kq) = lw;
}

__device__ inline void stageT_pk(const unsigned int* __restrict__ P,
                                 int ldm, int k0, int m0, short* lds, int tid) {
    const int kp = tid >> 4, mc = tid & 15;
    const int k = kp << 1;
    const unsigned int* p0 = P + (long long)(k0 + k) * ldm + m0 + mc;
    const unsigned int* p1 = p0 + ldm;
    #pragma unroll
    for (int i = 0; i < 4; ++i) {
        unsigned int e0 = p0[i << 4], e1 = p1[i << 4];
        const int o = (mc + (i << 4)) * 40 + k;
        *(unsigned int*)(lds + o) = (e0 & 0xffffu) | (e1 << 16);
        *(unsigned int*)(lds + o + TSZ) = (e0 >> 16) | (e1 & 0xffff0000u);
    }
}

__device__ inline void stageW_split(const unsigned short* __restrict__ wh,
                                    const unsigned short* __restrict__ wl, int ldk,
                                    int n0, int k0, short* lds, int tid) {
    const int r = tid >> 2, kq = (tid & 3) << 3;
    *(s16x8*)(lds + r * 40 + kq) = *(const s16x8*)(wh + (long long)(n0 + r) * ldk + k0 + kq);
    *(s16x8*)(lds + TSZ + r * 40 + kq) = *(const s16x8*)(wl + (long long)(n0 + r) * ldk + k0 + kq);
}

// reg-staged double-buffer helpers (scattered transposed loads)
__device__ inline void loadT8(const unsigned int* __restrict__ P, int ldm, int k0, int m0,
                              int tid, unsigned int (&r)[8]) {
    const int kp = tid >> 4, mc = tid & 15;
    const int k = kp << 1;
    const unsigned int* p0 = P + (long long)(k0 + k) * ldm + m0 + mc;
    const unsigned int* p1 = p0 + ldm;
    #pragma unroll
    for (int i = 0; i < 4; ++i) { r[i] = p0[i << 4]; r[4 + i] = p1[i << 4]; }
}
__device__ inline void storeT8(short* lds, int tid, const unsigned int (&r)[8]) {
    const int kp = tid >> 4, mc = tid & 15;
    const int k = kp << 1;
    #pragma unroll
    for (int i = 0; i < 4; ++i) {
        unsigned int e0 = r[i], e1 = r[4 + i];
        const int o = (mc + (i << 4)) * 40 + k;
        *(unsigned int*)(lds + o) = (e0 & 0xffffu) | (e1 << 16);
        *(unsigned int*)(lds + o + TSZ) = (e0 >> 16) | (e1 & 0xffff0000u);
    }
}
__device__ inline void storeT8_hi(short* lds, int tid, const unsigned int (&r)[8]) {
    const int kp = tid >> 4, mc = tid & 15;
    const int k = kp << 1;
    #pragma unroll
    for (int i = 0; i < 4; ++i)
        *(unsigned int*)(lds + (mc + (i << 4)) * 40 + k) =
            (r[i] & 0xffffu) | (r[4 + i] << 16);
}

__device__ inline void mfma_split(const short* As, const short* Bs, int wm, int wn,
                                  int l15, int quad, f32x4 (&acc)[2][2]) {
    const int ko = quad << 3;
    s16x8 ah[2], al[2], bh[2], bl[2];
    #pragma unroll
    for (int i = 0; i < 2; ++i) {
        const int ra = (wm + (i << 4) + l15) * 40 + ko;
        const int rb = (wn + (i << 4) + l15) * 40 + ko;
        ah[i] = *(const s16x8*)&As[ra];
        al[i] = *(const s16x8*)&As[TSZ + ra];
        bh[i] = *(const s16x8*)&Bs[rb];
        bl[i] = *(const s16x8*)&Bs[TSZ + rb];
    }
    #pragma unroll
    for (int mi = 0; mi < 2; ++mi)
    #pragma unroll
    for (int ni = 0; ni < 2; ++ni) {
        f32x4 c = acc[mi][ni];
        c = __builtin_amdgcn_mfma_f32_16x16x32_bf16(ah[mi], bh[ni], c, 0, 0, 0);
        c = __builtin_amdgcn_mfma_f32_16x16x32_bf16(ah[mi], bl[ni], c, 0, 0, 0);
        c = __builtin_amdgcn_mfma_f32_16x16x32_bf16(al[mi], bh[ni], c, 0, 0, 0);
        acc[mi][ni] = c;
    }
}

__device__ inline void mfma_hi(const short* As, const short* Bs, int wm, int wn,
                               int l15, int quad, f32x4 (&acc)[2][2]) {
    const int ko = quad << 3;
    s16x8 ah[2], bh[2];
    #pragma unroll
    for (int i = 0; i < 2; ++i) {
        ah[i] = *(const s16x8*)&As[(wm + (i << 4) + l15) * 40 + ko];
        bh[i] = *(const s16x8*)&Bs[(wn + (i << 4) + l15) * 40 + ko];
    }
    #pragma unroll
    for (int mi = 0; mi < 2; ++mi)
    #pragma unroll
    for (int ni = 0; ni < 2; ++ni)
        acc[mi][ni] = __builtin_amdgcn_mfma_f32_16x16x32_bf16(ah[mi], bh[ni], acc[mi][ni], 0, 0, 0);
}

// ---------------- G1: flat C = op([A1|A2] @ Wt^T + bias), direct staging ------------------
__global__ __launch_bounds__(256) void gemm_aw(
    const unsigned int* __restrict__ A1p, const float* __restrict__ A1f, int K1,
    const unsigned int* __restrict__ A2p, const float* __restrict__ A2f, int K2,
    const unsigned short* __restrict__ Wh, const unsigned short* __restrict__ Wl,
    const float* __restrict__ bias, float* __restrict__ C,
    unsigned int* __restrict__ Cpk,
    int Nn, int doRelu)
{
    __shared__ short As[2 * TSZ], Bs[2 * TSZ];
    const int m0 = blockIdx.y << 6, n0 = blockIdx.x << 6;
    const int tid = threadIdx.x, lane = tid & 63, wv = tid >> 6;
    const int l15 = lane & 15, quad = lane >> 4;
    const int wm = (wv & 1) << 5, wn = (wv >> 1) << 5;
    f32x4 acc[2][2] = {};
    const int Kt = K1 + K2;
    for (int k0 = 0; k0 < Kt; k0 += 32) {
        if (k0 < K1) {
            if (A1p) stageN_pk(A1p + (long long)m0 * K1, K1, k0, As, tid);
            else     stageN_split(A1f + (long long)m0 * K1, K1, k0, As, tid);
        } else {
            if (A2p) stageN_pk(A2p + (long long)m0 * K2, K2, k0 - K1, As, tid);
            else     stageN_split(A2f + (long long)m0 * K2, K2, k0 - K1, As, tid);
        }
        stageW_split(Wh, Wl, Kt, n0, k0, Bs, tid);
        __syncthreads();
        mfma_split(As, Bs, wm, wn, l15, quad, acc);
        __syncthreads();
    }
    #pragma unroll
    for (int mi = 0; mi < 2; ++mi)
    #pragma unroll
    for (int ni = 0; ni < 2; ++ni) {
        const int col = n0 + wn + (ni << 4) + l15;
        const float bv = bias ? bias[col] : 0.f;
        #pragma unroll
        for (int r = 0; r < 4; ++r) {
            const int row = m0 + wm + (mi << 4) + (quad << 2) + r;
            float v = acc[mi][ni][r] + bv;
            if (doRelu) v = fmaxf(v, 0.f);
            if (C)   C[(long long)row * Nn + col] = v;
            if (Cpk) Cpk[(long long)row * Nn + col] = f2pk(v);
        }
    }
}

// ---------------- G2: batched C = A^T B, TWO jobs per launch, reg double-buffered ---------
// adj jobs additionally emit per-row col-sums (atomics) and the diagonal -> single-pass norm
struct TTSet {
    const unsigned int* Bp;
    float* C; unsigned int* Cpk; float* fro;
    int Nn; int dual;
    long long sB, sC;
    float* rsum; float* rdiag;      // per-row stats (adj jobs only), size NGRAPH*Nn
};

__global__ __launch_bounds__(256) void gemm_tt(
    const unsigned int* __restrict__ Ap, int Kd, int Mm, long long sA,
    int zsplit, TTSet t0, TTSet t1)
{
    __shared__ short As[2 * TSZ], Bs[2 * TSZ], A2s[TSZ];
    __shared__ float redf[4];
    const int z = blockIdx.x;
    int nz = blockIdx.z;
    const TTSet tt = (nz < zsplit) ? t0 : t1;
    if (blockIdx.z >= zsplit) nz -= zsplit;
    const unsigned int* Apz = Ap + (long long)z * sA;
    const unsigned int* Bpz = tt.Bp + (long long)z * tt.sB;
    const int m0 = blockIdx.y << 6, n0 = nz << 6;
    const int tid = threadIdx.x, lane = tid & 63, wv = tid >> 6;
    const int l15 = lane & 15, quad = lane >> 4;
    const int wm = (wv & 1) << 5, wn = (wv >> 1) << 5;
    const int fw = tt.dual ? ((m0 < n0) ? 2 : ((m0 == n0) ? 1 : 0)) : 0;
    f32x4 acc[2][2] = {};
    f32x4 accA[2][2] = {};
    unsigned int ra[8], rb[8], rh[8];
    loadT8(Apz, Mm, 0, m0, tid, ra);
    loadT8(Bpz, tt.Nn, 0, n0, tid, rb);
    if (fw) loadT8(Apz, Mm, 0, n0, tid, rh);
    for (int k0 = 0; k0 < Kd; k0 += 32) {
        storeT8(As, tid, ra);
        storeT8(Bs, tid, rb);
        if (fw) storeT8_hi(A2s, tid, rh);
        __syncthreads();
        const int kn = k0 + 32;
        if (kn < Kd) {
            loadT8(Apz, Mm, kn, m0, tid, ra);
            loadT8(Bpz, tt.Nn, kn, n0, tid, rb);
            if (fw) loadT8(Apz, Mm, kn, n0, tid, rh);
        }
        mfma_split(As, Bs, wm, wn, l15, quad, acc);
        if (fw) mfma_hi(As, A2s, wm, wn, l15, quad, accA);
        __syncthreads();
    }
    float* Cp = tt.C ? tt.C + (long long)z * tt.sC : nullptr;
    unsigned int* Ckp = tt.Cpk ? tt.Cpk + (long long)z * tt.sC : nullptr;
    #pragma unroll
    for (int mi = 0; mi < 2; ++mi)
    #pragma unroll
    for (int ni = 0; ni < 2; ++ni) {
        const int col = n0 + wn + (ni << 4) + l15;
        #pragma unroll
        for (int r = 0; r < 4; ++r) {
            const int row = m0 + wm + (mi << 4) + (quad << 2) + r;
            const float v = acc[mi][ni][r];
            if (Cp)  Cp[(long long)row * tt.Nn + col] = v;
            if (Ckp) Ckp[(long long)row * tt.Nn + col] = f2pk(v);
        }
    }
    if (tt.rsum) {
        // per-row partial sums of this wave's 32-column slice; 16-lane (l15) reduce
        #pragma unroll
        for (int mi = 0; mi < 2; ++mi) {
            #pragma unroll
            for (int r = 0; r < 4; ++r) {
                float rs = acc[mi][0][r] + acc[mi][1][r];
                rs += __shfl_xor(rs, 1);
                rs += __shfl_xor(rs, 2);
                rs += __shfl_xor(rs, 4);
                rs += __shfl_xor(rs, 8);
                if (l15 == 0) {
                    const int row = m0 + wm + (mi << 4) + (quad << 2) + r;
                    atomicAdd(&tt.rsum[z * tt.Nn + row], rs);
                }
            }
        }
        // diagonal (only blocks on the diagonal hold it); unique thread per element
        if (tt.rdiag && m0 == n0) {
            #pragma unroll
            for (int mi = 0; mi < 2; ++mi)
            #pragma unroll
            for (int ni = 0; ni < 2; ++ni)
            #pragma unroll
            for (int r = 0; r < 4; ++r) {
                const int rr = wm + (mi << 4) + (quad << 2) + r;
                const int cc = wn + (ni << 4) + l15;
                if (rr == cc) tt.rdiag[z * tt.Nn + m0 + rr] = acc[mi][ni][r];
            }
        }
    }
    if (fw) {
        float s = 0.f;
        #pragma unroll
        for (int mi = 0; mi < 2; ++mi)
        #pragma unroll
        for (int ni = 0; ni < 2; ++ni)
        #pragma unroll
        for (int r = 0; r < 4; ++r) s += accA[mi][ni][r] * accA[mi][ni][r];
        s *= (float)fw;
        for (int off = 32; off; off >>= 1) s += __shfl_xor(s, off);
        if (lane == 0) redf[wv] = s;
        __syncthreads();
        if (tid == 0) atomicAdd(&tt.fro[z], redf[0] + redf[1] + redf[2] + redf[3]);
    }
}

// ---------------- G3: batched C = A @ B; A direct, B reg-prefetched; rscale epilogue ------
__global__ __launch_bounds__(256) void gemm_nt(
    const unsigned short* __restrict__ Ah, const unsigned short* __restrict__ Al,
    const unsigned int* __restrict__ Bp,
    float* __restrict__ C, unsigned int* __restrict__ Cpk,
    const float* __restrict__ rscale, int rsn,
    int Kd, int Nn, long long sA, long long sB, long long sC)
{
    __shared__ short As[2 * TSZ], Bs[2 * TSZ];
    const int z = blockIdx.x;
    const int m0 = blockIdx.y << 6, n0 = blockIdx.z << 6;
    const unsigned short* Aph = Ah + (long long)z * sA;
    const unsigned short* Apl = Al + (long long)z * sA;
    const unsigned int* Bpz = Bp + (long long)z * sB;
    const int tid = threadIdx.x, lane = tid & 63, wv = tid >> 6;
    const int l15 = lane & 15, quad = lane >> 4;
    const int wm = (wv & 1) << 5, wn = (wv >> 1) << 5;
    f32x4 acc[2][2] = {};
    unsigned int rb[8];
    loadT8(Bpz, Nn, 0, n0, tid, rb);
    for (int k0 = 0; k0 < Kd; k0 += 32) {
        stageW_split(Aph, Apl, Kd, m0, k0, As, tid);   // row-major pre-split A: pure 16B copies
        storeT8(Bs, tid, rb);
        __syncthreads();
        const int kn = k0 + 32;
        if (kn < Kd) loadT8(Bpz, Nn, kn, n0, tid, rb);
        mfma_split(As, Bs, wm, wn, l15, quad, acc);
        __syncthreads();
    }
    #pragma unroll
    for (int mi = 0; mi < 2; ++mi)
    #pragma unroll
    for (int ni = 0; ni < 2; ++ni) {
        const int col = n0 + wn + (ni << 4) + l15;
        #pragma unroll
        for (int r = 0; r < 4; ++r) {
            const int row = m0 + wm + (mi << 4) + (quad << 2) + r;
            float v = acc[mi][ni][r];
            if (rscale) v *= rscale[z * rsn + row];
            if (C)   C[(long long)z * sC + (long long)row * Nn + col] = v;
            if (Cpk) Cpk[(long long)z * sC + (long long)row * Nn + col] = f2pk(v);
        }
    }
}

// ---------------- softmax rows: per-wave row, per-row partials (NO contended atomics) -----
__global__ __launch_bounds__(256) void softmax_rows_wave(
    const float* __restrict__ sm, int L,
    const float* __restrict__ deg,
    float* __restrict__ rowq2, float* __restrict__ rowdq2, int totRows,
    unsigned int* __restrict__ opk)
{
    const int wid = (blockIdx.x * 256 + threadIdx.x) >> 6;
    const int lane = threadIdx.x & 63;
    if (wid >= totRows) return;
    const float* rowp = sm + (long long)wid * L;
    const int nv = L >> 6;
    float v[4];
    if (nv == 4) {
        float4 t = *(const float4*)&rowp[lane << 2];
        v[0] = t.x; v[1] = t.y; v[2] = t.z; v[3] = t.w;
    } else {
        float2 t = *(const float2*)&rowp[lane << 1];
        v[0] = t.x; v[1] = t.y;
    }
    float mx = v[0];
    for (int i = 1; i < nv; ++i) mx = fmaxf(mx, v[i]);
    for (int off = 32; off; off >>= 1) mx = fmaxf(mx, __shfl_xor(mx, off));
    float s = 0.f;
    for (int i = 0; i < nv; ++i) { v[i] = expf(v[i] - mx); s += v[i]; }
    for (int off = 32; off; off >>= 1) s += __shfl_xor(s, off);
    const float inv = 1.f / s;
    float q2 = 0.f;
    for (int i = 0; i < nv; ++i) { float p = v[i] * inv; v[i] = p; q2 += p * p; }
    const long long rb = (long long)wid * L;
    if (nv == 4) {
        uint4 pk;
        pk.x = f2pk(v[0]); pk.y = f2pk(v[1]); pk.z = f2pk(v[2]); pk.w = f2pk(v[3]);
        *(uint4*)&opk[rb + (lane << 2)] = pk;
    } else {
        uint2 pk;
        pk.x = f2pk(v[0]); pk.y = f2pk(v[1]);
        *(uint2*)&opk[rb + (lane << 1)] = pk;
    }
    for (int off = 32; off; off >>= 1) q2 += __shfl_xor(q2, off);
    if (lane == 0) { rowq2[wid] = q2; rowdq2[wid] = deg[wid] * q2; }
}

__global__ __launch_bounds__(256) void reduce2_pergraph(
    const float* __restrict__ a, const float* __restrict__ b, int rowsPerGraph,
    float* __restrict__ outA, float* __restrict__ outB)
{
    __shared__ float redA[4], redB[4];
    const int g = blockIdx.x, t = threadIdx.x;
    float sa = 0.f, sb = 0.f;
    for (int i = t; i < rowsPerGraph; i += 256) {
        sa += a[g * rowsPerGraph + i];
        if (b) sb += b[g * rowsPerGraph + i];
    }
    for (int off = 32; off; off >>= 1) { sa += __shfl_xor(sa, off); sb += __shfl_xor(sb, off); }
    const int wv = t >> 6;
    if ((t & 63) == 0) { redA[wv] = sa; redB[wv] = sb; }
    __syncthreads();
    if (t == 0) {
        outA[g] = redA[0] + redA[1] + redA[2] + redA[3];
        if (outB) outB[g] = redB[0] + redB[1] + redB[2] + redB[3];
    }
}

// ---------------- SINGLE-PASS adjnorm: dpool from precomputed rsum/rdiag ------------------
__global__ __launch_bounds__(1024) void adjnorm(
    const float* __restrict__ adj, int K,
    const float* __restrict__ rsumIn, const float* __restrict__ rdiagIn,
    float* __restrict__ trace_out,
    float* __restrict__ rowsum, float* __restrict__ rscale,
    unsigned short* __restrict__ oh, unsigned short* __restrict__ ol)
{
    __shared__ float dpoolL[256];
    __shared__ float redt[16];
    const int g = blockIdx.x, tid = threadIdx.x;
    const int wv = tid >> 6, lane = tid & 63;
    float trp = 0.f;
    for (int r = tid; r < K; r += 1024) {
        float dv = rdiagIn[g * K + r];
        dpoolL[r] = sqrtf(rsumIn[g * K + r] - dv) + 1e-15f;
        trp += dv;
    }
    for (int off = 32; off; off >>= 1) trp += __shfl_xor(trp, off);
    if (lane == 0) redt[wv] = trp;
    __syncthreads();
    if (tid == 0) {
        float t = 0.f;
        #pragma unroll
        for (int i = 0; i < 16; ++i) t += redt[i];
        trace_out[g] = t;
    }
    const int rowsPerWave = K >> 4;   // 16 waves
    const int nv = K >> 6;
    for (int rr = 0; rr < rowsPerWave; ++rr) {
        const int r = wv * rowsPerWave + rr;
        const int wid = g * K + r;
        const float* rowp = adj + (long long)wid * K;
        const float inv_r = 1.f / dpoolL[r];
        float s = 0.f;
        for (int q = 0; q < nv; ++q) {
            int c = lane + (q << 6);
            float a = rowp[c];
            if (c == r) a = 0.f;
            float v = a * inv_r / dpoolL[c];
            s += v;
            unsigned short h = f2bf(v);
            oh[(long long)wid * K + c] = h;
            ol[(long long)wid * K + c] = f2bf(v - bf2f(h));
        }
        for (int off = 32; off; off >>= 1) s += __shfl_xor(s, off);
        if (lane == 0) { rowsum[wid] = s; rscale[wid] = 1.f / fmaxf(s, 1.f); }
    }
}

// ---------------- fused topk: score+rank+select + gather-gate + readout + cnt zero --------
__global__ __launch_bounds__(512) void topk_fused(
    const float* __restrict__ x, const float* __restrict__ p, int n, int k,
    int* __restrict__ new_id, float* __restrict__ outx,
    float* __restrict__ sxsum, int* __restrict__ cntZero)
{
    __shared__ float sc[512];
    __shared__ int pref[512];
    __shared__ int   selL[256];
    __shared__ float gateL[256];
    __shared__ float red[1024];
    const int g = blockIdx.x, tid = threadIdx.x;
    if (cntZero && tid < k) cntZero[g * k + tid] = 0;
    float myScore = 0.f;
    if (tid < n) {
        const float* xr = x + (long long)(g * n + tid) * 128;
        float pn2 = 0.f, d = 0.f;
        #pragma unroll 4
        for (int f = 0; f < 128; f += 4) {
            float4 pv = *(const float4*)&p[f];
            float4 v = *(const float4*)&xr[f];
            pn2 += pv.x * pv.x + pv.y * pv.y + pv.z * pv.z + pv.w * pv.w;
            d += v.x * pv.x + v.y * pv.y + v.z * pv.z + v.w * pv.w;
        }
        myScore = d / (sqrtf(pn2) + 1e-16f);
        sc[tid] = myScore;
    }
    __syncthreads();
    int keep = 0;
    if (tid < n) {
        const float si = myScore;
        int rank = 0;
        for (int j = 0; j < n; j += 4) {
            float4 s4 = *(const float4*)&sc[j];
            rank += (s4.x > si) || (s4.x == si && (j + 0) < tid);
            rank += (s4.y > si) || (s4.y == si && (j + 1) < tid);
            rank += (s4.z > si) || (s4.z == si && (j + 2) < tid);
            rank += (s4.w > si) || (s4.w == si && (j + 3) < tid);
        }
        keep = rank < k;
    }
    pref[tid] = keep;
    __syncthreads();
    for (int d = 1; d < 512; d <<= 1) {
        int u = (tid >= d) ? pref[tid - d] : 0;
        __syncthreads();
        pref[tid] += u;
        __syncthreads();
    }
    if (tid < n) {
        if (keep) {
            int pos = pref[tid] - 1;
            new_id[g * n + tid] = g * k + pos;
            selL[pos] = g * n + tid;
            gateL[pos] = tanhf(myScore);
        } else new_id[g * n + tid] = -1;
    }
    __syncthreads();
    const int f = tid & 127, grp = tid >> 7;     // 4 row-groups x 128 features
    float mx = -INFINITY, sm = 0.f;
    for (int r = grp; r < k; r += 4) {
        float v = x[(long long)selL[r] * 128 + f] * gateL[r];
        outx[(long long)(g * k + r) * 128 + f] = v;
        mx = fmaxf(mx, v); sm += v;
    }
    red[grp * 128 + f] = mx;
    red[512 + grp * 128 + f] = sm;
    __syncthreads();
    if (tid < 128) {
        float m = fmaxf(fmaxf(red[f], red[128 + f]), fmaxf(red[256 + f], red[384 + f]));
        float s2 = red[512 + f] + red[640 + f] + red[768 + f] + red[896 + f];
        sxsum[g * 256 + f] += m;
        sxsum[g * 256 + 128 + f] += s2 / k;
    }
}

__global__ void remap_edges_count(const int* __restrict__ s, const int* __restrict__ d,
                                  const float* __restrict__ m, const int* __restrict__ new_id,
                                  int* __restrict__ so, int* __restrict__ do_,
                                  float* __restrict__ mo, int* __restrict__ counts) {
    int e = blockIdx.x * blockDim.x + threadIdx.x;
    if (e >= NE) return;
    int ns = new_id[s[e]], nd = new_id[d[e]];
    bool v = (ns >= 0) && (nd >= 0) && (m ? (m[e] > 0.f) : true);
    so[e] = v ? ns : 0; do_[e] = v ? nd : 0; mo[e] = v ? 1.f : 0.f;
    if (v) atomicAdd(&counts[nd], 1);
}

// final head: mean_lin fused + mc/o scalar epilogue in block 0
__global__ void final_head(const float* __restrict__ sxsum, const float* __restrict__ w11,
                           const float* __restrict__ b11,
                           const float* __restrict__ xd2, const float* __restrict__ l1w,
                           const float* __restrict__ l1b,
                           const float* __restrict__ w2, const float* __restrict__ b2,
                           const float* __restrict__ accs, float* __restrict__ out) {
    __shared__ float meanv[128];
    __shared__ float sin_[256];
    __shared__ float cat[256];
    __shared__ float rm[2], ro[2];
    int b = blockIdx.x, t = threadIdx.x; // 128
    {
        float s = 0.f;
        for (int n = 0; n < 128; n++) s += xd2[(long long)(b * 128 + n) * 128 + t];
        meanv[t] = s / 128.f;
    }
    if (b == 0) {
        int wvi = t >> 6, lane = t & 63;
        const float* acc = accs + wvi * 256;
        float sqrtk = wvi ? sqrtf(128.f) : 16.f;
        float numv = acc[lane], denv = acc[64 + lane], trv = acc[128 + lane], frov = acc[192 + lane];
        float mcb = numv / (denv + 1e-15f);
        float ssn = sqrtf(frov) + 1e-15f;
        float ob = sqrtf(fmaxf(frov / (ssn * ssn) - 2.f * trv / (ssn * sqrtk) + 1.f, 0.f));
        for (int off = 32; off; off >>= 1) { mcb += __shfl_down(mcb, off); ob += __shfl_down(ob, off); }
        if (lane == 0) { rm[wvi] = mcb; ro[wvi] = ob; }
        __syncthreads();
        if (t == 0) {
            out[640] = -(rm[0] + rm[1]) / 64.f;
            out[641] = (ro[0] + ro[1]) / 64.f;
        }
    }
    sin_[t] = sxsum[b * 256 + t];
    sin_[t + 128] = sxsum[b * 256 + 128 + t];
    __syncthreads();
    float acc = b11[t];
    for (int i = 0; i < 256; i++) acc += sin_[i] * w11[i * 128 + t];
    cat[t] = fmaxf(acc, 0.f);
    float xga = l1b[t];
    for (int i = 0; i < 128; i++) xga += meanv[i] * l1w[i * 128 + t];
    cat[128 + t] = fmaxf(xga, 0.f);
    __syncthreads();
    if (t < 10) {
        float a = b2[t];
        for (int i = 0; i < 256; i++) a += cat[i] * w2[i * 10 + t];
        out[b * 10 + t] = a;
    }
}

// ------------------------------------------------------------------------------------------
extern "C" void kernel_launch(void* const* d_in, const int* in_sizes, int n_in,
                              void* d_out, int out_size, void* d_ws, size_t ws_size,
                              hipStream_t stream) {
    const float* x         = (const float*)d_in[0];
    const int*   src       = (const int*)d_in[1];
    const int*   dst       = (const int*)d_in[2];
    const float* conv0_wr  = (const float*)d_in[3];
    const float* conv0_wrt = (const float*)d_in[4];
    const float* conv0_b   = (const float*)d_in[5];
    const float* sc2_wr    = (const float*)d_in[6];
    const float* sc2_wrt   = (const float*)d_in[7];
    const float* sc2_b     = (const float*)d_in[8];
    const float* sc3_wr    = (const float*)d_in[9];
    const float* sc3_wrt   = (const float*)d_in[10];
    const float* sc3_b     = (const float*)d_in[11];
    const float* sg1_wr    = (const float*)d_in[12];
    const float* sg1_wrt   = (const float*)d_in[13];
    const float* sg1_b     = (const float*)d_in[14];
    const float* sg2_wr    = (const float*)d_in[15];
    const float* sg2_wrt   = (const float*)d_in[16];
    const float* sg2_b     = (const float*)d_in[17];
    const float* pool0_w   = (const float*)d_in[18];
    const float* pool0_b   = (const float*)d_in[19];
    const float* pool1_w   = (const float*)d_in[20];
    const float* pool1_b   = (const float*)d_in[21];
    const float* p1        = (const float*)d_in[22];
    const float* p2        = (const float*)d_in[23];
    const float* p3        = (const float*)d_in[24];
    const float* l11_w     = (const float*)d_in[25];
    const float* l11_b     = (const float*)d_in[26];
    const float* l1_w      = (const float*)d_in[27];
    const float* l1_b      = (const float*)d_in[28];
    const float* l2_w      = (const float*)d_in[29];
    const float* l2_b      = (const float*)d_in[30];
    float* out = (float*)d_out;

    char* w = (char*)d_ws;
    const unsigned long long MBy = 1ull << 20;
    float* x0    = (float*)(w + 0);           // 16 MB
    float* BIG1  = (float*)(w + 16 * MBy);    // 32 MB
    float* BIG2  = (float*)(w + 48 * MBy);    // 32 MB
    float* agg   = (float*)(w + 80 * MBy);    // 16 MB
    float* adj1  = (float*)(w + 104 * MBy);   // 16 MB
    int*   s1    = (int*)(w + 120 * MBy);
    int*   d1    = (int*)(w + 122 * MBy);
    float* m1    = (float*)(w + 124 * MBy);
    int*   s2e   = (int*)(w + 126 * MBy);
    int*   d2e   = (int*)(w + 128 * MBy);
    float* m2e   = (float*)(w + 130 * MBy);
    char*  misc  = w + 132 * MBy;
    float* rowq2  = (float*)(misc);                 // 128 KB (32768 f32)
    float* rowdq2 = (float*)(misc + 128 * 1024);    // 128 KB
    int*   newid = (int*)(misc + 256 * 1024);
    float* deg   = (float*)(misc + 384 * 1024);
    float* rowsum2 = (float*)(misc + 576 * 1024);
    float* rscale2 = (float*)(misc + 640 * 1024);
    float* rowsum3 = (float*)(misc + 736 * 1024);
    float* rscale3 = (float*)(misc + 768 * 1024);
    float* accs    = (float*)(misc + 800 * 1024);
    float* sxsum   = (float*)(misc + 900 * 1024);

    unsigned short* wt_sg1h   = (unsigned short*)(misc + 1024 * 1024);
    unsigned short* wt_sg1l   = wt_sg1h + 32768;
    unsigned short* wt_sg2h   = wt_sg1l + 32768;
    unsigned short* wt_sg2l   = wt_sg2h + 32768;
    unsigned short* wt_pool0h = wt_sg2l + 32768;
    unsigned short* wt_pool0l = wt_pool0h + 32768;
    unsigned short* wt_pool1h = wt_pool0l + 32768;
    unsigned short* wt_pool1l = wt_pool1h + 32768;
    unsigned short* wt_c0h    = wt_pool1l + 32768;
    unsigned short* wt_c0l    = wt_c0h + 32768;
    unsigned short* wt_sc2h   = wt_c0l + 32768;
    unsigned short* wt_sc2l   = wt_sc2h + 32768;
    unsigned short* wt_sc3h   = wt_sc2l + 32768;
    unsigned short* wt_sc3l   = wt_sc3h + 32768;

    // adj row stats (zeroed each iteration): rsum1+rdiag1 contiguous, rsum2+rdiag2 contiguous
    float* rsum1  = (float*)(misc + 2048 * 1024);   // 64 KB (64*256)
    float* rdiag1 = (float*)(misc + 2112 * 1024);   // 64 KB
    float* rsum2  = (float*)(misc + 2176 * 1024);   // 32 KB (64*128)
    float* rdiag2 = (float*)(misc + 2208 * 1024);   // 32 KB

    float* s_sm  = BIG1;                      // f32 softmax input (pre-softmax scores)
    unsigned int* Tbp = (unsigned int*)BIG2;  // phase A; dead after adj1 GEMM
    float* s2sm  = BIG2 + 4 * 1024 * 1024;                       // +16..24 MiB
    unsigned int* T2p = (unsigned int*)((char*)BIG2 + 24 * MBy); // +24..32 MiB
    float* adj2b = BIG1 + 1024 * 1024;
    float* xd2   = BIG1 + 2 * 1024 * 1024;
    float* sxA   = BIG1 + 3 * 1024 * 1024;
    float* sxE   = BIG1 + 5 * 1024 * 1024;
    float* sxB   = x0;
    float* sxC   = x0 + 2 * 1024 * 1024;
    float* sxD   = x0 + 3 * 1024 * 1024;

    // packed split-bf16 planes (region 136..244 MiB of the workspace)
    unsigned int* s_smp = (unsigned int*)(w + 136 * MBy);  // 32 MiB
    unsigned int* x0p   = (unsigned int*)(w + 168 * MBy);  // 16 MiB
    unsigned int* ox1p  = (unsigned int*)(w + 184 * MBy);  // 8 MiB
    unsigned int* xd1p  = (unsigned int*)(w + 192 * MBy);  // 8 MiB
    unsigned int* s2p   = (unsigned int*)(w + 200 * MBy);  // 8 MiB
    unsigned int* ox2p  = (unsigned int*)(w + 208 * MBy);  // 4 MiB
    unsigned short* a1h = (unsigned short*)(w + 212 * MBy); // 8 MiB
    unsigned short* a1l = (unsigned short*)(w + 220 * MBy); // 8 MiB
    unsigned short* a2h = (unsigned short*)(w + 228 * MBy); // 2 MiB
    unsigned short* a2l = (unsigned short*)(w + 230 * MBy); // 2 MiB
    unsigned int* AXp   = (unsigned int*)(w + 232 * MBy);  // 8 MiB
    unsigned int* AXp2  = (unsigned int*)(w + 240 * MBy);  // 4 MiB

    unsigned int* aggp  = (unsigned int*)agg;
    unsigned int* agg2p = (unsigned int*)agg;
    unsigned int* agg3p = (unsigned int*)agg;

    char* adjc = (char*)adj1;
    int* elA  = (int*)(adjc + 0);
    int* elB  = (int*)(adjc + 2 * MBy);
    int* cntA = (int*)(adjc + 4 * MBy);                  // 128 KB
    int* cntB = (int*)(adjc + 4 * MBy + 128 * 1024);     // contiguous -> one memset
    int* offA = (int*)(adjc + 4 * MBy + 256 * 1024);
    int* curA = (int*)(adjc + 4 * MBy + 384 * 1024);
    int* offB = (int*)(adjc + 4 * MBy + 512 * 1024);
    int* curB = (int*)(adjc + 4 * MBy + 640 * 1024);
    char* aggc = (char*)agg;
    int* elC  = (int*)(aggc + 8 * MBy);
    int* elD  = (int*)(aggc + 10 * MBy);
    int* cntC = (int*)(aggc + 12 * MBy);
    int* offC = (int*)(aggc + 12 * MBy + 256 * 1024);
    int* curC = (int*)(aggc + 12 * MBy + 512 * 1024);
    int* cntD = (int*)(aggc + 13 * MBy);
    int* offD = (int*)(aggc + 13 * MBy + 256 * 1024);
    int* curD = (int*)(aggc + 13 * MBy + 512 * 1024);

    hipMemsetAsync(accs, 0, 520 * sizeof(float), stream);
    hipMemsetAsync(sxsum, 0, 16384 * sizeof(float), stream);
    hipMemsetAsync(cntA, 0, 65536 * sizeof(int), stream);   // cntA + cntB
    hipMemsetAsync(rsum1, 0, 128 * 1024, stream);           // rsum1 + rdiag1
    hipMemsetAsync(rsum2, 0, 64 * 1024, stream);            // rsum2 + rdiag2

    {
        WSpec a{sg1_wr, sg1_wrt, 128, 128, 128, wt_sg1h, wt_sg1l};
        WSpec b{sg2_wr, sg2_wrt, 128, 128, 128, wt_sg2h, wt_sg2l};
        WSpec c{pool0_w, nullptr, 128, 0, 256, wt_pool0h, wt_pool0l};
        WSpec d{pool1_w, nullptr, 128, 0, 128, wt_pool1h, wt_pool1l};
        WSpec e{conv0_wr, conv0_wrt, 128, 128, 128, wt_c0h, wt_c0l};
        WSpec f{sc2_wr, sc2_wrt, 128, 128, 128, wt_sc2h, wt_sc2l};
        WSpec g{sc3_wr, sc3_wrt, 128, 128, 128, wt_sc3h, wt_sc3l};
        wconv_all<<<dim3(128, 7), 256, 0, stream>>>(a, b, c, d, e, f, g);
    }

    edge_count2<<<dim3(2048, 2), 256, 0, stream>>>(dst, cntA, src, cntB);
    scan_offsets2<<<dim3(64, 2), 512, 0, stream>>>(cntA, offA, curA, cntB, offB, curB, 512, deg);
    edge_fill2<<<dim3(2048, 2), 256, 0, stream>>>(dst, src, curA, elA, src, dst, curB, elB);

    // ---- conv0: gather (f32 in -> packed out), gemm emits x0 f32 (topk) + x0p packed ----
    gather_csr<<<4096, 256, 0, stream>>>(x, nullptr, 128, offA, cntA, elA, aggp, 32768, 512);
    gemm_aw<<<dim3(2, 512), 256, 0, stream>>>(aggp, nullptr, 128, nullptr, x, 128,
        wt_c0h, wt_c0l, conv0_b, x0, x0p, 128, 1);

    // ---- dense branch, pool 1 ----
    gemm_aw<<<dim3(4, 512), 256, 0, stream>>>(x0p, nullptr, 128, nullptr, nullptr, 0,
        wt_pool0h, wt_pool0l, pool0_b, s_sm, nullptr, 256, 0);
    softmax_rows_wave<<<8192, 256, 0, stream>>>(s_sm, 256, deg, rowq2, rowdq2, 32768, s_smp);
    reduce2_pergraph<<<64, 256, 0, stream>>>(rowq2, rowdq2, 512, accs + 128, accs + 64);
    gather_csr<<<8192, 256, 0, stream>>>(nullptr, s_smp, 256, offB, cntB, elB, Tbp, 32768, 512);
    {   // outx1 (z 0..1) + adj1 (z 2..5) in ONE launch; adj job emits row stats
        TTSet t0{x0p, nullptr, ox1p, nullptr, 128, 0, 512 * 128, 256 * 128, nullptr, nullptr};
        TTSet t1{Tbp, adj1, nullptr, accs + 192, 256, 1, 512 * 256, 256 * 256, rsum1, rdiag1};
        gemm_tt<<<dim3(64, 4, 6), 256, 0, stream>>>(s_smp, 512, 256, 512 * 256, 2, t0, t1);
    }
    adjnorm<<<64, 1024, 0, stream>>>(adj1, 256, rsum1, rdiag1, accs + 0,
        rowsum2, rscale2, a1h, a1l);
    // sage1 (rscale fused into gemm_nt epilogue -> AXp packed)
    gemm_nt<<<dim3(64, 4, 2), 256, 0, stream>>>(a1h, a1l, ox1p, nullptr, AXp, rscale2, 256,
        256, 128, 256 * 256, 256 * 128, 256 * 128);
    gemm_aw<<<dim3(2, 256), 256, 0, stream>>>(AXp, nullptr, 128, ox1p, nullptr, 128,
        wt_sg1h, wt_sg1l, sg1_b, nullptr, xd1p, 128, 1);
    // pool 2
    gemm_aw<<<dim3(2, 256), 256, 0, stream>>>(xd1p, nullptr, 128, nullptr, nullptr, 0,
        wt_pool1h, wt_pool1l, pool1_b, s2sm, nullptr, 128, 0);
    softmax_rows_wave<<<4096, 256, 0, stream>>>(s2sm, 128, rowsum2, rowq2, rowdq2, 16384, s2p);
    reduce2_pergraph<<<64, 256, 0, stream>>>(rowq2, rowdq2, 256, accs + 384, accs + 320);
    gemm_nt<<<dim3(64, 4, 2), 256, 0, stream>>>(a1h, a1l, s2p, nullptr, T2p, nullptr, 0,
        256, 128, 256 * 256, 256 * 128, 256 * 128);
    {   // outx2 (z 0..1) + adj2 (z 2..3) in ONE launch; adj job emits row stats
        TTSet t0{xd1p, nullptr, ox2p, nullptr, 128, 0, 256 * 128, 128 * 128, nullptr, nullptr};
        TTSet t1{T2p, adj2b, nullptr, accs + 448, 128, 1, 256 * 128, 128 * 128, rsum2, rdiag2};
        gemm_tt<<<dim3(64, 2, 4), 256, 0, stream>>>(s2p, 256, 128, 256 * 128, 2, t0, t1);
    }
    adjnorm<<<64, 1024, 0, stream>>>(adj2b, 128, rsum2, rdiag2, accs + 256,
        rowsum3, rscale3, a2h, a2l);
    // sage2 + head
    gemm_nt<<<dim3(64, 2, 2), 256, 0, stream>>>(a2h, a2l, ox2p, nullptr, AXp2, rscale3, 128,
        128, 128, 128 * 128, 128 * 128, 128 * 128);
    gemm_aw<<<dim3(2, 128), 256, 0, stream>>>(AXp2, nullptr, 128, ox2p, nullptr, 128,
        wt_sg2h, wt_sg2l, sg2_b, xd2, nullptr, 128, 0);

    // ---- sparse branch (topk fused with gather-gate + readout + cnt zeroing) ----
    topk_fused<<<64, 512, 0, stream>>>(x0, p1, 512, 256, newid, sxA, sxsum, cntC);
    remap_edges_count<<<2048, 256, 0, stream>>>(src, dst, nullptr, newid, s1, d1, m1, cntC);
    scan_offsets<<<64, 512, 0, stream>>>(cntC, offC, curC, 256, nullptr);
    edge_fill<<<2048, 256, 0, stream>>>(d1, s1, m1, curC, elC);
    gather_csr<<<2048, 256, 0, stream>>>(sxA, nullptr, 128, offC, cntC, elC, agg2p, 16384, 256);
    gemm_aw<<<dim3(2, 256), 256, 0, stream>>>(agg2p, nullptr, 128, nullptr, sxA, 128,
        wt_sc2h, wt_sc2l, sc2_b, sxB, nullptr, 128, 1);
    topk_fused<<<64, 512, 0, stream>>>(sxB, p2, 256, 128, newid, sxC, sxsum, cntD);
    remap_edges_count<<<2048, 256, 0, stream>>>(s1, d1, m1, newid, s2e, d2e, m2e, cntD);
    scan_offsets<<<64, 512, 0, stream>>>(cntD, offD, curD, 128, nullptr);
    edge_fill<<<2048, 256, 0, stream>>>(d2e, s2e, m2e, curD, elD);
    gather_csr<<<1024, 256, 0, stream>>>(sxC, nullptr, 128, offD, cntD, elD, agg3p, 8192, 128);
    gemm_aw<<<dim3(2, 128), 256, 0, stream>>>(agg3p, nullptr, 128, nullptr, sxC, 128,
        wt_sc3h, wt_sc3l, sc3_b, sxD, nullptr, 128, 1);
    topk_fused<<<64, 512, 0, stream>>>(sxD, p3, 128, 64, newid, sxE, sxsum, nullptr);

    final_head<<<64, 128, 0, stream>>>(sxsum, l11_w, l11_b, xd2, l1_w, l1_b,
        l2_w, l2_b, accs, out);
}

// Round 9
// 626.937 us; speedup vs baseline: 1.1093x; 1.0037x over previous
//
#include <hip/hip_runtime.h>
#include <math.h>

#define NGRAPH 64
#define NE 524288      // total edges
#define EPG 8192       // edges per graph
#define TSZ 2560       // 64 rows * 40 shorts per LDS tile half

typedef short s16x8 __attribute__((ext_vector_type(8)));
typedef float f32x4 __attribute__((ext_vector_type(4)));

__device__ inline unsigned short f2bf(float f) {
    unsigned int u = __float_as_uint(f);
    return (unsigned short)((u + 0x7FFFu + ((u >> 16) & 1u)) >> 16);
}
__device__ inline float bf2f(unsigned short h) {
    return __uint_as_float((unsigned int)h << 16);
}
// packed split-bf16: low16 = hi part, high16 = lo (residual) part
__device__ inline unsigned int f2pk(float v) {
    unsigned short h = f2bf(v);
    return (unsigned int)h | ((unsigned int)f2bf(v - bf2f(h)) << 16);
}

// ---------------- CSR build (L0: both directions in one launch) ---------------------------
__global__ void edge_count2(const int* __restrict__ keyA, int* __restrict__ cntA,
                            const int* __restrict__ keyB, int* __restrict__ cntB) {
    int e = blockIdx.x * 256 + threadIdx.x;
    if (e >= NE) return;
    if (blockIdx.y == 0) atomicAdd(&cntA[keyA[e]], 1);
    else                 atomicAdd(&cntB[keyB[e]], 1);
}

__device__ inline void scan_body(const int* __restrict__ counts, int* __restrict__ offs,
                                 int* __restrict__ cursor, int nPerGraph,
                                 float* __restrict__ degOut, int* s) {
    const int g = blockIdx.x, t = threadIdx.x;
    int v = (t < nPerGraph) ? counts[g * nPerGraph + t] : 0;
    s[t] = v; __syncthreads();
    for (int d = 1; d < 512; d <<= 1) {
        int u = (t >= d) ? s[t - d] : 0;
        __syncthreads();
        s[t] += u;
        __syncthreads();
    }
    if (t < nPerGraph) {
        int o = g * EPG + s[t] - v;
        offs[g * nPerGraph + t] = o;
        cursor[g * nPerGraph + t] = o;
        if (degOut) degOut[g * nPerGraph + t] = (float)v;
    }
}

__global__ __launch_bounds__(512) void scan_offsets2(
        const int* __restrict__ cA, int* __restrict__ oA, int* __restrict__ uA,
        const int* __restrict__ cB, int* __restrict__ oB, int* __restrict__ uB,
        int nPerGraph, float* __restrict__ degB) {
    __shared__ int s[512];
    if (blockIdx.y == 0) scan_body(cA, oA, uA, nPerGraph, nullptr, s);
    else                 scan_body(cB, oB, uB, nPerGraph, degB, s);
}

__global__ void edge_fill2(const int* __restrict__ kA, const int* __restrict__ pA,
                           int* __restrict__ uA, int* __restrict__ eA,
                           const int* __restrict__ kB, const int* __restrict__ pB,
                           int* __restrict__ uB, int* __restrict__ eB) {
    int e = blockIdx.x * 256 + threadIdx.x;
    if (e >= NE) return;
    if (blockIdx.y == 0) { int p = atomicAdd(&uA[kA[e]], 1); eA[p] = pA[e]; }
    else                 { int p = atomicAdd(&uB[kB[e]], 1); eB[p] = pB[e]; }
}

// ---------------- CSR gather: f32 or packed input, packed output --------------------------
__device__ inline void addpk(float4& acc, uint4 u) {
    acc.x += __uint_as_float(u.x << 16) + __uint_as_float(u.x & 0xffff0000u);
    acc.y += __uint_as_float(u.y << 16) + __uint_as_float(u.y & 0xffff0000u);
    acc.z += __uint_as_float(u.z << 16) + __uint_as_float(u.z & 0xffff0000u);
    acc.w += __uint_as_float(u.w << 16) + __uint_as_float(u.w & 0xffff0000u);
}

__global__ __launch_bounds__(256) void gather_csr(
    const float* __restrict__ xf, const unsigned int* __restrict__ xp, int Fx,
    const int* __restrict__ offs, const int* __restrict__ cnts,
    const int* __restrict__ elist,
    unsigned int* __restrict__ opk,
    int totRows, int rowsPerGraph)
{
    const int gid = (blockIdx.x * 256 + threadIdx.x) >> 5;
    const int lane = threadIdx.x & 31;
    const int csh = (Fx == 256) ? 1 : 0;
    const int rid = gid >> csh;
    const int c0 = (gid & ((1 << csh) - 1)) << 7;
    if (rid >= totRows) return;
    const int row = (rid & 63) * rowsPerGraph + (rid >> 6);
    const int beg = offs[row];
    const int n = cnts[row];
    const long long co = (long long)c0 + (lane << 2);
    float4 acc = make_float4(0.f, 0.f, 0.f, 0.f);
    int j = 0;
    if (xp) {
        for (; j + 4 <= n; j += 4) {
            const int n0 = elist[beg + j], n1 = elist[beg + j + 1];
            const int n2 = elist[beg + j + 2], n3 = elist[beg + j + 3];
            const uint4 u0 = *(const uint4*)&xp[(long long)n0 * Fx + co];
            const uint4 u1 = *(const uint4*)&xp[(long long)n1 * Fx + co];
            const uint4 u2 = *(const uint4*)&xp[(long long)n2 * Fx + co];
            const uint4 u3 = *(const uint4*)&xp[(long long)n3 * Fx + co];
            addpk(acc, u0); addpk(acc, u1); addpk(acc, u2); addpk(acc, u3);
        }
        for (; j < n; ++j)
            addpk(acc, *(const uint4*)&xp[(long long)elist[beg + j] * Fx + co]);
    } else {
        for (; j + 4 <= n; j += 4) {
            const int n0 = elist[beg + j], n1 = elist[beg + j + 1];
            const int n2 = elist[beg + j + 2], n3 = elist[beg + j + 3];
            const float4 v0 = *(const float4*)&xf[(long long)n0 * Fx + co];
            const float4 v1 = *(const float4*)&xf[(long long)n1 * Fx + co];
            const float4 v2 = *(const float4*)&xf[(long long)n2 * Fx + co];
            const float4 v3 = *(const float4*)&xf[(long long)n3 * Fx + co];
            acc.x += v0.x + v1.x + v2.x + v3.x;
            acc.y += v0.y + v1.y + v2.y + v3.y;
            acc.z += v0.z + v1.z + v2.z + v3.z;
            acc.w += v0.w + v1.w + v2.w + v3.w;
        }
        for (; j < n; ++j) {
            const float4 v = *(const float4*)&xf[(long long)elist[beg + j] * Fx + co];
            acc.x += v.x; acc.y += v.y; acc.z += v.z; acc.w += v.w;
        }
    }
    uint4 pk;
    pk.x = f2pk(acc.x); pk.y = f2pk(acc.y); pk.z = f2pk(acc.z); pk.w = f2pk(acc.w);
    *(uint4*)&opk[(long long)row * Fx + co] = pk;
}

// ---------------- all 7 weight converts in ONE launch -------------------------------------
struct WSpec {
    const float* w1; const float* w2; int K1; int K2; int Nn;
    unsigned short* oh; unsigned short* ol;
};

__global__ void wconv_all(WSpec s0, WSpec s1, WSpec s2, WSpec s3, WSpec s4, WSpec s5, WSpec s6) {
    WSpec s;
    switch (blockIdx.y) {
        case 0: s = s0; break; case 1: s = s1; break; case 2: s = s2; break;
        case 3: s = s3; break; case 4: s = s4; break; case 5: s = s5; break;
        default: s = s6; break;
    }
    int idx = blockIdx.x * 256 + threadIdx.x;
    int Kt = s.K1 + s.K2;
    if (idx >= s.Nn * Kt) return;
    int n = idx / Kt, k = idx - n * Kt;
    float v = (k < s.K1) ? s.w1[(long long)k * s.Nn + n] : s.w2[(long long)(k - s.K1) * s.Nn + n];
    unsigned short h = f2bf(v);
    s.oh[idx] = h;
    s.ol[idx] = f2bf(v - __uint_as_float((unsigned int)h << 16));
}

// ---------------- staging (hi at base, lo at base+TSZ) ------------------------------------
__device__ inline void stageN_split(const float* __restrict__ src, int ldk, int k0,
                                    short* lds, int tid) {
    const int r = tid >> 2, kq = (tid & 3) << 3;
    const float* p = src + (long long)r * ldk + k0 + kq;
    float v[8];
    *(float4*)v = *(const float4*)p;
    *(float4*)(v + 4) = *(const float4*)(p + 4);
    s16x8 hv, lv;
    #pragma unroll
    for (int i = 0; i < 8; ++i) {
        unsigned short h = f2bf(v[i]);
        float hf = __uint_as_float((unsigned int)h << 16);
        hv[i] = (short)h;
        lv[i] = (short)f2bf(v[i] - hf);
    }
    *(s16x8*)(lds + r * 40 + kq) = hv;
    *(s16x8*)(lds + TSZ + r * 40 + kq) = lv;
}

__device__ inline void stageN_pk(const unsigned int* __restrict__ src, int ldk, int k0,
                                 short* lds, int tid) {
    const int r = tid >> 2, kq = (tid & 3) << 3;
    const unsigned int* p = src + (long long)r * ldk + k0 + kq;
    uint4 a = *(const uint4*)p;
    uint4 b = *(const uint4*)(p + 4);
    uint4 hw, lw;
    hw.x = (a.x & 0xffffu) | (a.y << 16);
    hw.y = (a.z & 0xffffu) | (a.w << 16);
    hw.z = (b.x & 0xffffu) | (b.y << 16);
    hw.w = (b.z & 0xffffu) | (b.w << 16);
    lw.x = (a.x >> 16) | (a.y & 0xffff0000u);
    lw.y = (a.z >> 16) | (a.w & 0xffff0000u);
    lw.z = (b.x >> 16) | (b.y & 0xffff0000u);
    lw.w = (b.z >> 16) | (b.w & 0xffff0000u);
    *(uint4*)(lds + r * 40 + kq) = hw;
    *(uint4*)(lds + TSZ + r * 40 + kq) = lw;
}

__device__ inline void stageT_pk(const unsigned int* __restrict__ P,
                                 int ldm, int k0, int m0, short* lds, int tid) {
    const int kp = tid >> 4, mc = tid & 15;
    const int k = kp << 1;
    const unsigned int* p0 = P + (long long)(k0 + k) * ldm + m0 + mc;
    const unsigned int* p1 = p0 + ldm;
    #pragma unroll
    for (int i = 0; i < 4; ++i) {
        unsigned int e0 = p0[i << 4], e1 = p1[i << 4];
        const int o = (mc + (i << 4)) * 40 + k;
        *(unsigned int*)(lds + o) = (e0 & 0xffffu) | (e1 << 16);
        *(unsigned int*)(lds + o + TSZ) = (e0 >> 16) | (e1 & 0xffff0000u);
    }
}

__device__ inline void stageW_split(const unsigned short* __restrict__ wh,
                                    const unsigned short* __restrict__ wl, int ldk,
                                    int n0, int k0, short* lds, int tid) {
    const int r = tid >> 2, kq = (tid & 3) << 3;
    *(s16x8*)(lds + r * 40 + kq) = *(const s16x8*)(wh + (long long)(n0 + r) * ldk + k0 + kq);
    *(s16x8*)(lds + TSZ + r * 40 + kq) = *(const s16x8*)(wl + (long long)(n0 + r) * ldk + k0 + kq);
}

// reg-staged double-buffer helpers (scattered transposed loads)
__device__ inline void loadT8(const unsigned int* __restrict__ P, int ldm, int k0, int m0,
                              int tid, unsigned int (&r)[8]) {
    const int kp = tid >> 4, mc = tid & 15;
    const int k = kp << 1;
    const unsigned int* p0 = P + (long long)(k0 + k) * ldm + m0 + mc;
    const unsigned int* p1 = p0 + ldm;
    #pragma unroll
    for (int i = 0; i < 4; ++i) { r[i] = p0[i << 4]; r[4 + i] = p1[i << 4]; }
}
__device__ inline void storeT8(short* lds, int tid, const unsigned int (&r)[8]) {
    const int kp = tid >> 4, mc = tid & 15;
    const int k = kp << 1;
    #pragma unroll
    for (int i = 0; i < 4; ++i) {
        unsigned int e0 = r[i], e1 = r[4 + i];
        const int o = (mc + (i << 4)) * 40 + k;
        *(unsigned int*)(lds + o) = (e0 & 0xffffu) | (e1 << 16);
        *(unsigned int*)(lds + o + TSZ) = (e0 >> 16) | (e1 & 0xffff0000u);
    }
}
__device__ inline void storeT8_hi(short* lds, int tid, const unsigned int (&r)[8]) {
    const int kp = tid >> 4, mc = tid & 15;
    const int k = kp << 1;
    #pragma unroll
    for (int i = 0; i < 4; ++i)
        *(unsigned int*)(lds + (mc + (i << 4)) * 40 + k) =
            (r[i] & 0xffffu) | (r[4 + i] << 16);
}

__device__ inline void mfma_split(const short* As, const short* Bs, int wm, int wn,
                                  int l15, int quad, f32x4 (&acc)[2][2]) {
    const int ko = quad << 3;
    s16x8 ah[2], al[2], bh[2], bl[2];
    #pragma unroll
    for (int i = 0; i < 2; ++i) {
        const int ra = (wm + (i << 4) + l15) * 40 + ko;
        const int rb = (wn + (i << 4) + l15) * 40 + ko;
        ah[i] = *(const s16x8*)&As[ra];
        al[i] = *(const s16x8*)&As[TSZ + ra];
        bh[i] = *(const s16x8*)&Bs[rb];
        bl[i] = *(const s16x8*)&Bs[TSZ + rb];
    }
    #pragma unroll
    for (int mi = 0; mi < 2; ++mi)
    #pragma unroll
    for (int ni = 0; ni < 2; ++ni) {
        f32x4 c = acc[mi][ni];
        c = __builtin_amdgcn_mfma_f32_16x16x32_bf16(ah[mi], bh[ni], c, 0, 0, 0);
        c = __builtin_amdgcn_mfma_f32_16x16x32_bf16(ah[mi], bl[ni], c, 0, 0, 0);
        c = __builtin_amdgcn_mfma_f32_16x16x32_bf16(al[mi], bh[ni], c, 0, 0, 0);
        acc[mi][ni] = c;
    }
}

__device__ inline void mfma_hi(const short* As, const short* Bs, int wm, int wn,
                               int l15, int quad, f32x4 (&acc)[2][2]) {
    const int ko = quad << 3;
    s16x8 ah[2], bh[2];
    #pragma unroll
    for (int i = 0; i < 2; ++i) {
        ah[i] = *(const s16x8*)&As[(wm + (i << 4) + l15) * 40 + ko];
        bh[i] = *(const s16x8*)&Bs[(wn + (i << 4) + l15) * 40 + ko];
    }
    #pragma unroll
    for (int mi = 0; mi < 2; ++mi)
    #pragma unroll
    for (int ni = 0; ni < 2; ++ni)
        acc[mi][ni] = __builtin_amdgcn_mfma_f32_16x16x32_bf16(ah[mi], bh[ni], acc[mi][ni], 0, 0, 0);
}

// ---------------- G1: flat C = op([A1|A2] @ Wt^T + bias), direct staging ------------------
__global__ __launch_bounds__(256) void gemm_aw(
    const unsigned int* __restrict__ A1p, const float* __restrict__ A1f, int K1,
    const unsigned int* __restrict__ A2p, const float* __restrict__ A2f, int K2,
    const unsigned short* __restrict__ Wh, const unsigned short* __restrict__ Wl,
    const float* __restrict__ bias, float* __restrict__ C,
    unsigned int* __restrict__ Cpk,
    int Nn, int doRelu)
{
    __shared__ short As[2 * TSZ], Bs[2 * TSZ];
    const int m0 = blockIdx.y << 6, n0 = blockIdx.x << 6;
    const int tid = threadIdx.x, lane = tid & 63, wv = tid >> 6;
    const int l15 = lane & 15, quad = lane >> 4;
    const int wm = (wv & 1) << 5, wn = (wv >> 1) << 5;
    f32x4 acc[2][2] = {};
    const int Kt = K1 + K2;
    for (int k0 = 0; k0 < Kt; k0 += 32) {
        if (k0 < K1) {
            if (A1p) stageN_pk(A1p + (long long)m0 * K1, K1, k0, As, tid);
            else     stageN_split(A1f + (long long)m0 * K1, K1, k0, As, tid);
        } else {
            if (A2p) stageN_pk(A2p + (long long)m0 * K2, K2, k0 - K1, As, tid);
            else     stageN_split(A2f + (long long)m0 * K2, K2, k0 - K1, As, tid);
        }
        stageW_split(Wh, Wl, Kt, n0, k0, Bs, tid);
        __syncthreads();
        mfma_split(As, Bs, wm, wn, l15, quad, acc);
        __syncthreads();
    }
    #pragma unroll
    for (int mi = 0; mi < 2; ++mi)
    #pragma unroll
    for (int ni = 0; ni < 2; ++ni) {
        const int col = n0 + wn + (ni << 4) + l15;
        const float bv = bias ? bias[col] : 0.f;
        #pragma unroll
        for (int r = 0; r < 4; ++r) {
            const int row = m0 + wm + (mi << 4) + (quad << 2) + r;
            float v = acc[mi][ni][r] + bv;
            if (doRelu) v = fmaxf(v, 0.f);
            if (C)   C[(long long)row * Nn + col] = v;
            if (Cpk) Cpk[(long long)row * Nn + col] = f2pk(v);
        }
    }
}

// ---------------- G2: batched C = A^T B, TWO jobs per launch, reg double-buffered ---------
// adj jobs additionally emit per-row col-sums (atomics) and the diagonal -> single-pass norm
struct TTSet {
    const unsigned int* Bp;
    float* C; unsigned int* Cpk; float* fro;
    int Nn; int dual;
    long long sB, sC;
    float* rsum; float* rdiag;      // per-row stats (adj jobs only), size NGRAPH*Nn
};

__global__ __launch_bounds__(256) void gemm_tt(
    const unsigned int* __restrict__ Ap, int Kd, int Mm, long long sA,
    int zsplit, TTSet t0, TTSet t1)
{
    __shared__ short As[2 * TSZ], Bs[2 * TSZ], A2s[TSZ];
    __shared__ float redf[4];
    const int z = blockIdx.x;
    int nz = blockIdx.z;
    const TTSet tt = (nz < zsplit) ? t0 : t1;
    if (blockIdx.z >= zsplit) nz -= zsplit;
    const unsigned int* Apz = Ap + (long long)z * sA;
    const unsigned int* Bpz = tt.Bp + (long long)z * tt.sB;
    const int m0 = blockIdx.y << 6, n0 = nz << 6;
    const int tid = threadIdx.x, lane = tid & 63, wv = tid >> 6;
    const int l15 = lane & 15, quad = lane >> 4;
    const int wm = (wv & 1) << 5, wn = (wv >> 1) << 5;
    const int fw = tt.dual ? ((m0 < n0) ? 2 : ((m0 == n0) ? 1 : 0)) : 0;
    f32x4 acc[2][2] = {};
    f32x4 accA[2][2] = {};
    unsigned int ra[8], rb[8], rh[8];
    loadT8(Apz, Mm, 0, m0, tid, ra);
    loadT8(Bpz, tt.Nn, 0, n0, tid, rb);
    if (fw) loadT8(Apz, Mm, 0, n0, tid, rh);
    for (int k0 = 0; k0 < Kd; k0 += 32) {
        storeT8(As, tid, ra);
        storeT8(Bs, tid, rb);
        if (fw) storeT8_hi(A2s, tid, rh);
        __syncthreads();
        const int kn = k0 + 32;
        if (kn < Kd) {
            loadT8(Apz, Mm, kn, m0, tid, ra);
            loadT8(Bpz, tt.Nn, kn, n0, tid, rb);
            if (fw) loadT8(Apz, Mm, kn, n0, tid, rh);
        }
        mfma_split(As, Bs, wm, wn, l15, quad, acc);
        if (fw) mfma_hi(As, A2s, wm, wn, l15, quad, accA);
        __syncthreads();
    }
    float* Cp = tt.C ? tt.C + (long long)z * tt.sC : nullptr;
    unsigned int* Ckp = tt.Cpk ? tt.Cpk + (long long)z * tt.sC : nullptr;
    #pragma unroll
    for (int mi = 0; mi < 2; ++mi)
    #pragma unroll
    for (int ni = 0; ni < 2; ++ni) {
        const int col = n0 + wn + (ni << 4) + l15;
        #pragma unroll
        for (int r = 0; r < 4; ++r) {
            const int row = m0 + wm + (mi << 4) + (quad << 2) + r;
            const float v = acc[mi][ni][r];
            if (Cp)  Cp[(long long)row * tt.Nn + col] = v;
            if (Ckp) Ckp[(long long)row * tt.Nn + col] = f2pk(v);
        }
    }
    if (tt.rsum) {
        // per-row partial sums of this wave's 32-column slice; 16-lane (l15) reduce
        #pragma unroll
        for (int mi = 0; mi < 2; ++mi) {
            #pragma unroll
            for (int r = 0; r < 4; ++r) {
                float rs = acc[mi][0][r] + acc[mi][1][r];
                rs += __shfl_xor(rs, 1);
                rs += __shfl_xor(rs, 2);
                rs += __shfl_xor(rs, 4);
                rs += __shfl_xor(rs, 8);
                if (l15 == 0) {
                    const int row = m0 + wm + (mi << 4) + (quad << 2) + r;
                    atomicAdd(&tt.rsum[z * tt.Nn + row], rs);
                }
            }
        }
        // diagonal (only blocks on the diagonal hold it); unique thread per element
        if (tt.rdiag && m0 == n0) {
            #pragma unroll
            for (int mi = 0; mi < 2; ++mi)
            #pragma unroll
            for (int ni = 0; ni < 2; ++ni)
            #pragma unroll
            for (int r = 0; r < 4; ++r) {
                const int rr = wm + (mi << 4) + (quad << 2) + r;
                const int cc = wn + (ni << 4) + l15;
                if (rr == cc) tt.rdiag[z * tt.Nn + m0 + rr] = acc[mi][ni][r];
            }
        }
    }
    if (fw) {
        float s = 0.f;
        #pragma unroll
        for (int mi = 0; mi < 2; ++mi)
        #pragma unroll
        for (int ni = 0; ni < 2; ++ni)
        #pragma unroll
        for (int r = 0; r < 4; ++r) s += accA[mi][ni][r] * accA[mi][ni][r];
        s *= (float)fw;
        for (int off = 32; off; off >>= 1) s += __shfl_xor(s, off);
        if (lane == 0) redf[wv] = s;
        __syncthreads();
        if (tid == 0) atomicAdd(&tt.fro[z], redf[0] + redf[1] + redf[2] + redf[3]);
    }
}

// ---------------- G3: batched C = A @ B; A direct, B reg-prefetched; rscale epilogue ------
__global__ __launch_bounds__(256) void gemm_nt(
    const unsigned short* __restrict__ Ah, const unsigned short* __restrict__ Al,
    const unsigned int* __restrict__ Bp,
    float* __restrict__ C, unsigned int* __restrict__ Cpk,
    const float* __restrict__ rscale, int rsn,
    int Kd, int Nn, long long sA, long long sB, long long sC)
{
    __shared__ short As[2 * TSZ], Bs[2 * TSZ];
    const int z = blockIdx.x;
    const int m0 = blockIdx.y << 6, n0 = blockIdx.z << 6;
    const unsigned short* Aph = Ah + (long long)z * sA;
    const unsigned short* Apl = Al + (long long)z * sA;
    const unsigned int* Bpz = Bp + (long long)z * sB;
    const int tid = threadIdx.x, lane = tid & 63, wv = tid >> 6;
    const int l15 = lane & 15, quad = lane >> 4;
    const int wm = (wv & 1) << 5, wn = (wv >> 1) << 5;
    f32x4 acc[2][2] = {};
    unsigned int rb[8];
    loadT8(Bpz, Nn, 0, n0, tid, rb);
    for (int k0 = 0; k0 < Kd; k0 += 32) {
        stageW_split(Aph, Apl, Kd, m0, k0, As, tid);   // row-major pre-split A: pure 16B copies
        storeT8(Bs, tid, rb);
        __syncthreads();
        const int kn = k0 + 32;
        if (kn < Kd) loadT8(Bpz, Nn, kn, n0, tid, rb);
        mfma_split(As, Bs, wm, wn, l15, quad, acc);
        __syncthreads();
    }
    #pragma unroll
    for (int mi = 0; mi < 2; ++mi)
    #pragma unroll
    for (int ni = 0; ni < 2; ++ni) {
        const int col = n0 + wn + (ni << 4) + l15;
        #pragma unroll
        for (int r = 0; r < 4; ++r) {
            const int row = m0 + wm + (mi << 4) + (quad << 2) + r;
            float v = acc[mi][ni][r];
            if (rscale) v *= rscale[z * rsn + row];
            if (C)   C[(long long)z * sC + (long long)row * Nn + col] = v;
            if (Cpk) Cpk[(long long)z * sC + (long long)row * Nn + col] = f2pk(v);
        }
    }
}

// ---------------- softmax rows: per-wave row, per-row partials (NO contended atomics) -----
__global__ __launch_bounds__(256) void softmax_rows_wave(
    const float* __restrict__ sm, int L,
    const float* __restrict__ deg,
    float* __restrict__ rowq2, float* __restrict__ rowdq2, int totRows,
    unsigned int* __restrict__ opk)
{
    const int wid = (blockIdx.x * 256 + threadIdx.x) >> 6;
    const int lane = threadIdx.x & 63;
    if (wid >= totRows) return;
    const float* rowp = sm + (long long)wid * L;
    const int nv = L >> 6;
    float v[4];
    if (nv == 4) {
        float4 t = *(const float4*)&rowp[lane << 2];
        v[0] = t.x; v[1] = t.y; v[2] = t.z; v[3] = t.w;
    } else {
        float2 t = *(const float2*)&rowp[lane << 1];
        v[0] = t.x; v[1] = t.y;
    }
    float mx = v[0];
    for (int i = 1; i < nv; ++i) mx = fmaxf(mx, v[i]);
    for (int off = 32; off; off >>= 1) mx = fmaxf(mx, __shfl_xor(mx, off));
    float s = 0.f;
    for (int i = 0; i < nv; ++i) { v[i] = expf(v[i] - mx); s += v[i]; }
    for (int off = 32; off; off >>= 1) s += __shfl_xor(s, off);
    const float inv = 1.f / s;
    float q2 = 0.f;
    for (int i = 0; i < nv; ++i) { float p = v[i] * inv; v[i] = p; q2 += p * p; }
    const long long rb = (long long)wid * L;
    if (nv == 4) {
        uint4 pk;
        pk.x = f2pk(v[0]); pk.y = f2pk(v[1]); pk.z = f2pk(v[2]); pk.w = f2pk(v[3]);
        *(uint4*)&opk[rb + (lane << 2)] = pk;
    } else {
        uint2 pk;
        pk.x = f2pk(v[0]); pk.y = f2pk(v[1]);
        *(uint2*)&opk[rb + (lane << 1)] = pk;
    }
    for (int off = 32; off; off >>= 1) q2 += __shfl_xor(q2, off);
    if (lane == 0) { rowq2[wid] = q2; rowdq2[wid] = deg[wid] * q2; }
}

__global__ __launch_bounds__(256) void reduce2_pergraph(
    const float* __restrict__ a, const float* __restrict__ b, int rowsPerGraph,
    float* __restrict__ outA, float* __restrict__ outB)
{
    __shared__ float redA[4], redB[4];
    const int g = blockIdx.x, t = threadIdx.x;
    float sa = 0.f, sb = 0.f;
    for (int i = t; i < rowsPerGraph; i += 256) {
        sa += a[g * rowsPerGraph + i];
        if (b) sb += b[g * rowsPerGraph + i];
    }
    for (int off = 32; off; off >>= 1) { sa += __shfl_xor(sa, off); sb += __shfl_xor(sb, off); }
    const int wv = t >> 6;
    if ((t & 63) == 0) { redA[wv] = sa; redB[wv] = sb; }
    __syncthreads();
    if (t == 0) {
        outA[g] = redA[0] + redA[1] + redA[2] + redA[3];
        if (outB) outB[g] = redB[0] + redB[1] + redB[2] + redB[3];
    }
}

// ---------------- SINGLE-PASS adjnorm: dpool from precomputed rsum/rdiag ------------------
__global__ __launch_bounds__(1024) void adjnorm(
    const float* __restrict__ adj, int K,
    const float* __restrict__ rsumIn, const float* __restrict__ rdiagIn,
    float* __restrict__ trace_out,
    float* __restrict__ rowsum, float* __restrict__ rscale,
    unsigned short* __restrict__ oh, unsigned short* __restrict__ ol)
{
    __shared__ float dpoolL[256];
    __shared__ float redt[16];
    const int g = blockIdx.x, tid = threadIdx.x;
    const int wv = tid >> 6, lane = tid & 63;
    float trp = 0.f;
    for (int r = tid; r < K; r += 1024) {
        float dv = rdiagIn[g * K + r];
        dpoolL[r] = sqrtf(rsumIn[g * K + r] - dv) + 1e-15f;
        trp += dv;
    }
    for (int off = 32; off; off >>= 1) trp += __shfl_xor(trp, off);
    if (lane == 0) redt[wv] = trp;
    __syncthreads();
    if (tid == 0) {
        float t = 0.f;
        #pragma unroll
        for (int i = 0; i < 16; ++i) t += redt[i];
        trace_out[g] = t;
    }
    const int rowsPerWave = K >> 4;   // 16 waves
    const int nv = K >> 6;
    for (int rr = 0; rr < rowsPerWave; ++rr) {
        const int r = wv * rowsPerWave + rr;
        const int wid = g * K + r;
        const float* rowp = adj + (long long)wid * K;
        const float inv_r = 1.f / dpoolL[r];
        float s = 0.f;
        for (int q = 0; q < nv; ++q) {
            int c = lane + (q << 6);
            float a = rowp[c];
            if (c == r) a = 0.f;
            float v = a * inv_r / dpoolL[c];
            s += v;
            unsigned short h = f2bf(v);
            oh[(long long)wid * K + c] = h;
            ol[(long long)wid * K + c] = f2bf(v - bf2f(h));
        }
        for (int off = 32; off; off >>= 1) s += __shfl_xor(s, off);
        if (lane == 0) { rowsum[wid] = s; rscale[wid] = 1.f / fmaxf(s, 1.f); }
    }
}

// ---------------- fused topk v2: score/rank/select + gather-gate + readout + CSR build ----
// Block g owns graph g entirely: new_id lives in LDS; remap+count+scan+fill of the graph's
// EPG edges happens block-locally (edges are intra-graph by construction).
__global__ __launch_bounds__(512) void topk_fused(
    const float* __restrict__ x, const float* __restrict__ p, int n, int k,
    float* __restrict__ outx, float* __restrict__ sxsum,
    const int* __restrict__ sIn, const int* __restrict__ dIn, const float* __restrict__ mIn,
    int* __restrict__ sOut, int* __restrict__ dOut, float* __restrict__ mOut,
    int* __restrict__ elist, int* __restrict__ offs, int* __restrict__ cnts)
{
    __shared__ float sc[512];
    __shared__ int pref[512];
    __shared__ int   selL[256];
    __shared__ float gateL[256];
    __shared__ float red[1024];
    __shared__ int   nidL[512];
    __shared__ int   cntL[256];
    __shared__ int   curL[256];
    const int g = blockIdx.x, tid = threadIdx.x;
    float myScore = 0.f;
    if (tid < n) {
        const float* xr = x + (long long)(g * n + tid) * 128;
        float pn2 = 0.f, d = 0.f;
        #pragma unroll 4
        for (int f = 0; f < 128; f += 4) {
            float4 pv = *(const float4*)&p[f];
            float4 v = *(const float4*)&xr[f];
            pn2 += pv.x * pv.x + pv.y * pv.y + pv.z * pv.z + pv.w * pv.w;
            d += v.x * pv.x + v.y * pv.y + v.z * pv.z + v.w * pv.w;
        }
        myScore = d / (sqrtf(pn2) + 1e-16f);
        sc[tid] = myScore;
    }
    __syncthreads();
    int keep = 0;
    if (tid < n) {
        const float si = myScore;
        int rank = 0;
        for (int j = 0; j < n; j += 4) {
            float4 s4 = *(const float4*)&sc[j];
            rank += (s4.x > si) || (s4.x == si && (j + 0) < tid);
            rank += (s4.y > si) || (s4.y == si && (j + 1) < tid);
            rank += (s4.z > si) || (s4.z == si && (j + 2) < tid);
            rank += (s4.w > si) || (s4.w == si && (j + 3) < tid);
        }
        keep = rank < k;
    }
    pref[tid] = keep;
    __syncthreads();
    for (int d = 1; d < 512; d <<= 1) {
        int u = (tid >= d) ? pref[tid - d] : 0;
        __syncthreads();
        pref[tid] += u;
        __syncthreads();
    }
    {
        int nid = -1;
        if (tid < n && keep) {
            int pos = pref[tid] - 1;
            nid = g * k + pos;
            selL[pos] = g * n + tid;
            gateL[pos] = tanhf(myScore);
        }
        nidL[tid] = nid;
    }
    __syncthreads();
    // gather + gate + per-graph readout (max / mean)
    const int f = tid & 127, grp = tid >> 7;     // 4 row-groups x 128 features
    float mx = -INFINITY, sm = 0.f;
    for (int r = grp; r < k; r += 4) {
        float v = x[(long long)selL[r] * 128 + f] * gateL[r];
        outx[(long long)(g * k + r) * 128 + f] = v;
        mx = fmaxf(mx, v); sm += v;
    }
    red[grp * 128 + f] = mx;
    red[512 + grp * 128 + f] = sm;
    __syncthreads();
    if (tid < 128) {
        float m = fmaxf(fmaxf(red[f], red[128 + f]), fmaxf(red[256 + f], red[384 + f]));
        float s2 = red[512 + f] + red[640 + f] + red[768 + f] + red[896 + f];
        sxsum[g * 256 + f] += m;
        sxsum[g * 256 + 128 + f] += s2 / k;
    }
    // ---- block-local edge remap + count + scan + CSR fill ----
    if (sIn) {
        if (tid < k) cntL[tid] = 0;
        __syncthreads();
        const int e0 = g * EPG;
        for (int e = e0 + tid; e < e0 + EPG; e += 512) {
            bool vin = mIn ? (mIn[e] > 0.f) : true;
            int ns = -1, nd = -1;
            if (vin) {
                ns = nidL[sIn[e] - g * n];
                nd = nidL[dIn[e] - g * n];
            }
            bool v = (ns >= 0) && (nd >= 0);
            sOut[e] = v ? ns : 0;
            dOut[e] = v ? nd : 0;
            mOut[e] = v ? 1.f : 0.f;
            if (v) atomicAdd(&cntL[nd - g * k], 1);
        }
        __syncthreads();
        int c = (tid < k) ? cntL[tid] : 0;
        pref[tid] = c;
        __syncthreads();
        for (int d = 1; d < 512; d <<= 1) {
            int u = (tid >= d) ? pref[tid - d] : 0;
            __syncthreads();
            pref[tid] += u;
            __syncthreads();
        }
        if (tid < k) {
            int o = pref[tid] - c;     // exclusive prefix (local)
            offs[g * k + tid] = e0 + o;
            cnts[g * k + tid] = c;
            curL[tid] = o;
        }
        __syncthreads();
        for (int e = e0 + tid; e < e0 + EPG; e += 512) {
            bool vin = mIn ? (mIn[e] > 0.f) : true;
            int ns = -1, nd = -1;
            if (vin) {
                ns = nidL[sIn[e] - g * n];
                nd = nidL[dIn[e] - g * n];
            }
            if (ns >= 0 && nd >= 0) {
                int p_ = atomicAdd(&curL[nd - g * k], 1);
                elist[e0 + p_] = ns;
            }
        }
    }
}

// final head: mean_lin fused + mc/o scalar epilogue in block 0
__global__ void final_head(const float* __restrict__ sxsum, const float* __restrict__ w11,
                           const float* __restrict__ b11,
                           const float* __restrict__ xd2, const float* __restrict__ l1w,
                           const float* __restrict__ l1b,
                           const float* __restrict__ w2, const float* __restrict__ b2,
                           const float* __restrict__ accs, float* __restrict__ out) {
    __shared__ float meanv[128];
    __shared__ float sin_[256];
    __shared__ float cat[256];
    __shared__ float rm[2], ro[2];
    int b = blockIdx.x, t = threadIdx.x; // 128
    {
        float s = 0.f;
        for (int n = 0; n < 128; n++) s += xd2[(long long)(b * 128 + n) * 128 + t];
        meanv[t] = s / 128.f;
    }
    if (b == 0) {
        int wvi = t >> 6, lane = t & 63;
        const float* acc = accs + wvi * 256;
        float sqrtk = wvi ? sqrtf(128.f) : 16.f;
        float numv = acc[lane], denv = acc[64 + lane], trv = acc[128 + lane], frov = acc[192 + lane];
        float mcb = numv / (denv + 1e-15f);
        float ssn = sqrtf(frov) + 1e-15f;
        float ob = sqrtf(fmaxf(frov / (ssn * ssn) - 2.f * trv / (ssn * sqrtk) + 1.f, 0.f));
        for (int off = 32; off; off >>= 1) { mcb += __shfl_down(mcb, off); ob += __shfl_down(ob, off); }
        if (lane == 0) { rm[wvi] = mcb; ro[wvi] = ob; }
        __syncthreads();
        if (t == 0) {
            out[640] = -(rm[0] + rm[1]) / 64.f;
            out[641] = (ro[0] + ro[1]) / 64.f;
        }
    }
    sin_[t] = sxsum[b * 256 + t];
    sin_[t + 128] = sxsum[b * 256 + 128 + t];
    __syncthreads();
    float acc = b11[t];
    for (int i = 0; i < 256; i++) acc += sin_[i] * w11[i * 128 + t];
    cat[t] = fmaxf(acc, 0.f);
    float xga = l1b[t];
    for (int i = 0; i < 128; i++) xga += meanv[i] * l1w[i * 128 + t];
    cat[128 + t] = fmaxf(xga, 0.f);
    __syncthreads();
    if (t < 10) {
        float a = b2[t];
        for (int i = 0; i < 256; i++) a += cat[i] * w2[i * 10 + t];
        out[b * 10 + t] = a;
    }
}

// ------------------------------------------------------------------------------------------
extern "C" void kernel_launch(void* const* d_in, const int* in_sizes, int n_in,
                              void* d_out, int out_size, void* d_ws, size_t ws_size,
                              hipStream_t stream) {
    const float* x         = (const float*)d_in[0];
    const int*   src       = (const int*)d_in[1];
    const int*   dst       = (const int*)d_in[2];
    const float* conv0_wr  = (const float*)d_in[3];
    const float* conv0_wrt = (const float*)d_in[4];
    const float* conv0_b   = (const float*)d_in[5];
    const float* sc2_wr    = (const float*)d_in[6];
    const float* sc2_wrt   = (const float*)d_in[7];
    const float* sc2_b     = (const float*)d_in[8];
    const float* sc3_wr    = (const float*)d_in[9];
    const float* sc3_wrt   = (const float*)d_in[10];
    const float* sc3_b     = (const float*)d_in[11];
    const float* sg1_wr    = (const float*)d_in[12];
    const float* sg1_wrt   = (const float*)d_in[13];
    const float* sg1_b     = (const float*)d_in[14];
    const float* sg2_wr    = (const float*)d_in[15];
    const float* sg2_wrt   = (const float*)d_in[16];
    const float* sg2_b     = (const float*)d_in[17];
    const float* pool0_w   = (const float*)d_in[18];
    const float* pool0_b   = (const float*)d_in[19];
    const float* pool1_w   = (const float*)d_in[20];
    const float* pool1_b   = (const float*)d_in[21];
    const float* p1        = (const float*)d_in[22];
    const float* p2        = (const float*)d_in[23];
    const float* p3        = (const float*)d_in[24];
    const float* l11_w     = (const float*)d_in[25];
    const float* l11_b     = (const float*)d_in[26];
    const float* l1_w      = (const float*)d_in[27];
    const float* l1_b      = (const float*)d_in[28];
    const float* l2_w      = (const float*)d_in[29];
    const float* l2_b      = (const float*)d_in[30];
    float* out = (float*)d_out;

    char* w = (char*)d_ws;
    const unsigned long long MBy = 1ull << 20;
    float* x0    = (float*)(w + 0);           // 16 MB
    float* BIG1  = (float*)(w + 16 * MBy);    // 32 MB
    float* BIG2  = (float*)(w + 48 * MBy);    // 32 MB
    float* agg   = (float*)(w + 80 * MBy);    // 16 MB
    float* adj1  = (float*)(w + 104 * MBy);   // 16 MB
    int*   s1    = (int*)(w + 120 * MBy);
    int*   d1    = (int*)(w + 122 * MBy);
    float* m1    = (float*)(w + 124 * MBy);
    int*   s2e   = (int*)(w + 126 * MBy);
    int*   d2e   = (int*)(w + 128 * MBy);
    float* m2e   = (float*)(w + 130 * MBy);
    char*  misc  = w + 132 * MBy;
    float* rowq2  = (float*)(misc);                 // 128 KB (32768 f32)
    float* rowdq2 = (float*)(misc + 128 * 1024);    // 128 KB
    float* deg   = (float*)(misc + 384 * 1024);
    float* rowsum2 = (float*)(misc + 576 * 1024);
    float* rscale2 = (float*)(misc + 640 * 1024);
    float* rowsum3 = (float*)(misc + 736 * 1024);
    float* rscale3 = (float*)(misc + 768 * 1024);
    float* accs    = (float*)(misc + 800 * 1024);
    float* sxsum   = (float*)(misc + 900 * 1024);

    unsigned short* wt_sg1h   = (unsigned short*)(misc + 1024 * 1024);
    unsigned short* wt_sg1l   = wt_sg1h + 32768;
    unsigned short* wt_sg2h   = wt_sg1l + 32768;
    unsigned short* wt_sg2l   = wt_sg2h + 32768;
    unsigned short* wt_pool0h = wt_sg2l + 32768;
    unsigned short* wt_pool0l = wt_pool0h + 32768;
    unsigned short* wt_pool1h = wt_pool0l + 32768;
    unsigned short* wt_pool1l = wt_pool1h + 32768;
    unsigned short* wt_c0h    = wt_pool1l + 32768;
    unsigned short* wt_c0l    = wt_c0h + 32768;
    unsigned short* wt_sc2h   = wt_c0l + 32768;
    unsigned short* wt_sc2l   = wt_sc2h + 32768;
    unsigned short* wt_sc3h   = wt_sc2l + 32768;
    unsigned short* wt_sc3l   = wt_sc3h + 32768;

    // adj row stats (zeroed each iteration): rsum1+rdiag1 contiguous, rsum2+rdiag2 contiguous
    float* rsum1  = (float*)(misc + 2048 * 1024);   // 64 KB (64*256)
    float* rdiag1 = (float*)(misc + 2112 * 1024);   // 64 KB
    float* rsum2  = (float*)(misc + 2176 * 1024);   // 32 KB (64*128)
    float* rdiag2 = (float*)(misc + 2208 * 1024);   // 32 KB

    float* s_sm  = BIG1;                      // f32 softmax input (pre-softmax scores)
    unsigned int* Tbp = (unsigned int*)BIG2;  // phase A; dead after adj1 GEMM
    float* s2sm  = BIG2 + 4 * 1024 * 1024;                       // +16..24 MiB
    unsigned int* T2p = (unsigned int*)((char*)BIG2 + 24 * MBy); // +24..32 MiB
    float* adj2b = BIG1 + 1024 * 1024;
    float* xd2   = BIG1 + 2 * 1024 * 1024;
    float* sxA   = BIG1 + 3 * 1024 * 1024;
    float* sxE   = BIG1 + 5 * 1024 * 1024;
    float* sxB   = x0;
    float* sxC   = x0 + 2 * 1024 * 1024;
    float* sxD   = x0 + 3 * 1024 * 1024;

    // packed split-bf16 planes (region 136..244 MiB of the workspace)
    unsigned int* s_smp = (unsigned int*)(w + 136 * MBy);  // 32 MiB
    unsigned int* x0p   = (unsigned int*)(w + 168 * MBy);  // 16 MiB
    unsigned int* ox1p  = (unsigned int*)(w + 184 * MBy);  // 8 MiB
    unsigned int* xd1p  = (unsigned int*)(w + 192 * MBy);  // 8 MiB
    unsigned int* s2p   = (unsigned int*)(w + 200 * MBy);  // 8 MiB
    unsigned int* ox2p  = (unsigned int*)(w + 208 * MBy);  // 4 MiB
    unsigned short* a1h = (unsigned short*)(w + 212 * MBy); // 8 MiB
    unsigned short* a1l = (unsigned short*)(w + 220 * MBy); // 8 MiB
    unsigned short* a2h = (unsigned short*)(w + 228 * MBy); // 2 MiB
    unsigned short* a2l = (unsigned short*)(w + 230 * MBy); // 2 MiB
    unsigned int* AXp   = (unsigned int*)(w + 232 * MBy);  // 8 MiB
    unsigned int* AXp2  = (unsigned int*)(w + 240 * MBy);  // 4 MiB

    unsigned int* aggp  = (unsigned int*)agg;
    unsigned int* agg2p = (unsigned int*)agg;
    unsigned int* agg3p = (unsigned int*)agg;

    char* adjc = (char*)adj1;
    int* elA  = (int*)(adjc + 0);
    int* elB  = (int*)(adjc + 2 * MBy);
    int* cntA = (int*)(adjc + 4 * MBy);                  // 128 KB
    int* cntB = (int*)(adjc + 4 * MBy + 128 * 1024);     // contiguous -> one memset
    int* offA = (int*)(adjc + 4 * MBy + 256 * 1024);
    int* curA = (int*)(adjc + 4 * MBy + 384 * 1024);
    int* offB = (int*)(adjc + 4 * MBy + 512 * 1024);
    int* curB = (int*)(adjc + 4 * MBy + 640 * 1024);
    char* aggc = (char*)agg;
    int* elC  = (int*)(aggc + 8 * MBy);
    int* elD  = (int*)(aggc + 10 * MBy);
    int* cntC = (int*)(aggc + 12 * MBy);
    int* offC = (int*)(aggc + 12 * MBy + 256 * 1024);
    int* cntD = (int*)(aggc + 13 * MBy);
    int* offD = (int*)(aggc + 13 * MBy + 256 * 1024);

    hipMemsetAsync(accs, 0, 520 * sizeof(float), stream);
    hipMemsetAsync(sxsum, 0, 16384 * sizeof(float), stream);
    hipMemsetAsync(cntA, 0, 65536 * sizeof(int), stream);   // cntA + cntB
    hipMemsetAsync(rsum1, 0, 128 * 1024, stream);           // rsum1 + rdiag1
    hipMemsetAsync(rsum2, 0, 64 * 1024, stream);            // rsum2 + rdiag2

    {
        WSpec a{sg1_wr, sg1_wrt, 128, 128, 128, wt_sg1h, wt_sg1l};
        WSpec b{sg2_wr, sg2_wrt, 128, 128, 128, wt_sg2h, wt_sg2l};
        WSpec c{pool0_w, nullptr, 128, 0, 256, wt_pool0h, wt_pool0l};
        WSpec d{pool1_w, nullptr, 128, 0, 128, wt_pool1h, wt_pool1l};
        WSpec e{conv0_wr, conv0_wrt, 128, 128, 128, wt_c0h, wt_c0l};
        WSpec f{sc2_wr, sc2_wrt, 128, 128, 128, wt_sc2h, wt_sc2l};
        WSpec g{sc3_wr, sc3_wrt, 128, 128, 128, wt_sc3h, wt_sc3l};
        wconv_all<<<dim3(128, 7), 256, 0, stream>>>(a, b, c, d, e, f, g);
    }

    edge_count2<<<dim3(2048, 2), 256, 0, stream>>>(dst, cntA, src, cntB);
    scan_offsets2<<<dim3(64, 2), 512, 0, stream>>>(cntA, offA, curA, cntB, offB, curB, 512, deg);
    edge_fill2<<<dim3(2048, 2), 256, 0, stream>>>(dst, src, curA, elA, src, dst, curB, elB);

    // ---- conv0: gather (f32 in -> packed out), gemm emits x0 f32 (topk) + x0p packed ----
    gather_csr<<<4096, 256, 0, stream>>>(x, nullptr, 128, offA, cntA, elA, aggp, 32768, 512);
    gemm_aw<<<dim3(2, 512), 256, 0, stream>>>(aggp, nullptr, 128, nullptr, x, 128,
        wt_c0h, wt_c0l, conv0_b, x0, x0p, 128, 1);

    // ---- dense branch, pool 1 ----
    gemm_aw<<<dim3(4, 512), 256, 0, stream>>>(x0p, nullptr, 128, nullptr, nullptr, 0,
        wt_pool0h, wt_pool0l, pool0_b, s_sm, nullptr, 256, 0);
    softmax_rows_wave<<<8192, 256, 0, stream>>>(s_sm, 256, deg, rowq2, rowdq2, 32768, s_smp);
    reduce2_pergraph<<<64, 256, 0, stream>>>(rowq2, rowdq2, 512, accs + 128, accs + 64);
    gather_csr<<<8192, 256, 0, stream>>>(nullptr, s_smp, 256, offB, cntB, elB, Tbp, 32768, 512);
    {   // outx1 (z 0..1) + adj1 (z 2..5) in ONE launch; adj job emits row stats
        TTSet t0{x0p, nullptr, ox1p, nullptr, 128, 0, 512 * 128, 256 * 128, nullptr, nullptr};
        TTSet t1{Tbp, adj1, nullptr, accs + 192, 256, 1, 512 * 256, 256 * 256, rsum1, rdiag1};
        gemm_tt<<<dim3(64, 4, 6), 256, 0, stream>>>(s_smp, 512, 256, 512 * 256, 2, t0, t1);
    }
    adjnorm<<<64, 1024, 0, stream>>>(adj1, 256, rsum1, rdiag1, accs + 0,
        rowsum2, rscale2, a1h, a1l);
    // sage1 (rscale fused into gemm_nt epilogue -> AXp packed)
    gemm_nt<<<dim3(64, 4, 2), 256, 0, stream>>>(a1h, a1l, ox1p, nullptr, AXp, rscale2, 256,
        256, 128, 256 * 256, 256 * 128, 256 * 128);
    gemm_aw<<<dim3(2, 256), 256, 0, stream>>>(AXp, nullptr, 128, ox1p, nullptr, 128,
        wt_sg1h, wt_sg1l, sg1_b, nullptr, xd1p, 128, 1);
    // pool 2
    gemm_aw<<<dim3(2, 256), 256, 0, stream>>>(xd1p, nullptr, 128, nullptr, nullptr, 0,
        wt_pool1h, wt_pool1l, pool1_b, s2sm, nullptr, 128, 0);
    softmax_rows_wave<<<4096, 256, 0, stream>>>(s2sm, 128, rowsum2, rowq2, rowdq2, 16384, s2p);
    reduce2_pergraph<<<64, 256, 0, stream>>>(rowq2, rowdq2, 256, accs + 384, accs + 320);
    gemm_nt<<<dim3(64, 4, 2), 256, 0, stream>>>(a1h, a1l, s2p, nullptr, T2p, nullptr, 0,
        256, 128, 256 * 256, 256 * 128, 256 * 128);
    {   // outx2 (z 0..1) + adj2 (z 2..3) in ONE launch; adj job emits row stats
        TTSet t0{xd1p, nullptr, ox2p, nullptr, 128, 0, 256 * 128, 128 * 128, nullptr, nullptr};
        TTSet t1{T2p, adj2b, nullptr, accs + 448, 128, 1, 256 * 128, 128 * 128, rsum2, rdiag2};
        gemm_tt<<<dim3(64, 2, 4), 256, 0, stream>>>(s2p, 256, 128, 256 * 128, 2, t0, t1);
    }
    adjnorm<<<64, 1024, 0, stream>>>(adj2b, 128, rsum2, rdiag2, accs + 256,
        rowsum3, rscale3, a2h, a2l);
    // sage2 + head
    gemm_nt<<<dim3(64, 2, 2), 256, 0, stream>>>(a2h, a2l, ox2p, nullptr, AXp2, rscale3, 128,
        128, 128, 128 * 128, 128 * 128, 128 * 128);
    gemm_aw<<<dim3(2, 128), 256, 0, stream>>>(AXp2, nullptr, 128, ox2p, nullptr, 128,
        wt_sg2h, wt_sg2l, sg2_b, xd2, nullptr, 128, 0);

    // ---- sparse branch: topk_fused now builds the next-level CSR block-locally ----
    topk_fused<<<64, 512, 0, stream>>>(x0, p1, 512, 256, sxA, sxsum,
        src, dst, nullptr, s1, d1, m1, elC, offC, cntC);
    gather_csr<<<2048, 256, 0, stream>>>(sxA, nullptr, 128, offC, cntC, elC, agg2p, 16384, 256);
    gemm_aw<<<dim3(2, 256), 256, 0, stream>>>(agg2p, nullptr, 128, nullptr, sxA, 128,
        wt_sc2h, wt_sc2l, sc2_b, sxB, nullptr, 128, 1);
    topk_fused<<<64, 512, 0, stream>>>(sxB, p2, 256, 128, sxC, sxsum,
        s1, d1, m1, s2e, d2e, m2e, elD, offD, cntD);
    gather_csr<<<1024, 256, 0, stream>>>(sxC, nullptr, 128, offD, cntD, elD, agg3p, 8192, 128);
    gemm_aw<<<dim3(2, 128), 256, 0, stream>>>(agg3p, nullptr, 128, nullptr, sxC, 128,
        wt_sc3h, wt_sc3l, sc3_b, sxD, nullptr, 128, 1);
    topk_fused<<<64, 512, 0, stream>>>(sxD, p3, 128, 64, sxE, sxsum,
        nullptr, nullptr, nullptr, nullptr, nullptr, nullptr, nullptr, nullptr, nullptr);

    final_head<<<64, 128, 0, stream>>>(sxsum, l11_w, l11_b, xd2, l1_w, l1_b,
        l2_w, l2_b, accs, out);
}

// Round 10
// 610.824 us; speedup vs baseline: 1.1385x; 1.0264x over previous
//
#include <hip/hip_runtime.h>
#include <math.h>

#define NGRAPH 64
#define NE 524288      // total edges
#define EPG 8192       // edges per graph
#define TSZ 2560       // 64 rows * 40 shorts per LDS tile half

typedef short s16x8 __attribute__((ext_vector_type(8)));
typedef float f32x4 __attribute__((ext_vector_type(4)));

__device__ inline unsigned short f2bf(float f) {
    unsigned int u = __float_as_uint(f);
    return (unsigned short)((u + 0x7FFFu + ((u >> 16) & 1u)) >> 16);
}
__device__ inline float bf2f(unsigned short h) {
    return __uint_as_float((unsigned int)h << 16);
}
// packed split-bf16: low16 = hi part, high16 = lo (residual) part
__device__ inline unsigned int f2pk(float v) {
    unsigned short h = f2bf(v);
    return (unsigned int)h | ((unsigned int)f2bf(v - bf2f(h)) << 16);
}

// ---------------- CSR build (L0: both directions in one launch) ---------------------------
__global__ void edge_count2(const int* __restrict__ keyA, int* __restrict__ cntA,
                            const int* __restrict__ keyB, int* __restrict__ cntB) {
    int e = blockIdx.x * 256 + threadIdx.x;
    if (e >= NE) return;
    if (blockIdx.y == 0) atomicAdd(&cntA[keyA[e]], 1);
    else                 atomicAdd(&cntB[keyB[e]], 1);
}

__device__ inline void scan_body(const int* __restrict__ counts, int* __restrict__ offs,
                                 int* __restrict__ cursor, int nPerGraph,
                                 float* __restrict__ degOut, int* s) {
    const int g = blockIdx.x, t = threadIdx.x;
    int v = (t < nPerGraph) ? counts[g * nPerGraph + t] : 0;
    s[t] = v; __syncthreads();
    for (int d = 1; d < 512; d <<= 1) {
        int u = (t >= d) ? s[t - d] : 0;
        __syncthreads();
        s[t] += u;
        __syncthreads();
    }
    if (t < nPerGraph) {
        int o = g * EPG + s[t] - v;
        offs[g * nPerGraph + t] = o;
        cursor[g * nPerGraph + t] = o;
        if (degOut) degOut[g * nPerGraph + t] = (float)v;
    }
}

__global__ __launch_bounds__(512) void scan_offsets2(
        const int* __restrict__ cA, int* __restrict__ oA, int* __restrict__ uA,
        const int* __restrict__ cB, int* __restrict__ oB, int* __restrict__ uB,
        int nPerGraph, float* __restrict__ degB) {
    __shared__ int s[512];
    if (blockIdx.y == 0) scan_body(cA, oA, uA, nPerGraph, nullptr, s);
    else                 scan_body(cB, oB, uB, nPerGraph, degB, s);
}

__global__ void edge_fill2(const int* __restrict__ kA, const int* __restrict__ pA,
                           int* __restrict__ uA, int* __restrict__ eA,
                           const int* __restrict__ kB, const int* __restrict__ pB,
                           int* __restrict__ uB, int* __restrict__ eB) {
    int e = blockIdx.x * 256 + threadIdx.x;
    if (e >= NE) return;
    if (blockIdx.y == 0) { int p = atomicAdd(&uA[kA[e]], 1); eA[p] = pA[e]; }
    else                 { int p = atomicAdd(&uB[kB[e]], 1); eB[p] = pB[e]; }
}

// ---------------- CSR gather: f32 or packed input, packed output --------------------------
__device__ inline void addpk(float4& acc, uint4 u) {
    acc.x += __uint_as_float(u.x << 16) + __uint_as_float(u.x & 0xffff0000u);
    acc.y += __uint_as_float(u.y << 16) + __uint_as_float(u.y & 0xffff0000u);
    acc.z += __uint_as_float(u.z << 16) + __uint_as_float(u.z & 0xffff0000u);
    acc.w += __uint_as_float(u.w << 16) + __uint_as_float(u.w & 0xffff0000u);
}

__global__ __launch_bounds__(256) void gather_csr(
    const float* __restrict__ xf, const unsigned int* __restrict__ xp, int Fx,
    const int* __restrict__ offs, const int* __restrict__ cnts,
    const int* __restrict__ elist,
    unsigned int* __restrict__ opk,
    int totRows, int rowsPerGraph)
{
    const int gid = (blockIdx.x * 256 + threadIdx.x) >> 5;
    const int lane = threadIdx.x & 31;
    const int csh = (Fx == 256) ? 1 : 0;
    const int rid = gid >> csh;
    const int c0 = (gid & ((1 << csh) - 1)) << 7;
    if (rid >= totRows) return;
    const int row = (rid & 63) * rowsPerGraph + (rid >> 6);
    const int beg = offs[row];
    const int n = cnts[row];
    const long long co = (long long)c0 + (lane << 2);
    float4 acc = make_float4(0.f, 0.f, 0.f, 0.f);
    int j = 0;
    if (xp) {
        for (; j + 4 <= n; j += 4) {
            const int n0 = elist[beg + j], n1 = elist[beg + j + 1];
            const int n2 = elist[beg + j + 2], n3 = elist[beg + j + 3];
            const uint4 u0 = *(const uint4*)&xp[(long long)n0 * Fx + co];
            const uint4 u1 = *(const uint4*)&xp[(long long)n1 * Fx + co];
            const uint4 u2 = *(const uint4*)&xp[(long long)n2 * Fx + co];
            const uint4 u3 = *(const uint4*)&xp[(long long)n3 * Fx + co];
            addpk(acc, u0); addpk(acc, u1); addpk(acc, u2); addpk(acc, u3);
        }
        for (; j < n; ++j)
            addpk(acc, *(const uint4*)&xp[(long long)elist[beg + j] * Fx + co]);
    } else {
        for (; j + 4 <= n; j += 4) {
            const int n0 = elist[beg + j], n1 = elist[beg + j + 1];
            const int n2 = elist[beg + j + 2], n3 = elist[beg + j + 3];
            const float4 v0 = *(const float4*)&xf[(long long)n0 * Fx + co];
            const float4 v1 = *(const float4*)&xf[(long long)n1 * Fx + co];
            const float4 v2 = *(const float4*)&xf[(long long)n2 * Fx + co];
            const float4 v3 = *(const float4*)&xf[(long long)n3 * Fx + co];
            acc.x += v0.x + v1.x + v2.x + v3.x;
            acc.y += v0.y + v1.y + v2.y + v3.y;
            acc.z += v0.z + v1.z + v2.z + v3.z;
            acc.w += v0.w + v1.w + v2.w + v3.w;
        }
        for (; j < n; ++j) {
            const float4 v = *(const float4*)&xf[(long long)elist[beg + j] * Fx + co];
            acc.x += v.x; acc.y += v.y; acc.z += v.z; acc.w += v.w;
        }
    }
    uint4 pk;
    pk.x = f2pk(acc.x); pk.y = f2pk(acc.y); pk.z = f2pk(acc.z); pk.w = f2pk(acc.w);
    *(uint4*)&opk[(long long)row * Fx + co] = pk;
}

// ---------------- all 7 weight converts in ONE launch -------------------------------------
struct WSpec {
    const float* w1; const float* w2; int K1; int K2; int Nn;
    unsigned short* oh; unsigned short* ol;
};

__global__ void wconv_all(WSpec s0, WSpec s1, WSpec s2, WSpec s3, WSpec s4, WSpec s5, WSpec s6) {
    WSpec s;
    switch (blockIdx.y) {
        case 0: s = s0; break; case 1: s = s1; break; case 2: s = s2; break;
        case 3: s = s3; break; case 4: s = s4; break; case 5: s = s5; break;
        default: s = s6; break;
    }
    int idx = blockIdx.x * 256 + threadIdx.x;
    int Kt = s.K1 + s.K2;
    if (idx >= s.Nn * Kt) return;
    int n = idx / Kt, k = idx - n * Kt;
    float v = (k < s.K1) ? s.w1[(long long)k * s.Nn + n] : s.w2[(long long)(k - s.K1) * s.Nn + n];
    unsigned short h = f2bf(v);
    s.oh[idx] = h;
    s.ol[idx] = f2bf(v - __uint_as_float((unsigned int)h << 16));
}

// ---------------- staging (hi at base, lo at base+TSZ) ------------------------------------
__device__ inline void stageN_split(const float* __restrict__ src, int ldk, int k0,
                                    short* lds, int tid) {
    const int r = tid >> 2, kq = (tid & 3) << 3;
    const float* p = src + (long long)r * ldk + k0 + kq;
    float v[8];
    *(float4*)v = *(const float4*)p;
    *(float4*)(v + 4) = *(const float4*)(p + 4);
    s16x8 hv, lv;
    #pragma unroll
    for (int i = 0; i < 8; ++i) {
        unsigned short h = f2bf(v[i]);
        float hf = __uint_as_float((unsigned int)h << 16);
        hv[i] = (short)h;
        lv[i] = (short)f2bf(v[i] - hf);
    }
    *(s16x8*)(lds + r * 40 + kq) = hv;
    *(s16x8*)(lds + TSZ + r * 40 + kq) = lv;
}

__device__ inline void stageN_pk(const unsigned int* __restrict__ src, int ldk, int k0,
                                 short* lds, int tid) {
    const int r = tid >> 2, kq = (tid & 3) << 3;
    const unsigned int* p = src + (long long)r * ldk + k0 + kq;
    uint4 a = *(const uint4*)p;
    uint4 b = *(const uint4*)(p + 4);
    uint4 hw, lw;
    hw.x = (a.x & 0xffffu) | (a.y << 16);
    hw.y = (a.z & 0xffffu) | (a.w << 16);
    hw.z = (b.x & 0xffffu) | (b.y << 16);
    hw.w = (b.z & 0xffffu) | (b.w << 16);
    lw.x = (a.x >> 16) | (a.y & 0xffff0000u);
    lw.y = (a.z >> 16) | (a.w & 0xffff0000u);
    lw.z = (b.x >> 16) | (b.y & 0xffff0000u);
    lw.w = (b.z >> 16) | (b.w & 0xffff0000u);
    *(uint4*)(lds + r * 40 + kq) = hw;
    *(uint4*)(lds + TSZ + r * 40 + kq) = lw;
}

__device__ inline void stageT_pk(const unsigned int* __restrict__ P,
                                 int ldm, int k0, int m0, short* lds, int tid) {
    const int kp = tid >> 4, mc = tid & 15;
    const int k = kp << 1;
    const unsigned int* p0 = P + (long long)(k0 + k) * ldm + m0 + mc;
    const unsigned int* p1 = p0 + ldm;
    #pragma unroll
    for (int i = 0; i < 4; ++i) {
        unsigned int e0 = p0[i << 4], e1 = p1[i << 4];
        const int o = (mc + (i << 4)) * 40 + k;
        *(unsigned int*)(lds + o) = (e0 & 0xffffu) | (e1 << 16);
        *(unsigned int*)(lds + o + TSZ) = (e0 >> 16) | (e1 & 0xffff0000u);
    }
}

__device__ inline void stageW_split(const unsigned short* __restrict__ wh,
                                    const unsigned short* __restrict__ wl, int ldk,
                                    int n0, int k0, short* lds, int tid) {
    const int r = tid >> 2, kq = (tid & 3) << 3;
    *(s16x8*)(lds + r * 40 + kq) = *(const s16x8*)(wh + (long long)(n0 + r) * ldk + k0 + kq);
    *(s16x8*)(lds + TSZ + r * 40 + kq) = *(const s16x8*)(wl + (long long)(n0 + r) * ldk + k0 + kq);
}

// reg-staged double-buffer helpers (scattered transposed loads)
__device__ inline void loadT8(const unsigned int* __restrict__ P, int ldm, int k0, int m0,
                              int tid, unsigned int (&r)[8]) {
    const int kp = tid >> 4, mc = tid & 15;
    const int k = kp << 1;
    const unsigned int* p0 = P + (long long)(k0 + k) * ldm + m0 + mc;
    const unsigned int* p1 = p0 + ldm;
    #pragma unroll
    for (int i = 0; i < 4; ++i) { r[i] = p0[i << 4]; r[4 + i] = p1[i << 4]; }
}
__device__ inline void storeT8(short* lds, int tid, const unsigned int (&r)[8]) {
    const int kp = tid >> 4, mc = tid & 15;
    const int k = kp << 1;
    #pragma unroll
    for (int i = 0; i < 4; ++i) {
        unsigned int e0 = r[i], e1 = r[4 + i];
        const int o = (mc + (i << 4)) * 40 + k;
        *(unsigned int*)(lds + o) = (e0 & 0xffffu) | (e1 << 16);
        *(unsigned int*)(lds + o + TSZ) = (e0 >> 16) | (e1 & 0xffff0000u);
    }
}
__device__ inline void storeT8_hi(short* lds, int tid, const unsigned int (&r)[8]) {
    const int kp = tid >> 4, mc = tid & 15;
    const int k = kp << 1;
    #pragma unroll
    for (int i = 0; i < 4; ++i)
        *(unsigned int*)(lds + (mc + (i << 4)) * 40 + k) =
            (r[i] & 0xffffu) | (r[4 + i] << 16);
}

__device__ inline void mfma_split(const short* As, const short* Bs, int wm, int wn,
                                  int l15, int quad, f32x4 (&acc)[2][2]) {
    const int ko = quad << 3;
    s16x8 ah[2], al[2], bh[2], bl[2];
    #pragma unroll
    for (int i = 0; i < 2; ++i) {
        const int ra = (wm + (i << 4) + l15) * 40 + ko;
        const int rb = (wn + (i << 4) + l15) * 40 + ko;
        ah[i] = *(const s16x8*)&As[ra];
        al[i] = *(const s16x8*)&As[TSZ + ra];
        bh[i] = *(const s16x8*)&Bs[rb];
        bl[i] = *(const s16x8*)&Bs[TSZ + rb];
    }
    #pragma unroll
    for (int mi = 0; mi < 2; ++mi)
    #pragma unroll
    for (int ni = 0; ni < 2; ++ni) {
        f32x4 c = acc[mi][ni];
        c = __builtin_amdgcn_mfma_f32_16x16x32_bf16(ah[mi], bh[ni], c, 0, 0, 0);
        c = __builtin_amdgcn_mfma_f32_16x16x32_bf16(ah[mi], bl[ni], c, 0, 0, 0);
        c = __builtin_amdgcn_mfma_f32_16x16x32_bf16(al[mi], bh[ni], c, 0, 0, 0);
        acc[mi][ni] = c;
    }
}

__device__ inline void mfma_hi(const short* As, const short* Bs, int wm, int wn,
                               int l15, int quad, f32x4 (&acc)[2][2]) {
    const int ko = quad << 3;
    s16x8 ah[2], bh[2];
    #pragma unroll
    for (int i = 0; i < 2; ++i) {
        ah[i] = *(const s16x8*)&As[(wm + (i << 4) + l15) * 40 + ko];
        bh[i] = *(const s16x8*)&Bs[(wn + (i << 4) + l15) * 40 + ko];
    }
    #pragma unroll
    for (int mi = 0; mi < 2; ++mi)
    #pragma unroll
    for (int ni = 0; ni < 2; ++ni)
        acc[mi][ni] = __builtin_amdgcn_mfma_f32_16x16x32_bf16(ah[mi], bh[ni], acc[mi][ni], 0, 0, 0);
}

// ---------------- G1: flat C = op([A1|A2] @ Wt^T + bias), direct staging ------------------
__global__ __launch_bounds__(256) void gemm_aw(
    const unsigned int* __restrict__ A1p, const float* __restrict__ A1f, int K1,
    const unsigned int* __restrict__ A2p, const float* __restrict__ A2f, int K2,
    const unsigned short* __restrict__ Wh, const unsigned short* __restrict__ Wl,
    const float* __restrict__ bias, float* __restrict__ C,
    unsigned int* __restrict__ Cpk,
    int Nn, int doRelu)
{
    __shared__ short As[2 * TSZ], Bs[2 * TSZ];
    const int m0 = blockIdx.y << 6, n0 = blockIdx.x << 6;
    const int tid = threadIdx.x, lane = tid & 63, wv = tid >> 6;
    const int l15 = lane & 15, quad = lane >> 4;
    const int wm = (wv & 1) << 5, wn = (wv >> 1) << 5;
    f32x4 acc[2][2] = {};
    const int Kt = K1 + K2;
    for (int k0 = 0; k0 < Kt; k0 += 32) {
        if (k0 < K1) {
            if (A1p) stageN_pk(A1p + (long long)m0 * K1, K1, k0, As, tid);
            else     stageN_split(A1f + (long long)m0 * K1, K1, k0, As, tid);
        } else {
            if (A2p) stageN_pk(A2p + (long long)m0 * K2, K2, k0 - K1, As, tid);
            else     stageN_split(A2f + (long long)m0 * K2, K2, k0 - K1, As, tid);
        }
        stageW_split(Wh, Wl, Kt, n0, k0, Bs, tid);
        __syncthreads();
        mfma_split(As, Bs, wm, wn, l15, quad, acc);
        __syncthreads();
    }
    #pragma unroll
    for (int mi = 0; mi < 2; ++mi)
    #pragma unroll
    for (int ni = 0; ni < 2; ++ni) {
        const int col = n0 + wn + (ni << 4) + l15;
        const float bv = bias ? bias[col] : 0.f;
        #pragma unroll
        for (int r = 0; r < 4; ++r) {
            const int row = m0 + wm + (mi << 4) + (quad << 2) + r;
            float v = acc[mi][ni][r] + bv;
            if (doRelu) v = fmaxf(v, 0.f);
            if (C)   C[(long long)row * Nn + col] = v;
            if (Cpk) Cpk[(long long)row * Nn + col] = f2pk(v);
        }
    }
}

// ---------------- G2: batched C = A^T B, TWO jobs per launch, reg double-buffered ---------
// adj jobs additionally emit per-row col-sums (atomics) and the diagonal -> single-pass norm
struct TTSet {
    const unsigned int* Bp;
    float* C; unsigned int* Cpk; float* fro;
    int Nn; int dual;
    long long sB, sC;
    float* rsum; float* rdiag;      // per-row stats (adj jobs only), size NGRAPH*Nn
};

__global__ __launch_bounds__(256) void gemm_tt(
    const unsigned int* __restrict__ Ap, int Kd, int Mm, long long sA,
    int zsplit, TTSet t0, TTSet t1)
{
    __shared__ short As[2 * TSZ], Bs[2 * TSZ], A2s[TSZ];
    __shared__ float redf[4];
    const int z = blockIdx.x;
    int nz = blockIdx.z;
    const TTSet tt = (nz < zsplit) ? t0 : t1;
    if (blockIdx.z >= zsplit) nz -= zsplit;
    const unsigned int* Apz = Ap + (long long)z * sA;
    const unsigned int* Bpz = tt.Bp + (long long)z * tt.sB;
    const int m0 = blockIdx.y << 6, n0 = nz << 6;
    const int tid = threadIdx.x, lane = tid & 63, wv = tid >> 6;
    const int l15 = lane & 15, quad = lane >> 4;
    const int wm = (wv & 1) << 5, wn = (wv >> 1) << 5;
    const int fw = tt.dual ? ((m0 < n0) ? 2 : ((m0 == n0) ? 1 : 0)) : 0;
    f32x4 acc[2][2] = {};
    f32x4 accA[2][2] = {};
    unsigned int ra[8], rb[8], rh[8];
    loadT8(Apz, Mm, 0, m0, tid, ra);
    loadT8(Bpz, tt.Nn, 0, n0, tid, rb);
    if (fw) loadT8(Apz, Mm, 0, n0, tid, rh);
    for (int k0 = 0; k0 < Kd; k0 += 32) {
        storeT8(As, tid, ra);
        storeT8(Bs, tid, rb);
        if (fw) storeT8_hi(A2s, tid, rh);
        __syncthreads();
        const int kn = k0 + 32;
        if (kn < Kd) {
            loadT8(Apz, Mm, kn, m0, tid, ra);
            loadT8(Bpz, tt.Nn, kn, n0, tid, rb);
            if (fw) loadT8(Apz, Mm, kn, n0, tid, rh);
        }
        mfma_split(As, Bs, wm, wn, l15, quad, acc);
        if (fw) mfma_hi(As, A2s, wm, wn, l15, quad, accA);
        __syncthreads();
    }
    float* Cp = tt.C ? tt.C + (long long)z * tt.sC : nullptr;
    unsigned int* Ckp = tt.Cpk ? tt.Cpk + (long long)z * tt.sC : nullptr;
    #pragma unroll
    for (int mi = 0; mi < 2; ++mi)
    #pragma unroll
    for (int ni = 0; ni < 2; ++ni) {
        const int col = n0 + wn + (ni << 4) + l15;
        #pragma unroll
        for (int r = 0; r < 4; ++r) {
            const int row = m0 + wm + (mi << 4) + (quad << 2) + r;
            const float v = acc[mi][ni][r];
            if (Cp)  Cp[(long long)row * tt.Nn + col] = v;
            if (Ckp) Ckp[(long long)row * tt.Nn + col] = f2pk(v);
        }
    }
    if (tt.rsum) {
        // per-row partial sums of this wave's 32-column slice; 16-lane (l15) reduce
        #pragma unroll
        for (int mi = 0; mi < 2; ++mi) {
            #pragma unroll
            for (int r = 0; r < 4; ++r) {
                float rs = acc[mi][0][r] + acc[mi][1][r];
                rs += __shfl_xor(rs, 1);
                rs += __shfl_xor(rs, 2);
                rs += __shfl_xor(rs, 4);
                rs += __shfl_xor(rs, 8);
                if (l15 == 0) {
                    const int row = m0 + wm + (mi << 4) + (quad << 2) + r;
                    atomicAdd(&tt.rsum[z * tt.Nn + row], rs);
                }
            }
        }
        // diagonal (only blocks on the diagonal hold it); unique thread per element
        if (tt.rdiag && m0 == n0) {
            #pragma unroll
            for (int mi = 0; mi < 2; ++mi)
            #pragma unroll
            for (int ni = 0; ni < 2; ++ni)
            #pragma unroll
            for (int r = 0; r < 4; ++r) {
                const int rr = wm + (mi << 4) + (quad << 2) + r;
                const int cc = wn + (ni << 4) + l15;
                if (rr == cc) tt.rdiag[z * tt.Nn + m0 + rr] = acc[mi][ni][r];
            }
        }
    }
    if (fw) {
        float s = 0.f;
        #pragma unroll
        for (int mi = 0; mi < 2; ++mi)
        #pragma unroll
        for (int ni = 0; ni < 2; ++ni)
        #pragma unroll
        for (int r = 0; r < 4; ++r) s += accA[mi][ni][r] * accA[mi][ni][r];
        s *= (float)fw;
        for (int off = 32; off; off >>= 1) s += __shfl_xor(s, off);
        if (lane == 0) redf[wv] = s;
        __syncthreads();
        if (tid == 0) atomicAdd(&tt.fro[z], redf[0] + redf[1] + redf[2] + redf[3]);
    }
}

// ---------------- G3: batched C = A @ B; A direct, B reg-prefetched; rscale epilogue ------
__global__ __launch_bounds__(256) void gemm_nt(
    const unsigned short* __restrict__ Ah, const unsigned short* __restrict__ Al,
    const unsigned int* __restrict__ Bp,
    float* __restrict__ C, unsigned int* __restrict__ Cpk,
    const float* __restrict__ rscale, int rsn,
    int Kd, int Nn, long long sA, long long sB, long long sC)
{
    __shared__ short As[2 * TSZ], Bs[2 * TSZ];
    const int z = blockIdx.x;
    const int m0 = blockIdx.y << 6, n0 = blockIdx.z << 6;
    const unsigned short* Aph = Ah + (long long)z * sA;
    const unsigned short* Apl = Al + (long long)z * sA;
    const unsigned int* Bpz = Bp + (long long)z * sB;
    const int tid = threadIdx.x, lane = tid & 63, wv = tid >> 6;
    const int l15 = lane & 15, quad = lane >> 4;
    const int wm = (wv & 1) << 5, wn = (wv >> 1) << 5;
    f32x4 acc[2][2] = {};
    unsigned int rb[8];
    loadT8(Bpz, Nn, 0, n0, tid, rb);
    for (int k0 = 0; k0 < Kd; k0 += 32) {
        stageW_split(Aph, Apl, Kd, m0, k0, As, tid);   // row-major pre-split A: pure 16B copies
        storeT8(Bs, tid, rb);
        __syncthreads();
        const int kn = k0 + 32;
        if (kn < Kd) loadT8(Bpz, Nn, kn, n0, tid, rb);
        mfma_split(As, Bs, wm, wn, l15, quad, acc);
        __syncthreads();
    }
    #pragma unroll
    for (int mi = 0; mi < 2; ++mi)
    #pragma unroll
    for (int ni = 0; ni < 2; ++ni) {
        const int col = n0 + wn + (ni << 4) + l15;
        #pragma unroll
        for (int r = 0; r < 4; ++r) {
            const int row = m0 + wm + (mi << 4) + (quad << 2) + r;
            float v = acc[mi][ni][r];
            if (rscale) v *= rscale[z * rsn + row];
            if (C)   C[(long long)z * sC + (long long)row * Nn + col] = v;
            if (Cpk) Cpk[(long long)z * sC + (long long)row * Nn + col] = f2pk(v);
        }
    }
}

// ---------------- softmax rows: per-wave row, per-row partials (NO contended atomics) -----
__global__ __launch_bounds__(256) void softmax_rows_wave(
    const float* __restrict__ sm, int L,
    const float* __restrict__ deg,
    float* __restrict__ rowq2, float* __restrict__ rowdq2, int totRows,
    unsigned int* __restrict__ opk)
{
    const int wid = (blockIdx.x * 256 + threadIdx.x) >> 6;
    const int lane = threadIdx.x & 63;
    if (wid >= totRows) return;
    const float* rowp = sm + (long long)wid * L;
    const int nv = L >> 6;
    float v[4];
    if (nv == 4) {
        float4 t = *(const float4*)&rowp[lane << 2];
        v[0] = t.x; v[1] = t.y; v[2] = t.z; v[3] = t.w;
    } else {
        float2 t = *(const float2*)&rowp[lane << 1];
        v[0] = t.x; v[1] = t.y;
    }
    float mx = v[0];
    for (int i = 1; i < nv; ++i) mx = fmaxf(mx, v[i]);
    for (int off = 32; off; off >>= 1) mx = fmaxf(mx, __shfl_xor(mx, off));
    float s = 0.f;
    for (int i = 0; i < nv; ++i) { v[i] = expf(v[i] - mx); s += v[i]; }
    for (int off = 32; off; off >>= 1) s += __shfl_xor(s, off);
    const float inv = 1.f / s;
    float q2 = 0.f;
    for (int i = 0; i < nv; ++i) { float p = v[i] * inv; v[i] = p; q2 += p * p; }
    const long long rb = (long long)wid * L;
    if (nv == 4) {
        uint4 pk;
        pk.x = f2pk(v[0]); pk.y = f2pk(v[1]); pk.z = f2pk(v[2]); pk.w = f2pk(v[3]);
        *(uint4*)&opk[rb + (lane << 2)] = pk;
    } else {
        uint2 pk;
        pk.x = f2pk(v[0]); pk.y = f2pk(v[1]);
        *(uint2*)&opk[rb + (lane << 1)] = pk;
    }
    for (int off = 32; off; off >>= 1) q2 += __shfl_xor(q2, off);
    if (lane == 0) { rowq2[wid] = q2; rowdq2[wid] = deg[wid] * q2; }
}

__global__ __launch_bounds__(256) void reduce2_pergraph(
    const float* __restrict__ a, const float* __restrict__ b, int rowsPerGraph,
    float* __restrict__ outA, float* __restrict__ outB)
{
    __shared__ float redA[4], redB[4];
    const int g = blockIdx.x, t = threadIdx.x;
    float sa = 0.f, sb = 0.f;
    for (int i = t; i < rowsPerGraph; i += 256) {
        sa += a[g * rowsPerGraph + i];
        if (b) sb += b[g * rowsPerGraph + i];
    }
    for (int off = 32; off; off >>= 1) { sa += __shfl_xor(sa, off); sb += __shfl_xor(sb, off); }
    const int wv = t >> 6;
    if ((t & 63) == 0) { redA[wv] = sa; redB[wv] = sb; }
    __syncthreads();
    if (t == 0) {
        outA[g] = redA[0] + redA[1] + redA[2] + redA[3];
        if (outB) outB[g] = redB[0] + redB[1] + redB[2] + redB[3];
    }
}

// ---------------- SINGLE-PASS adjnorm: dpool from precomputed rsum/rdiag ------------------
__global__ __launch_bounds__(1024) void adjnorm(
    const float* __restrict__ adj, int K,
    const float* __restrict__ rsumIn, const float* __restrict__ rdiagIn,
    float* __restrict__ trace_out,
    float* __restrict__ rowsum, float* __restrict__ rscale,
    unsigned short* __restrict__ oh, unsigned short* __restrict__ ol)
{
    __shared__ float dpoolL[256];
    __shared__ float redt[16];
    const int g = blockIdx.x, tid = threadIdx.x;
    const int wv = tid >> 6, lane = tid & 63;
    float trp = 0.f;
    for (int r = tid; r < K; r += 1024) {
        float dv = rdiagIn[g * K + r];
        dpoolL[r] = sqrtf(rsumIn[g * K + r] - dv) + 1e-15f;
        trp += dv;
    }
    for (int off = 32; off; off >>= 1) trp += __shfl_xor(trp, off);
    if (lane == 0) redt[wv] = trp;
    __syncthreads();
    if (tid == 0) {
        float t = 0.f;
        #pragma unroll
        for (int i = 0; i < 16; ++i) t += redt[i];
        trace_out[g] = t;
    }
    const int rowsPerWave = K >> 4;   // 16 waves
    const int nv = K >> 6;
    for (int rr = 0; rr < rowsPerWave; ++rr) {
        const int r = wv * rowsPerWave + rr;
        const int wid = g * K + r;
        const float* rowp = adj + (long long)wid * K;
        const float inv_r = 1.f / dpoolL[r];
        float s = 0.f;
        for (int q = 0; q < nv; ++q) {
            int c = lane + (q << 6);
            float a = rowp[c];
            if (c == r) a = 0.f;
            float v = a * inv_r / dpoolL[c];
            s += v;
            unsigned short h = f2bf(v);
            oh[(long long)wid * K + c] = h;
            ol[(long long)wid * K + c] = f2bf(v - bf2f(h));
        }
        for (int off = 32; off; off >>= 1) s += __shfl_xor(s, off);
        if (lane == 0) { rowsum[wid] = s; rscale[wid] = 1.f / fmaxf(s, 1.f); }
    }
}

// ---------------- fused topk v3: vectorized edge phase + LDS edge cache -------------------
// Block g owns graph g. Edge passes use int4/float4 loads (4 edges/iter/thread) and cache
// remapped edges packed in LDS so pass 2 is LDS-only. sOut may be null (dead outputs).
__global__ __launch_bounds__(512) void topk_fused(
    const float* __restrict__ x, const float* __restrict__ p, int n, int k,
    float* __restrict__ outx, float* __restrict__ sxsum,
    const int* __restrict__ sIn, const int* __restrict__ dIn, const float* __restrict__ mIn,
    int* __restrict__ sOut, int* __restrict__ dOut, float* __restrict__ mOut,
    int* __restrict__ elist, int* __restrict__ offs, int* __restrict__ cnts)
{
    __shared__ float sc[512];
    __shared__ int pref[512];
    __shared__ int   selL[256];
    __shared__ float gateL[256];
    __shared__ float red[1024];
    __shared__ int   nidL[512];
    __shared__ int   cntL[256];
    __shared__ int   curL[256];
    __shared__ unsigned int eL[EPG];   // (ndLocal<<9)|nsLocal, 0xFFFFFFFF = invalid
    const int g = blockIdx.x, tid = threadIdx.x;
    float myScore = 0.f;
    if (tid < n) {
        const float* xr = x + (long long)(g * n + tid) * 128;
        float pn2 = 0.f, d = 0.f;
        #pragma unroll 4
        for (int f = 0; f < 128; f += 4) {
            float4 pv = *(const float4*)&p[f];
            float4 v = *(const float4*)&xr[f];
            pn2 += pv.x * pv.x + pv.y * pv.y + pv.z * pv.z + pv.w * pv.w;
            d += v.x * pv.x + v.y * pv.y + v.z * pv.z + v.w * pv.w;
        }
        myScore = d / (sqrtf(pn2) + 1e-16f);
        sc[tid] = myScore;
    }
    __syncthreads();
    int keep = 0;
    if (tid < n) {
        const float si = myScore;
        int rank = 0;
        for (int j = 0; j < n; j += 4) {
            float4 s4 = *(const float4*)&sc[j];
            rank += (s4.x > si) || (s4.x == si && (j + 0) < tid);
            rank += (s4.y > si) || (s4.y == si && (j + 1) < tid);
            rank += (s4.z > si) || (s4.z == si && (j + 2) < tid);
            rank += (s4.w > si) || (s4.w == si && (j + 3) < tid);
        }
        keep = rank < k;
    }
    pref[tid] = keep;
    __syncthreads();
    for (int d = 1; d < 512; d <<= 1) {
        int u = (tid >= d) ? pref[tid - d] : 0;
        __syncthreads();
        pref[tid] += u;
        __syncthreads();
    }
    {
        int nid = -1;
        if (tid < n && keep) {
            int pos = pref[tid] - 1;
            nid = g * k + pos;
            selL[pos] = g * n + tid;
            gateL[pos] = tanhf(myScore);
        }
        nidL[tid] = nid;
    }
    __syncthreads();
    // gather + gate + per-graph readout (max / mean)
    const int f = tid & 127, grp = tid >> 7;     // 4 row-groups x 128 features
    float mx = -INFINITY, sm = 0.f;
    for (int r = grp; r < k; r += 4) {
        float v = x[(long long)selL[r] * 128 + f] * gateL[r];
        outx[(long long)(g * k + r) * 128 + f] = v;
        mx = fmaxf(mx, v); sm += v;
    }
    red[grp * 128 + f] = mx;
    red[512 + grp * 128 + f] = sm;
    __syncthreads();
    if (tid < 128) {
        float m = fmaxf(fmaxf(red[f], red[128 + f]), fmaxf(red[256 + f], red[384 + f]));
        float s2 = red[512 + f] + red[640 + f] + red[768 + f] + red[896 + f];
        sxsum[g * 256 + f] += m;
        sxsum[g * 256 + 128 + f] += s2 / k;
    }
    // ---- block-local edge remap + count + scan + CSR fill (vectorized, LDS-cached) ----
    if (sIn) {
        if (tid < k) cntL[tid] = 0;
        __syncthreads();
        const int e0 = g * EPG;
        const int gn = g * n, gk = g * k;
        #pragma unroll
        for (int i = 0; i < 4; ++i) {
            const int eidx = ((i << 9) + tid) << 2;      // 4 consecutive edges
            int4 s4 = *(const int4*)&sIn[e0 + eidx];
            int4 d4 = *(const int4*)&dIn[e0 + eidx];
            float4 m4 = mIn ? *(const float4*)&mIn[e0 + eidx] : make_float4(1.f,1.f,1.f,1.f);
            int ss[4] = {s4.x, s4.y, s4.z, s4.w};
            int dd[4] = {d4.x, d4.y, d4.z, d4.w};
            float mm[4] = {m4.x, m4.y, m4.z, m4.w};
            int so_[4], do_[4]; float mo_[4];
            #pragma unroll
            for (int j = 0; j < 4; ++j) {
                int ns = -1, nd = -1;
                if (mm[j] > 0.f) {
                    ns = nidL[ss[j] - gn];
                    nd = nidL[dd[j] - gn];
                }
                const bool v = (ns >= 0) && (nd >= 0);
                so_[j] = v ? ns : 0; do_[j] = v ? nd : 0; mo_[j] = v ? 1.f : 0.f;
                eL[eidx + j] = v ? (((unsigned)(nd - gk) << 9) | (unsigned)(ns - gk))
                                 : 0xFFFFFFFFu;
                if (v) atomicAdd(&cntL[nd - gk], 1);
            }
            if (sOut) {
                *(int4*)&sOut[e0 + eidx] = make_int4(so_[0], so_[1], so_[2], so_[3]);
                *(int4*)&dOut[e0 + eidx] = make_int4(do_[0], do_[1], do_[2], do_[3]);
                *(float4*)&mOut[e0 + eidx] = make_float4(mo_[0], mo_[1], mo_[2], mo_[3]);
            }
        }
        __syncthreads();
        int c = (tid < k) ? cntL[tid] : 0;
        pref[tid] = c;
        __syncthreads();
        for (int d = 1; d < 512; d <<= 1) {
            int u = (tid >= d) ? pref[tid - d] : 0;
            __syncthreads();
            pref[tid] += u;
            __syncthreads();
        }
        if (tid < k) {
            int o = pref[tid] - c;     // exclusive prefix (local)
            offs[gk + tid] = e0 + o;
            cnts[gk + tid] = c;
            curL[tid] = o;
        }
        __syncthreads();
        #pragma unroll
        for (int i = 0; i < 4; ++i) {
            const int eidx = ((i << 9) + tid) << 2;
            #pragma unroll
            for (int j = 0; j < 4; ++j) {
                const unsigned int pk_ = eL[eidx + j];
                if (pk_ != 0xFFFFFFFFu) {
                    const int nd = pk_ >> 9, ns = pk_ & 511;
                    const int p_ = atomicAdd(&curL[nd], 1);
                    elist[e0 + p_] = gk + ns;
                }
            }
        }
    }
}

// final head: mean_lin fused + mc/o scalar epilogue in block 0
__global__ void final_head(const float* __restrict__ sxsum, const float* __restrict__ w11,
                           const float* __restrict__ b11,
                           const float* __restrict__ xd2, const float* __restrict__ l1w,
                           const float* __restrict__ l1b,
                           const float* __restrict__ w2, const float* __restrict__ b2,
                           const float* __restrict__ accs, float* __restrict__ out) {
    __shared__ float meanv[128];
    __shared__ float sin_[256];
    __shared__ float cat[256];
    __shared__ float rm[2], ro[2];
    int b = blockIdx.x, t = threadIdx.x; // 128
    {
        float s = 0.f;
        for (int n = 0; n < 128; n++) s += xd2[(long long)(b * 128 + n) * 128 + t];
        meanv[t] = s / 128.f;
    }
    if (b == 0) {
        int wvi = t >> 6, lane = t & 63;
        const float* acc = accs + wvi * 256;
        float sqrtk = wvi ? sqrtf(128.f) : 16.f;
        float numv = acc[lane], denv = acc[64 + lane], trv = acc[128 + lane], frov = acc[192 + lane];
        float mcb = numv / (denv + 1e-15f);
        float ssn = sqrtf(frov) + 1e-15f;
        float ob = sqrtf(fmaxf(frov / (ssn * ssn) - 2.f * trv / (ssn * sqrtk) + 1.f, 0.f));
        for (int off = 32; off; off >>= 1) { mcb += __shfl_down(mcb, off); ob += __shfl_down(ob, off); }
        if (lane == 0) { rm[wvi] = mcb; ro[wvi] = ob; }
        __syncthreads();
        if (t == 0) {
            out[640] = -(rm[0] + rm[1]) / 64.f;
            out[641] = (ro[0] + ro[1]) / 64.f;
        }
    }
    sin_[t] = sxsum[b * 256 + t];
    sin_[t + 128] = sxsum[b * 256 + 128 + t];
    __syncthreads();
    float acc = b11[t];
    for (int i = 0; i < 256; i++) acc += sin_[i] * w11[i * 128 + t];
    cat[t] = fmaxf(acc, 0.f);
    float xga = l1b[t];
    for (int i = 0; i < 128; i++) xga += meanv[i] * l1w[i * 128 + t];
    cat[128 + t] = fmaxf(xga, 0.f);
    __syncthreads();
    if (t < 10) {
        float a = b2[t];
        for (int i = 0; i < 256; i++) a += cat[i] * w2[i * 10 + t];
        out[b * 10 + t] = a;
    }
}

// ------------------------------------------------------------------------------------------
extern "C" void kernel_launch(void* const* d_in, const int* in_sizes, int n_in,
                              void* d_out, int out_size, void* d_ws, size_t ws_size,
                              hipStream_t stream) {
    const float* x         = (const float*)d_in[0];
    const int*   src       = (const int*)d_in[1];
    const int*   dst       = (const int*)d_in[2];
    const float* conv0_wr  = (const float*)d_in[3];
    const float* conv0_wrt = (const float*)d_in[4];
    const float* conv0_b   = (const float*)d_in[5];
    const float* sc2_wr    = (const float*)d_in[6];
    const float* sc2_wrt   = (const float*)d_in[7];
    const float* sc2_b     = (const float*)d_in[8];
    const float* sc3_wr    = (const float*)d_in[9];
    const float* sc3_wrt   = (const float*)d_in[10];
    const float* sc3_b     = (const float*)d_in[11];
    const float* sg1_wr    = (const float*)d_in[12];
    const float* sg1_wrt   = (const float*)d_in[13];
    const float* sg1_b     = (const float*)d_in[14];
    const float* sg2_wr    = (const float*)d_in[15];
    const float* sg2_wrt   = (const float*)d_in[16];
    const float* sg2_b     = (const float*)d_in[17];
    const float* pool0_w   = (const float*)d_in[18];
    const float* pool0_b   = (const float*)d_in[19];
    const float* pool1_w   = (const float*)d_in[20];
    const float* pool1_b   = (const float*)d_in[21];
    const float* p1        = (const float*)d_in[22];
    const float* p2        = (const float*)d_in[23];
    const float* p3        = (const float*)d_in[24];
    const float* l11_w     = (const float*)d_in[25];
    const float* l11_b     = (const float*)d_in[26];
    const float* l1_w      = (const float*)d_in[27];
    const float* l1_b      = (const float*)d_in[28];
    const float* l2_w      = (const float*)d_in[29];
    const float* l2_b      = (const float*)d_in[30];
    float* out = (float*)d_out;

    char* w = (char*)d_ws;
    const unsigned long long MBy = 1ull << 20;
    float* x0    = (float*)(w + 0);           // 16 MB
    float* BIG1  = (float*)(w + 16 * MBy);    // 32 MB
    float* BIG2  = (float*)(w + 48 * MBy);    // 32 MB
    float* agg   = (float*)(w + 80 * MBy);    // 16 MB
    float* adj1  = (float*)(w + 104 * MBy);   // 16 MB
    int*   s1    = (int*)(w + 120 * MBy);
    int*   d1    = (int*)(w + 122 * MBy);
    float* m1    = (float*)(w + 124 * MBy);
    char*  misc  = w + 132 * MBy;
    float* rowq2  = (float*)(misc);                 // 128 KB (32768 f32)
    float* rowdq2 = (float*)(misc + 128 * 1024);    // 128 KB
    float* deg   = (float*)(misc + 384 * 1024);
    float* rowsum2 = (float*)(misc + 576 * 1024);
    float* rscale2 = (float*)(misc + 640 * 1024);
    float* rowsum3 = (float*)(misc + 736 * 1024);
    float* rscale3 = (float*)(misc + 768 * 1024);
    float* accs    = (float*)(misc + 800 * 1024);
    float* sxsum   = (float*)(misc + 900 * 1024);

    unsigned short* wt_sg1h   = (unsigned short*)(misc + 1024 * 1024);
    unsigned short* wt_sg1l   = wt_sg1h + 32768;
    unsigned short* wt_sg2h   = wt_sg1l + 32768;
    unsigned short* wt_sg2l   = wt_sg2h + 32768;
    unsigned short* wt_pool0h = wt_sg2l + 32768;
    unsigned short* wt_pool0l = wt_pool0h + 32768;
    unsigned short* wt_pool1h = wt_pool0l + 32768;
    unsigned short* wt_pool1l = wt_pool1h + 32768;
    unsigned short* wt_c0h    = wt_pool1l + 32768;
    unsigned short* wt_c0l    = wt_c0h + 32768;
    unsigned short* wt_sc2h   = wt_c0l + 32768;
    unsigned short* wt_sc2l   = wt_sc2h + 32768;
    unsigned short* wt_sc3h   = wt_sc2l + 32768;
    unsigned short* wt_sc3l   = wt_sc3h + 32768;

    // adj row stats (zeroed each iteration)
    float* rsum1  = (float*)(misc + 2048 * 1024);   // 64 KB (64*256)
    float* rdiag1 = (float*)(misc + 2112 * 1024);   // 64 KB
    float* rsum2  = (float*)(misc + 2176 * 1024);   // 32 KB (64*128)
    float* rdiag2 = (float*)(misc + 2208 * 1024);   // 32 KB

    float* s_sm  = BIG1;                      // f32 softmax input (pre-softmax scores)
    unsigned int* Tbp = (unsigned int*)BIG2;  // phase A; dead after adj1 GEMM
    float* s2sm  = BIG2 + 4 * 1024 * 1024;                       // +16..24 MiB
    unsigned int* T2p = (unsigned int*)((char*)BIG2 + 24 * MBy); // +24..32 MiB
    float* adj2b = BIG1 + 1024 * 1024;
    float* xd2   = BIG1 + 2 * 1024 * 1024;
    float* sxA   = BIG1 + 3 * 1024 * 1024;
    float* sxE   = BIG1 + 5 * 1024 * 1024;
    float* sxB   = x0;
    float* sxC   = x0 + 2 * 1024 * 1024;
    float* sxD   = x0 + 3 * 1024 * 1024;

    // packed split-bf16 planes (region 136..244 MiB of the workspace)
    unsigned int* s_smp = (unsigned int*)(w + 136 * MBy);  // 32 MiB
    unsigned int* x0p   = (unsigned int*)(w + 168 * MBy);  // 16 MiB
    unsigned int* ox1p  = (unsigned int*)(w + 184 * MBy);  // 8 MiB
    unsigned int* xd1p  = (unsigned int*)(w + 192 * MBy);  // 8 MiB
    unsigned int* s2p   = (unsigned int*)(w + 200 * MBy);  // 8 MiB
    unsigned int* ox2p  = (unsigned int*)(w + 208 * MBy);  // 4 MiB
    unsigned short* a1h = (unsigned short*)(w + 212 * MBy); // 8 MiB
    unsigned short* a1l = (unsigned short*)(w + 220 * MBy); // 8 MiB
    unsigned short* a2h = (unsigned short*)(w + 228 * MBy); // 2 MiB
    unsigned short* a2l = (unsigned short*)(w + 230 * MBy); // 2 MiB
    unsigned int* AXp   = (unsigned int*)(w + 232 * MBy);  // 8 MiB
    unsigned int* AXp2  = (unsigned int*)(w + 240 * MBy);  // 4 MiB

    unsigned int* aggp  = (unsigned int*)agg;
    unsigned int* agg2p = (unsigned int*)agg;
    unsigned int* agg3p = (unsigned int*)agg;

    char* adjc = (char*)adj1;
    int* elA  = (int*)(adjc + 0);
    int* elB  = (int*)(adjc + 2 * MBy);
    int* cntA = (int*)(adjc + 4 * MBy);                  // 128 KB
    int* cntB = (int*)(adjc + 4 * MBy + 128 * 1024);     // contiguous -> one memset
    int* offA = (int*)(adjc + 4 * MBy + 256 * 1024);
    int* curA = (int*)(adjc + 4 * MBy + 384 * 1024);
    int* offB = (int*)(adjc + 4 * MBy + 512 * 1024);
    int* curB = (int*)(adjc + 4 * MBy + 640 * 1024);
    char* aggc = (char*)agg;
    int* elC  = (int*)(aggc + 8 * MBy);
    int* elD  = (int*)(aggc + 10 * MBy);
    int* cntC = (int*)(aggc + 12 * MBy);
    int* offC = (int*)(aggc + 12 * MBy + 256 * 1024);
    int* cntD = (int*)(aggc + 13 * MBy);
    int* offD = (int*)(aggc + 13 * MBy + 256 * 1024);

    hipMemsetAsync(accs, 0, 520 * sizeof(float), stream);
    hipMemsetAsync(sxsum, 0, 16384 * sizeof(float), stream);
    hipMemsetAsync(cntA, 0, 65536 * sizeof(int), stream);   // cntA + cntB
    hipMemsetAsync(rsum1, 0, 128 * 1024, stream);           // rsum1 + rdiag1
    hipMemsetAsync(rsum2, 0, 64 * 1024, stream);            // rsum2 + rdiag2

    {
        WSpec a{sg1_wr, sg1_wrt, 128, 128, 128, wt_sg1h, wt_sg1l};
        WSpec b{sg2_wr, sg2_wrt, 128, 128, 128, wt_sg2h, wt_sg2l};
        WSpec c{pool0_w, nullptr, 128, 0, 256, wt_pool0h, wt_pool0l};
        WSpec d{pool1_w, nullptr, 128, 0, 128, wt_pool1h, wt_pool1l};
        WSpec e{conv0_wr, conv0_wrt, 128, 128, 128, wt_c0h, wt_c0l};
        WSpec f{sc2_wr, sc2_wrt, 128, 128, 128, wt_sc2h, wt_sc2l};
        WSpec g{sc3_wr, sc3_wrt, 128, 128, 128, wt_sc3h, wt_sc3l};
        wconv_all<<<dim3(128, 7), 256, 0, stream>>>(a, b, c, d, e, f, g);
    }

    edge_count2<<<dim3(2048, 2), 256, 0, stream>>>(dst, cntA, src, cntB);
    scan_offsets2<<<dim3(64, 2), 512, 0, stream>>>(cntA, offA, curA, cntB, offB, curB, 512, deg);
    edge_fill2<<<dim3(2048, 2), 256, 0, stream>>>(dst, src, curA, elA, src, dst, curB, elB);

    // ---- conv0: gather (f32 in -> packed out), gemm emits x0 f32 (topk) + x0p packed ----
    gather_csr<<<4096, 256, 0, stream>>>(x, nullptr, 128, offA, cntA, elA, aggp, 32768, 512);
    gemm_aw<<<dim3(2, 512), 256, 0, stream>>>(aggp, nullptr, 128, nullptr, x, 128,
        wt_c0h, wt_c0l, conv0_b, x0, x0p, 128, 1);

    // ---- dense branch, pool 1 ----
    gemm_aw<<<dim3(4, 512), 256, 0, stream>>>(x0p, nullptr, 128, nullptr, nullptr, 0,
        wt_pool0h, wt_pool0l, pool0_b, s_sm, nullptr, 256, 0);
    softmax_rows_wave<<<8192, 256, 0, stream>>>(s_sm, 256, deg, rowq2, rowdq2, 32768, s_smp);
    reduce2_pergraph<<<64, 256, 0, stream>>>(rowq2, rowdq2, 512, accs + 128, accs + 64);
    gather_csr<<<8192, 256, 0, stream>>>(nullptr, s_smp, 256, offB, cntB, elB, Tbp, 32768, 512);
    {   // outx1 (z 0..1) + adj1 (z 2..5) in ONE launch; adj job emits row stats
        TTSet t0{x0p, nullptr, ox1p, nullptr, 128, 0, 512 * 128, 256 * 128, nullptr, nullptr};
        TTSet t1{Tbp, adj1, nullptr, accs + 192, 256, 1, 512 * 256, 256 * 256, rsum1, rdiag1};
        gemm_tt<<<dim3(64, 4, 6), 256, 0, stream>>>(s_smp, 512, 256, 512 * 256, 2, t0, t1);
    }
    adjnorm<<<64, 1024, 0, stream>>>(adj1, 256, rsum1, rdiag1, accs + 0,
        rowsum2, rscale2, a1h, a1l);
    // sage1 (rscale fused into gemm_nt epilogue -> AXp packed)
    gemm_nt<<<dim3(64, 4, 2), 256, 0, stream>>>(a1h, a1l, ox1p, nullptr, AXp, rscale2, 256,
        256, 128, 256 * 256, 256 * 128, 256 * 128);
    gemm_aw<<<dim3(2, 256), 256, 0, stream>>>(AXp, nullptr, 128, ox1p, nullptr, 128,
        wt_sg1h, wt_sg1l, sg1_b, nullptr, xd1p, 128, 1);
    // pool 2
    gemm_aw<<<dim3(2, 256), 256, 0, stream>>>(xd1p, nullptr, 128, nullptr, nullptr, 0,
        wt_pool1h, wt_pool1l, pool1_b, s2sm, nullptr, 128, 0);
    softmax_rows_wave<<<4096, 256, 0, stream>>>(s2sm, 128, rowsum2, rowq2, rowdq2, 16384, s2p);
    reduce2_pergraph<<<64, 256, 0, stream>>>(rowq2, rowdq2, 256, accs + 384, accs + 320);
    gemm_nt<<<dim3(64, 4, 2), 256, 0, stream>>>(a1h, a1l, s2p, nullptr, T2p, nullptr, 0,
        256, 128, 256 * 256, 256 * 128, 256 * 128);
    {   // outx2 (z 0..1) + adj2 (z 2..3) in ONE launch; adj job emits row stats
        TTSet t0{xd1p, nullptr, ox2p, nullptr, 128, 0, 256 * 128, 128 * 128, nullptr, nullptr};
        TTSet t1{T2p, adj2b, nullptr, accs + 448, 128, 1, 256 * 128, 128 * 128, rsum2, rdiag2};
        gemm_tt<<<dim3(64, 2, 4), 256, 0, stream>>>(s2p, 256, 128, 256 * 128, 2, t0, t1);
    }
    adjnorm<<<64, 1024, 0, stream>>>(adj2b, 128, rsum2, rdiag2, accs + 256,
        rowsum3, rscale3, a2h, a2l);
    // sage2 + head
    gemm_nt<<<dim3(64, 2, 2), 256, 0, stream>>>(a2h, a2l, ox2p, nullptr, AXp2, rscale3, 128,
        128, 128, 128 * 128, 128 * 128, 128 * 128);
    gemm_aw<<<dim3(2, 128), 256, 0, stream>>>(AXp2, nullptr, 128, ox2p, nullptr, 128,
        wt_sg2h, wt_sg2l, sg2_b, xd2, nullptr, 128, 0);

    // ---- sparse branch: topk_fused builds the next-level CSR block-locally ----
    topk_fused<<<64, 512, 0, stream>>>(x0, p1, 512, 256, sxA, sxsum,
        src, dst, nullptr, s1, d1, m1, elC, offC, cntC);
    gather_csr<<<2048, 256, 0, stream>>>(sxA, nullptr, 128, offC, cntC, elC, agg2p, 16384, 256);
    gemm_aw<<<dim3(2, 256), 256, 0, stream>>>(agg2p, nullptr, 128, nullptr, sxA, 128,
        wt_sc2h, wt_sc2l, sc2_b, sxB, nullptr, 128, 1);
    topk_fused<<<64, 512, 0, stream>>>(sxB, p2, 256, 128, sxC, sxsum,
        s1, d1, m1, nullptr, nullptr, nullptr, elD, offD, cntD);
    gather_csr<<<1024, 256, 0, stream>>>(sxC, nullptr, 128, offD, cntD, elD, agg3p, 8192, 128);
    gemm_aw<<<dim3(2, 128), 256, 0, stream>>>(agg3p, nullptr, 128, nullptr, sxC, 128,
        wt_sc3h, wt_sc3l, sc3_b, sxD, nullptr, 128, 1);
    topk_fused<<<64, 512, 0, stream>>>(sxD, p3, 128, 64, sxE, sxsum,
        nullptr, nullptr, nullptr, nullptr, nullptr, nullptr, nullptr, nullptr, nullptr);

    final_head<<<64, 128, 0, stream>>>(sxsum, l11_w, l11_b, xd2, l1_w, l1_b,
        l2_w, l2_b, accs, out);
}

// Round 12
// 598.892 us; speedup vs baseline: 1.1612x; 1.0199x over previous
//
#include <hip/hip_runtime.h>
#include <math.h>

#define NGRAPH 64
#define NE 524288      // total edges
#define EPG 8192       // edges per graph
#define TSZ 2560       // 64 rows * 40 shorts per LDS tile half

typedef short s16x8 __attribute__((ext_vector_type(8)));
typedef float f32x4 __attribute__((ext_vector_type(4)));

__device__ inline unsigned short f2bf(float f) {
    unsigned int u = __float_as_uint(f);
    return (unsigned short)((u + 0x7FFFu + ((u >> 16) & 1u)) >> 16);
}
__device__ inline float bf2f(unsigned short h) {
    return __uint_as_float((unsigned int)h << 16);
}
// packed split-bf16: low16 = hi part, high16 = lo (residual) part
__device__ inline unsigned int f2pk(float v) {
    unsigned short h = f2bf(v);
    return (unsigned int)h | ((unsigned int)f2bf(v - bf2f(h)) << 16);
}

// ---------------- CSR build (L0: both directions in one launch) ---------------------------
__global__ void edge_count2(const int* __restrict__ keyA, int* __restrict__ cntA,
                            const int* __restrict__ keyB, int* __restrict__ cntB) {
    int e = blockIdx.x * 256 + threadIdx.x;
    if (e >= NE) return;
    if (blockIdx.y == 0) atomicAdd(&cntA[keyA[e]], 1);
    else                 atomicAdd(&cntB[keyB[e]], 1);
}

__device__ inline void scan_body(const int* __restrict__ counts, int* __restrict__ offs,
                                 int* __restrict__ cursor, int nPerGraph,
                                 float* __restrict__ degOut, int* s) {
    const int g = blockIdx.x, t = threadIdx.x;
    int v = (t < nPerGraph) ? counts[g * nPerGraph + t] : 0;
    s[t] = v; __syncthreads();
    for (int d = 1; d < 512; d <<= 1) {
        int u = (t >= d) ? s[t - d] : 0;
        __syncthreads();
        s[t] += u;
        __syncthreads();
    }
    if (t < nPerGraph) {
        int o = g * EPG + s[t] - v;
        offs[g * nPerGraph + t] = o;
        cursor[g * nPerGraph + t] = o;
        if (degOut) degOut[g * nPerGraph + t] = (float)v;
    }
}

__global__ __launch_bounds__(512) void scan_offsets2(
        const int* __restrict__ cA, int* __restrict__ oA, int* __restrict__ uA,
        const int* __restrict__ cB, int* __restrict__ oB, int* __restrict__ uB,
        int nPerGraph, float* __restrict__ degB) {
    __shared__ int s[512];
    if (blockIdx.y == 0) scan_body(cA, oA, uA, nPerGraph, nullptr, s);
    else                 scan_body(cB, oB, uB, nPerGraph, degB, s);
}

__global__ void edge_fill2(const int* __restrict__ kA, const int* __restrict__ pA,
                           int* __restrict__ uA, int* __restrict__ eA,
                           const int* __restrict__ kB, const int* __restrict__ pB,
                           int* __restrict__ uB, int* __restrict__ eB) {
    int e = blockIdx.x * 256 + threadIdx.x;
    if (e >= NE) return;
    if (blockIdx.y == 0) { int p = atomicAdd(&uA[kA[e]], 1); eA[p] = pA[e]; }
    else                 { int p = atomicAdd(&uB[kB[e]], 1); eB[p] = pB[e]; }
}

// ---------------- CSR gather: XCD-affinity graph mapping ----------------------------------
// All blocks of graph g are mapped to the same XCD (g determined by blockIdx%8) so the
// graph's feature slice stays resident in that XCD's L2 across the ~8x neighbor re-reads.
__device__ inline void addpk(float4& acc, uint4 u) {
    acc.x += __uint_as_float(u.x << 16) + __uint_as_float(u.x & 0xffff0000u);
    acc.y += __uint_as_float(u.y << 16) + __uint_as_float(u.y & 0xffff0000u);
    acc.z += __uint_as_float(u.z << 16) + __uint_as_float(u.z & 0xffff0000u);
    acc.w += __uint_as_float(u.w << 16) + __uint_as_float(u.w & 0xffff0000u);
}

__global__ __launch_bounds__(256) void gather_csr(
    const float* __restrict__ xf, const unsigned int* __restrict__ xp, int Fx,
    const int* __restrict__ offs, const int* __restrict__ cnts,
    const int* __restrict__ elist,
    unsigned int* __restrict__ opk,
    int totRows, int rowsPerGraph)
{
    // XCD-chunked mapping: B = gridDim.x (pow2, divisible by 64); Bg = B/64 blocks/graph.
    const int B = gridDim.x;
    const int Bg = B >> 6;                       // blocks per graph (pow2)
    const int sh = 31 - __clz(Bg);
    const int xcd = blockIdx.x & 7;
    const int q = blockIdx.x >> 3;
    const int g = (xcd << 3) + (q >> sh);        // graph for this block
    const int slot = q & (Bg - 1);
    const int csh = (Fx == 256) ? 1 : 0;
    const int t = (slot << 3) + (threadIdx.x >> 5);   // wave-task within graph
    const int lane = threadIdx.x & 31;
    const int ridl = t >> csh;
    const int c0 = (t & ((1 << csh) - 1)) << 7;
    const int row = g * rowsPerGraph + ridl;
    if (row >= totRows) return;
    const int beg = offs[row];
    const int n = cnts[row];
    const long long co = (long long)c0 + (lane << 2);
    float4 acc = make_float4(0.f, 0.f, 0.f, 0.f);
    int j = 0;
    if (xp) {
        for (; j + 4 <= n; j += 4) {
            const int n0 = elist[beg + j], n1 = elist[beg + j + 1];
            const int n2 = elist[beg + j + 2], n3 = elist[beg + j + 3];
            const uint4 u0 = *(const uint4*)&xp[(long long)n0 * Fx + co];
            const uint4 u1 = *(const uint4*)&xp[(long long)n1 * Fx + co];
            const uint4 u2 = *(const uint4*)&xp[(long long)n2 * Fx + co];
            const uint4 u3 = *(const uint4*)&xp[(long long)n3 * Fx + co];
            addpk(acc, u0); addpk(acc, u1); addpk(acc, u2); addpk(acc, u3);
        }
        for (; j < n; ++j)
            addpk(acc, *(const uint4*)&xp[(long long)elist[beg + j] * Fx + co]);
    } else {
        for (; j + 4 <= n; j += 4) {
            const int n0 = elist[beg + j], n1 = elist[beg + j + 1];
            const int n2 = elist[beg + j + 2], n3 = elist[beg + j + 3];
            const float4 v0 = *(const float4*)&xf[(long long)n0 * Fx + co];
            const float4 v1 = *(const float4*)&xf[(long long)n1 * Fx + co];
            const float4 v2 = *(const float4*)&xf[(long long)n2 * Fx + co];
            const float4 v3 = *(const float4*)&xf[(long long)n3 * Fx + co];
            acc.x += v0.x + v1.x + v2.x + v3.x;
            acc.y += v0.y + v1.y + v2.y + v3.y;
            acc.z += v0.z + v1.z + v2.z + v3.z;
            acc.w += v0.w + v1.w + v2.w + v3.w;
        }
        for (; j < n; ++j) {
            const float4 v = *(const float4*)&xf[(long long)elist[beg + j] * Fx + co];
            acc.x += v.x; acc.y += v.y; acc.z += v.z; acc.w += v.w;
        }
    }
    uint4 pk;
    pk.x = f2pk(acc.x); pk.y = f2pk(acc.y); pk.z = f2pk(acc.z); pk.w = f2pk(acc.w);
    *(uint4*)&opk[(long long)row * Fx + co] = pk;
}

// ---------------- all 7 weight converts in ONE launch -------------------------------------
struct WSpec {
    const float* w1; const float* w2; int K1; int K2; int Nn;
    unsigned short* oh; unsigned short* ol;
};

__global__ void wconv_all(WSpec s0, WSpec s1, WSpec s2, WSpec s3, WSpec s4, WSpec s5, WSpec s6) {
    WSpec s;
    switch (blockIdx.y) {
        case 0: s = s0; break; case 1: s = s1; break; case 2: s = s2; break;
        case 3: s = s3; break; case 4: s = s4; break; case 5: s = s5; break;
        default: s = s6; break;
    }
    int idx = blockIdx.x * 256 + threadIdx.x;
    int Kt = s.K1 + s.K2;
    if (idx >= s.Nn * Kt) return;
    int n = idx / Kt, k = idx - n * Kt;
    float v = (k < s.K1) ? s.w1[(long long)k * s.Nn + n] : s.w2[(long long)(k - s.K1) * s.Nn + n];
    unsigned short h = f2bf(v);
    s.oh[idx] = h;
    s.ol[idx] = f2bf(v - __uint_as_float((unsigned int)h << 16));
}

// ---------------- staging (hi at base, lo at base+TSZ) ------------------------------------
__device__ inline void stageN_split(const float* __restrict__ src, int ldk, int k0,
                                    short* lds, int tid) {
    const int r = tid >> 2, kq = (tid & 3) << 3;
    const float* p = src + (long long)r * ldk + k0 + kq;
    float v[8];
    *(float4*)v = *(const float4*)p;
    *(float4*)(v + 4) = *(const float4*)(p + 4);
    s16x8 hv, lv;
    #pragma unroll
    for (int i = 0; i < 8; ++i) {
        unsigned short h = f2bf(v[i]);
        float hf = __uint_as_float((unsigned int)h << 16);
        hv[i] = (short)h;
        lv[i] = (short)f2bf(v[i] - hf);
    }
    *(s16x8*)(lds + r * 40 + kq) = hv;
    *(s16x8*)(lds + TSZ + r * 40 + kq) = lv;
}

__device__ inline void stageN_pk(const unsigned int* __restrict__ src, int ldk, int k0,
                                 short* lds, int tid) {
    const int r = tid >> 2, kq = (tid & 3) << 3;
    const unsigned int* p = src + (long long)r * ldk + k0 + kq;
    uint4 a = *(const uint4*)p;
    uint4 b = *(const uint4*)(p + 4);
    uint4 hw, lw;
    hw.x = (a.x & 0xffffu) | (a.y << 16);
    hw.y = (a.z & 0xffffu) | (a.w << 16);
    hw.z = (b.x & 0xffffu) | (b.y << 16);
    hw.w = (b.z & 0xffffu) | (b.w << 16);
    lw.x = (a.x >> 16) | (a.y & 0xffff0000u);
    lw.y = (a.z >> 16) | (a.w & 0xffff0000u);
    lw.z = (b.x >> 16) | (b.y & 0xffff0000u);
    lw.w = (b.z >> 16) | (b.w & 0xffff0000u);
    *(uint4*)(lds + r * 40 + kq) = hw;
    *(uint4*)(lds + TSZ + r * 40 + kq) = lw;
}

__device__ inline void stageT_pk(const unsigned int* __restrict__ P,
                                 int ldm, int k0, int m0, short* lds, int tid) {
    const int kp = tid >> 4, mc = tid & 15;
    const int k = kp << 1;
    const unsigned int* p0 = P + (long long)(k0 + k) * ldm + m0 + mc;
    const unsigned int* p1 = p0 + ldm;
    #pragma unroll
    for (int i = 0; i < 4; ++i) {
        unsigned int e0 = p0[i << 4], e1 = p1[i << 4];
        const int o = (mc + (i << 4)) * 40 + k;
        *(unsigned int*)(lds + o) = (e0 & 0xffffu) | (e1 << 16);
        *(unsigned int*)(lds + o + TSZ) = (e0 >> 16) | (e1 & 0xffff0000u);
    }
}

__device__ inline void stageW_split(const unsigned short* __restrict__ wh,
                                    const unsigned short* __restrict__ wl, int ldk,
                                    int n0, int k0, short* lds, int tid) {
    const int r = tid >> 2, kq = (tid & 3) << 3;
    *(s16x8*)(lds + r * 40 + kq) = *(const s16x8*)(wh + (long long)(n0 + r) * ldk + k0 + kq);
    *(s16x8*)(lds + TSZ + r * 40 + kq) = *(const s16x8*)(wl + (long long)(n0 + r) * ldk + k0 + kq);
}

// reg-staged double-buffer helpers (scattered transposed loads)
__device__ inline void loadT8(const unsigned int* __restrict__ P, int ldm, int k0, int m0,
                              int tid, unsigned int (&r)[8]) {
    const int kp = tid >> 4, mc = tid & 15;
    const int k = kp << 1;
    const unsigned int* p0 = P + (long long)(k0 + k) * ldm + m0 + mc;
    const unsigned int* p1 = p0 + ldm;
    #pragma unroll
    for (int i = 0; i < 4; ++i) { r[i] = p0[i << 4]; r[4 + i] = p1[i << 4]; }
}
__device__ inline void storeT8(short* lds, int tid, const unsigned int (&r)[8]) {
    const int kp = tid >> 4, mc = tid & 15;
    const int k = kp << 1;
    #pragma unroll
    for (int i = 0; i < 4; ++i) {
        unsigned int e0 = r[i], e1 = r[4 + i];
        const int o = (mc + (i << 4)) * 40 + k;
        *(unsigned int*)(lds + o) = (e0 & 0xffffu) | (e1 << 16);
        *(unsigned int*)(lds + o + TSZ) = (e0 >> 16) | (e1 & 0xffff0000u);
    }
}
__device__ inline void storeT8_hi(short* lds, int tid, const unsigned int (&r)[8]) {
    const int kp = tid >> 4, mc = tid & 15;
    const int k = kp << 1;
    #pragma unroll
    for (int i = 0; i < 4; ++i)
        *(unsigned int*)(lds + (mc + (i << 4)) * 40 + k) =
            (r[i] & 0xffffu) | (r[4 + i] << 16);
}

__device__ inline void mfma_split(const short* As, const short* Bs, int wm, int wn,
                                  int l15, int quad, f32x4 (&acc)[2][2]) {
    const int ko = quad << 3;
    s16x8 ah[2], al[2], bh[2], bl[2];
    #pragma unroll
    for (int i = 0; i < 2; ++i) {
        const int ra = (wm + (i << 4) + l15) * 40 + ko;
        const int rb = (wn + (i << 4) + l15) * 40 + ko;
        ah[i] = *(const s16x8*)&As[ra];
        al[i] = *(const s16x8*)&As[TSZ + ra];
        bh[i] = *(const s16x8*)&Bs[rb];
        bl[i] = *(const s16x8*)&Bs[TSZ + rb];
    }
    #pragma unroll
    for (int mi = 0; mi < 2; ++mi)
    #pragma unroll
    for (int ni = 0; ni < 2; ++ni) {
        f32x4 c = acc[mi][ni];
        c = __builtin_amdgcn_mfma_f32_16x16x32_bf16(ah[mi], bh[ni], c, 0, 0, 0);
        c = __builtin_amdgcn_mfma_f32_16x16x32_bf16(ah[mi], bl[ni], c, 0, 0, 0);
        c = __builtin_amdgcn_mfma_f32_16x16x32_bf16(al[mi], bh[ni], c, 0, 0, 0);
        acc[mi][ni] = c;
    }
}

__device__ inline void mfma_hi(const short* As, const short* Bs, int wm, int wn,
                               int l15, int quad, f32x4 (&acc)[2][2]) {
    const int ko = quad << 3;
    s16x8 ah[2], bh[2];
    #pragma unroll
    for (int i = 0; i < 2; ++i) {
        ah[i] = *(const s16x8*)&As[(wm + (i << 4) + l15) * 40 + ko];
        bh[i] = *(const s16x8*)&Bs[(wn + (i << 4) + l15) * 40 + ko];
    }
    #pragma unroll
    for (int mi = 0; mi < 2; ++mi)
    #pragma unroll
    for (int ni = 0; ni < 2; ++ni)
        acc[mi][ni] = __builtin_amdgcn_mfma_f32_16x16x32_bf16(ah[mi], bh[ni], acc[mi][ni], 0, 0, 0);
}

// ---------------- G1: flat C = op([A1|A2] @ Wt^T + bias), direct staging ------------------
__global__ __launch_bounds__(256) void gemm_aw(
    const unsigned int* __restrict__ A1p, const float* __restrict__ A1f, int K1,
    const unsigned int* __restrict__ A2p, const float* __restrict__ A2f, int K2,
    const unsigned short* __restrict__ Wh, const unsigned short* __restrict__ Wl,
    const float* __restrict__ bias, float* __restrict__ C,
    unsigned int* __restrict__ Cpk,
    int Nn, int doRelu)
{
    __shared__ short As[2 * TSZ], Bs[2 * TSZ];
    const int m0 = blockIdx.y << 6, n0 = blockIdx.x << 6;
    const int tid = threadIdx.x, lane = tid & 63, wv = tid >> 6;
    const int l15 = lane & 15, quad = lane >> 4;
    const int wm = (wv & 1) << 5, wn = (wv >> 1) << 5;
    f32x4 acc[2][2] = {};
    const int Kt = K1 + K2;
    for (int k0 = 0; k0 < Kt; k0 += 32) {
        if (k0 < K1) {
            if (A1p) stageN_pk(A1p + (long long)m0 * K1, K1, k0, As, tid);
            else     stageN_split(A1f + (long long)m0 * K1, K1, k0, As, tid);
        } else {
            if (A2p) stageN_pk(A2p + (long long)m0 * K2, K2, k0 - K1, As, tid);
            else     stageN_split(A2f + (long long)m0 * K2, K2, k0 - K1, As, tid);
        }
        stageW_split(Wh, Wl, Kt, n0, k0, Bs, tid);
        __syncthreads();
        mfma_split(As, Bs, wm, wn, l15, quad, acc);
        __syncthreads();
    }
    #pragma unroll
    for (int mi = 0; mi < 2; ++mi)
    #pragma unroll
    for (int ni = 0; ni < 2; ++ni) {
        const int col = n0 + wn + (ni << 4) + l15;
        const float bv = bias ? bias[col] : 0.f;
        #pragma unroll
        for (int r = 0; r < 4; ++r) {
            const int row = m0 + wm + (mi << 4) + (quad << 2) + r;
            float v = acc[mi][ni][r] + bv;
            if (doRelu) v = fmaxf(v, 0.f);
            if (C)   C[(long long)row * Nn + col] = v;
            if (Cpk) Cpk[(long long)row * Nn + col] = f2pk(v);
        }
    }
}

// ---------------- G2: batched C = A^T B, TWO jobs per launch, reg double-buffered ---------
// adj jobs additionally emit per-row col-sums (atomics) and the diagonal -> single-pass norm
struct TTSet {
    const unsigned int* Bp;
    float* C; unsigned int* Cpk; float* fro;
    int Nn; int dual;
    long long sB, sC;
    float* rsum; float* rdiag;      // per-row stats (adj jobs only), size NGRAPH*Nn
};

__global__ __launch_bounds__(256) void gemm_tt(
    const unsigned int* __restrict__ Ap, int Kd, int Mm, long long sA,
    int zsplit, TTSet t0, TTSet t1)
{
    __shared__ short As[2 * TSZ], Bs[2 * TSZ], A2s[TSZ];
    __shared__ float redf[4];
    const int z = blockIdx.x;
    int nz = blockIdx.z;
    const TTSet tt = (nz < zsplit) ? t0 : t1;
    if (blockIdx.z >= zsplit) nz -= zsplit;
    const unsigned int* Apz = Ap + (long long)z * sA;
    const unsigned int* Bpz = tt.Bp + (long long)z * tt.sB;
    const int m0 = blockIdx.y << 6, n0 = nz << 6;
    const int tid = threadIdx.x, lane = tid & 63, wv = tid >> 6;
    const int l15 = lane & 15, quad = lane >> 4;
    const int wm = (wv & 1) << 5, wn = (wv >> 1) << 5;
    const int fw = tt.dual ? ((m0 < n0) ? 2 : ((m0 == n0) ? 1 : 0)) : 0;
    f32x4 acc[2][2] = {};
    f32x4 accA[2][2] = {};
    unsigned int ra[8], rb[8], rh[8];
    loadT8(Apz, Mm, 0, m0, tid, ra);
    loadT8(Bpz, tt.Nn, 0, n0, tid, rb);
    if (fw) loadT8(Apz, Mm, 0, n0, tid, rh);
    for (int k0 = 0; k0 < Kd; k0 += 32) {
        storeT8(As, tid, ra);
        storeT8(Bs, tid, rb);
        if (fw) storeT8_hi(A2s, tid, rh);
        __syncthreads();
        const int kn = k0 + 32;
        if (kn < Kd) {
            loadT8(Apz, Mm, kn, m0, tid, ra);
            loadT8(Bpz, tt.Nn, kn, n0, tid, rb);
            if (fw) loadT8(Apz, Mm, kn, n0, tid, rh);
        }
        mfma_split(As, Bs, wm, wn, l15, quad, acc);
        if (fw) mfma_hi(As, A2s, wm, wn, l15, quad, accA);
        __syncthreads();
    }
    float* Cp = tt.C ? tt.C + (long long)z * tt.sC : nullptr;
    unsigned int* Ckp = tt.Cpk ? tt.Cpk + (long long)z * tt.sC : nullptr;
    #pragma unroll
    for (int mi = 0; mi < 2; ++mi)
    #pragma unroll
    for (int ni = 0; ni < 2; ++ni) {
        const int col = n0 + wn + (ni << 4) + l15;
        #pragma unroll
        for (int r = 0; r < 4; ++r) {
            const int row = m0 + wm + (mi << 4) + (quad << 2) + r;
            const float v = acc[mi][ni][r];
            if (Cp)  Cp[(long long)row * tt.Nn + col] = v;
            if (Ckp) Ckp[(long long)row * tt.Nn + col] = f2pk(v);
        }
    }
    if (tt.rsum) {
        // per-row partial sums of this wave's 32-column slice; 16-lane (l15) reduce
        #pragma unroll
        for (int mi = 0; mi < 2; ++mi) {
            #pragma unroll
            for (int r = 0; r < 4; ++r) {
                float rs = acc[mi][0][r] + acc[mi][1][r];
                rs += __shfl_xor(rs, 1);
                rs += __shfl_xor(rs, 2);
                rs += __shfl_xor(rs, 4);
                rs += __shfl_xor(rs, 8);
                if (l15 == 0) {
                    const int row = m0 + wm + (mi << 4) + (quad << 2) + r;
                    atomicAdd(&tt.rsum[z * tt.Nn + row], rs);
                }
            }
        }
        // diagonal (only blocks on the diagonal hold it); unique thread per element
        if (tt.rdiag && m0 == n0) {
            #pragma unroll
            for (int mi = 0; mi < 2; ++mi)
            #pragma unroll
            for (int ni = 0; ni < 2; ++ni)
            #pragma unroll
            for (int r = 0; r < 4; ++r) {
                const int rr = wm + (mi << 4) + (quad << 2) + r;
                const int cc = wn + (ni << 4) + l15;
                if (rr == cc) tt.rdiag[z * tt.Nn + m0 + rr] = acc[mi][ni][r];
            }
        }
    }
    if (fw) {
        float s = 0.f;
        #pragma unroll
        for (int mi = 0; mi < 2; ++mi)
        #pragma unroll
        for (int ni = 0; ni < 2; ++ni)
        #pragma unroll
        for (int r = 0; r < 4; ++r) s += accA[mi][ni][r] * accA[mi][ni][r];
        s *= (float)fw;
        for (int off = 32; off; off >>= 1) s += __shfl_xor(s, off);
        if (lane == 0) redf[wv] = s;
        __syncthreads();
        if (tid == 0) atomicAdd(&tt.fro[z], redf[0] + redf[1] + redf[2] + redf[3]);
    }
}

// ---------------- G3: batched C = A @ B; A direct, B reg-prefetched; rscale epilogue ------
__global__ __launch_bounds__(256) void gemm_nt(
    const unsigned short* __restrict__ Ah, const unsigned short* __restrict__ Al,
    const unsigned int* __restrict__ Bp,
    float* __restrict__ C, unsigned int* __restrict__ Cpk,
    const float* __restrict__ rscale, int rsn,
    int Kd, int Nn, long long sA, long long sB, long long sC)
{
    __shared__ short As[2 * TSZ], Bs[2 * TSZ];
    const int z = blockIdx.x;
    const int m0 = blockIdx.y << 6, n0 = blockIdx.z << 6;
    const unsigned short* Aph = Ah + (long long)z * sA;
    const unsigned short* Apl = Al + (long long)z * sA;
    const unsigned int* Bpz = Bp + (long long)z * sB;
    const int tid = threadIdx.x, lane = tid & 63, wv = tid >> 6;
    const int l15 = lane & 15, quad = lane >> 4;
    const int wm = (wv & 1) << 5, wn = (wv >> 1) << 5;
    f32x4 acc[2][2] = {};
    unsigned int rb[8];
    loadT8(Bpz, Nn, 0, n0, tid, rb);
    for (int k0 = 0; k0 < Kd; k0 += 32) {
        stageW_split(Aph, Apl, Kd, m0, k0, As, tid);   // row-major pre-split A: pure 16B copies
        storeT8(Bs, tid, rb);
        __syncthreads();
        const int kn = k0 + 32;
        if (kn < Kd) loadT8(Bpz, Nn, kn, n0, tid, rb);
        mfma_split(As, Bs, wm, wn, l15, quad, acc);
        __syncthreads();
    }
    #pragma unroll
    for (int mi = 0; mi < 2; ++mi)
    #pragma unroll
    for (int ni = 0; ni < 2; ++ni) {
        const int col = n0 + wn + (ni << 4) + l15;
        #pragma unroll
        for (int r = 0; r < 4; ++r) {
            const int row = m0 + wm + (mi << 4) + (quad << 2) + r;
            float v = acc[mi][ni][r];
            if (rscale) v *= rscale[z * rsn + row];
            if (C)   C[(long long)z * sC + (long long)row * Nn + col] = v;
            if (Cpk) Cpk[(long long)z * sC + (long long)row * Nn + col] = f2pk(v);
        }
    }
}

// ---------------- softmax rows: per-wave row, per-row partials (NO contended atomics) -----
__global__ __launch_bounds__(256) void softmax_rows_wave(
    const float* __restrict__ sm, int L,
    const float* __restrict__ deg,
    float* __restrict__ rowq2, float* __restrict__ rowdq2, int totRows,
    unsigned int* __restrict__ opk)
{
    const int wid = (blockIdx.x * 256 + threadIdx.x) >> 6;
    const int lane = threadIdx.x & 63;
    if (wid >= totRows) return;
    const float* rowp = sm + (long long)wid * L;
    const int nv = L >> 6;
    float v[4];
    if (nv == 4) {
        float4 t = *(const float4*)&rowp[lane << 2];
        v[0] = t.x; v[1] = t.y; v[2] = t.z; v[3] = t.w;
    } else {
        float2 t = *(const float2*)&rowp[lane << 1];
        v[0] = t.x; v[1] = t.y;
    }
    float mx = v[0];
    for (int i = 1; i < nv; ++i) mx = fmaxf(mx, v[i]);
    for (int off = 32; off; off >>= 1) mx = fmaxf(mx, __shfl_xor(mx, off));
    float s = 0.f;
    for (int i = 0; i < nv; ++i) { v[i] = expf(v[i] - mx); s += v[i]; }
    for (int off = 32; off; off >>= 1) s += __shfl_xor(s, off);
    const float inv = 1.f / s;
    float q2 = 0.f;
    for (int i = 0; i < nv; ++i) { float p = v[i] * inv; v[i] = p; q2 += p * p; }
    const long long rb = (long long)wid * L;
    if (nv == 4) {
        uint4 pk;
        pk.x = f2pk(v[0]); pk.y = f2pk(v[1]); pk.z = f2pk(v[2]); pk.w = f2pk(v[3]);
        *(uint4*)&opk[rb + (lane << 2)] = pk;
    } else {
        uint2 pk;
        pk.x = f2pk(v[0]); pk.y = f2pk(v[1]);
        *(uint2*)&opk[rb + (lane << 1)] = pk;
    }
    for (int off = 32; off; off >>= 1) q2 += __shfl_xor(q2, off);
    if (lane == 0) { rowq2[wid] = q2; rowdq2[wid] = deg[wid] * q2; }
}

__global__ __launch_bounds__(256) void reduce2_pergraph(
    const float* __restrict__ a, const float* __restrict__ b, int rowsPerGraph,
    float* __restrict__ outA, float* __restrict__ outB)
{
    __shared__ float redA[4], redB[4];
    const int g = blockIdx.x, t = threadIdx.x;
    float sa = 0.f, sb = 0.f;
    for (int i = t; i < rowsPerGraph; i += 256) {
        sa += a[g * rowsPerGraph + i];
        if (b) sb += b[g * rowsPerGraph + i];
    }
    for (int off = 32; off; off >>= 1) { sa += __shfl_xor(sa, off); sb += __shfl_xor(sb, off); }
    const int wv = t >> 6;
    if ((t & 63) == 0) { redA[wv] = sa; redB[wv] = sb; }
    __syncthreads();
    if (t == 0) {
        outA[g] = redA[0] + redA[1] + redA[2] + redA[3];
        if (outB) outB[g] = redB[0] + redB[1] + redB[2] + redB[3];
    }
}

// ---------------- SINGLE-PASS adjnorm: dpool from precomputed rsum/rdiag ------------------
__global__ __launch_bounds__(1024) void adjnorm(
    const float* __restrict__ adj, int K,
    const float* __restrict__ rsumIn, const float* __restrict__ rdiagIn,
    float* __restrict__ trace_out,
    float* __restrict__ rowsum, float* __restrict__ rscale,
    unsigned short* __restrict__ oh, unsigned short* __restrict__ ol)
{
    __shared__ float dpoolL[256];
    __shared__ float redt[16];
    const int g = blockIdx.x, tid = threadIdx.x;
    const int wv = tid >> 6, lane = tid & 63;
    float trp = 0.f;
    for (int r = tid; r < K; r += 1024) {
        float dv = rdiagIn[g * K + r];
        dpoolL[r] = sqrtf(rsumIn[g * K + r] - dv) + 1e-15f;
        trp += dv;
    }
    for (int off = 32; off; off >>= 1) trp += __shfl_xor(trp, off);
    if (lane == 0) redt[wv] = trp;
    __syncthreads();
    if (tid == 0) {
        float t = 0.f;
        #pragma unroll
        for (int i = 0; i < 16; ++i) t += redt[i];
        trace_out[g] = t;
    }
    const int rowsPerWave = K >> 4;   // 16 waves
    const int nv = K >> 6;
    for (int rr = 0; rr < rowsPerWave; ++rr) {
        const int r = wv * rowsPerWave + rr;
        const int wid = g * K + r;
        const float* rowp = adj + (long long)wid * K;
        const float inv_r = 1.f / dpoolL[r];
        float s = 0.f;
        for (int q = 0; q < nv; ++q) {
            int c = lane + (q << 6);
            float a = rowp[c];
            if (c == r) a = 0.f;
            float v = a * inv_r / dpoolL[c];
            s += v;
            unsigned short h = f2bf(v);
            oh[(long long)wid * K + c] = h;
            ol[(long long)wid * K + c] = f2bf(v - bf2f(h));
        }
        for (int off = 32; off; off >>= 1) s += __shfl_xor(s, off);
        if (lane == 0) { rowsum[wid] = s; rscale[wid] = 1.f / fmaxf(s, 1.f); }
    }
}

// ---------------- fused topk v3: vectorized edge phase + LDS edge cache -------------------
__global__ __launch_bounds__(512) void topk_fused(
    const float* __restrict__ x, const float* __restrict__ p, int n, int k,
    float* __restrict__ outx, float* __restrict__ sxsum,
    const int* __restrict__ sIn, const int* __restrict__ dIn, const float* __restrict__ mIn,
    int* __restrict__ sOut, int* __restrict__ dOut, float* __restrict__ mOut,
    int* __restrict__ elist, int* __restrict__ offs, int* __restrict__ cnts)
{
    __shared__ float sc[512];
    __shared__ int pref[512];
    __shared__ int   selL[256];
    __shared__ float gateL[256];
    __shared__ float red[1024];
    __shared__ int   nidL[512];
    __shared__ int   cntL[256];
    __shared__ int   curL[256];
    __shared__ unsigned int eL[EPG];   // (ndLocal<<9)|nsLocal, 0xFFFFFFFF = invalid
    const int g = blockIdx.x, tid = threadIdx.x;
    float myScore = 0.f;
    if (tid < n) {
        const float* xr = x + (long long)(g * n + tid) * 128;
        float pn2 = 0.f, d = 0.f;
        #pragma unroll 4
        for (int f = 0; f < 128; f += 4) {
            float4 pv = *(const float4*)&p[f];
            float4 v = *(const float4*)&xr[f];
            pn2 += pv.x * pv.x + pv.y * pv.y + pv.z * pv.z + pv.w * pv.w;
            d += v.x * pv.x + v.y * pv.y + v.z * pv.z + v.w * pv.w;
        }
        myScore = d / (sqrtf(pn2) + 1e-16f);
        sc[tid] = myScore;
    }
    __syncthreads();
    int keep = 0;
    if (tid < n) {
        const float si = myScore;
        int rank = 0;
        for (int j = 0; j < n; j += 4) {
            float4 s4 = *(const float4*)&sc[j];
            rank += (s4.x > si) || (s4.x == si && (j + 0) < tid);
            rank += (s4.y > si) || (s4.y == si && (j + 1) < tid);
            rank += (s4.z > si) || (s4.z == si && (j + 2) < tid);
            rank += (s4.w > si) || (s4.w == si && (j + 3) < tid);
        }
        keep = rank < k;
    }
    pref[tid] = keep;
    __syncthreads();
    for (int d = 1; d < 512; d <<= 1) {
        int u = (tid >= d) ? pref[tid - d] : 0;
        __syncthreads();
        pref[tid] += u;
        __syncthreads();
    }
    {
        int nid = -1;
        if (tid < n && keep) {
            int pos = pref[tid] - 1;
            nid = g * k + pos;
            selL[pos] = g * n + tid;
            gateL[pos] = tanhf(myScore);
        }
        nidL[tid] = nid;
    }
    __syncthreads();
    // gather + gate + per-graph readout (max / mean)
    const int f = tid & 127, grp = tid >> 7;     // 4 row-groups x 128 features
    float mx = -INFINITY, sm = 0.f;
    for (int r = grp; r < k; r += 4) {
        float v = x[(long long)selL[r] * 128 + f] * gateL[r];
        outx[(long long)(g * k + r) * 128 + f] = v;
        mx = fmaxf(mx, v); sm += v;
    }
    red[grp * 128 + f] = mx;
    red[512 + grp * 128 + f] = sm;
    __syncthreads();
    if (tid < 128) {
        float m = fmaxf(fmaxf(red[f], red[128 + f]), fmaxf(red[256 + f], red[384 + f]));
        float s2 = red[512 + f] + red[640 + f] + red[768 + f] + red[896 + f];
        sxsum[g * 256 + f] += m;
        sxsum[g * 256 + 128 + f] += s2 / k;
    }
    // ---- block-local edge remap + count + scan + CSR fill (vectorized, LDS-cached) ----
    if (sIn) {
        if (tid < k) cntL[tid] = 0;
        __syncthreads();
        const int e0 = g * EPG;
        const int gn = g * n, gk = g * k;
        #pragma unroll
        for (int i = 0; i < 4; ++i) {
            const int eidx = ((i << 9) + tid) << 2;      // 4 consecutive edges
            int4 s4 = *(const int4*)&sIn[e0 + eidx];
            int4 d4 = *(const int4*)&dIn[e0 + eidx];
            float4 m4 = mIn ? *(const float4*)&mIn[e0 + eidx] : make_float4(1.f,1.f,1.f,1.f);
            int ss[4] = {s4.x, s4.y, s4.z, s4.w};
            int dd[4] = {d4.x, d4.y, d4.z, d4.w};
            float mm[4] = {m4.x, m4.y, m4.z, m4.w};
            int so_[4], do_[4]; float mo_[4];
            #pragma unroll
            for (int j = 0; j < 4; ++j) {
                int ns = -1, nd = -1;
                if (mm[j] > 0.f) {
                    ns = nidL[ss[j] - gn];
                    nd = nidL[dd[j] - gn];
                }
                const bool v = (ns >= 0) && (nd >= 0);
                so_[j] = v ? ns : 0; do_[j] = v ? nd : 0; mo_[j] = v ? 1.f : 0.f;
                eL[eidx + j] = v ? (((unsigned)(nd - gk) << 9) | (unsigned)(ns - gk))
                                 : 0xFFFFFFFFu;
                if (v) atomicAdd(&cntL[nd - gk], 1);
            }
            if (sOut) {
                *(int4*)&sOut[e0 + eidx] = make_int4(so_[0], so_[1], so_[2], so_[3]);
                *(int4*)&dOut[e0 + eidx] = make_int4(do_[0], do_[1], do_[2], do_[3]);
                *(float4*)&mOut[e0 + eidx] = make_float4(mo_[0], mo_[1], mo_[2], mo_[3]);
            }
        }
        __syncthreads();
        int c = (tid < k) ? cntL[tid] : 0;
        pref[tid] = c;
        __syncthreads();
        for (int d = 1; d < 512; d <<= 1) {
            int u = (tid >= d) ? pref[tid - d] : 0;
            __syncthreads();
            pref[tid] += u;
            __syncthreads();
        }
        if (tid < k) {
            int o = pref[tid] - c;     // exclusive prefix (local)
            offs[gk + tid] = e0 + o;
            cnts[gk + tid] = c;
            curL[tid] = o;
        }
        __syncthreads();
        #pragma unroll
        for (int i = 0; i < 4; ++i) {
            const int eidx = ((i << 9) + tid) << 2;
            #pragma unroll
            for (int j = 0; j < 4; ++j) {
                const unsigned int pk_ = eL[eidx + j];
                if (pk_ != 0xFFFFFFFFu) {
                    const int nd = pk_ >> 9, ns = pk_ & 511;
                    const int p_ = atomicAdd(&curL[nd], 1);
                    elist[e0 + p_] = gk + ns;
                }
            }
        }
    }
}

// final head: mean_lin fused + mc/o scalar epilogue in block 0
__global__ void final_head(const float* __restrict__ sxsum, const float* __restrict__ w11,
                           const float* __restrict__ b11,
                           const float* __restrict__ xd2, const float* __restrict__ l1w,
                           const float* __restrict__ l1b,
                           const float* __restrict__ w2, const float* __restrict__ b2,
                           const float* __restrict__ accs, float* __restrict__ out) {
    __shared__ float meanv[128];
    __shared__ float sin_[256];
    __shared__ float cat[256];
    __shared__ float rm[2], ro[2];
    int b = blockIdx.x, t = threadIdx.x; // 128
    {
        float s = 0.f;
        for (int n = 0; n < 128; n++) s += xd2[(long long)(b * 128 + n) * 128 + t];
        meanv[t] = s / 128.f;
    }
    if (b == 0) {
        int wvi = t >> 6, lane = t & 63;
        const float* acc = accs + wvi * 256;
        float sqrtk = wvi ? sqrtf(128.f) : 16.f;
        float numv = acc[lane], denv = acc[64 + lane], trv = acc[128 + lane], frov = acc[192 + lane];
        float mcb = numv / (denv + 1e-15f);
        float ssn = sqrtf(frov) + 1e-15f;
        float ob = sqrtf(fmaxf(frov / (ssn * ssn) - 2.f * trv / (ssn * sqrtk) + 1.f, 0.f));
        for (int off = 32; off; off >>= 1) { mcb += __shfl_down(mcb, off); ob += __shfl_down(ob, off); }
        if (lane == 0) { rm[wvi] = mcb; ro[wvi] = ob; }
        __syncthreads();
        if (t == 0) {
            out[640] = -(rm[0] + rm[1]) / 64.f;
            out[641] = (ro[0] + ro[1]) / 64.f;
        }
    }
    sin_[t] = sxsum[b * 256 + t];
    sin_[t + 128] = sxsum[b * 256 + 128 + t];
    __syncthreads();
    float acc = b11[t];
    for (int i = 0; i < 256; i++) acc += sin_[i] * w11[i * 128 + t];
    cat[t] = fmaxf(acc, 0.f);
    float xga = l1b[t];
    for (int i = 0; i < 128; i++) xga += meanv[i] * l1w[i * 128 + t];
    cat[128 + t] = fmaxf(xga, 0.f);
    __syncthreads();
    if (t < 10) {
        float a = b2[t];
        for (int i = 0; i < 256; i++) a += cat[i] * w2[i * 10 + t];
        out[b * 10 + t] = a;
    }
}

// ------------------------------------------------------------------------------------------
extern "C" void kernel_launch(void* const* d_in, const int* in_sizes, int n_in,
                              void* d_out, int out_size, void* d_ws, size_t ws_size,
                              hipStream_t stream) {
    const float* x         = (const float*)d_in[0];
    const int*   src       = (const int*)d_in[1];
    const int*   dst       = (const int*)d_in[2];
    const float* conv0_wr  = (const float*)d_in[3];
    const float* conv0_wrt = (const float*)d_in[4];
    const float* conv0_b   = (const float*)d_in[5];
    const float* sc2_wr    = (const float*)d_in[6];
    const float* sc2_wrt   = (const float*)d_in[7];
    const float* sc2_b     = (const float*)d_in[8];
    const float* sc3_wr    = (const float*)d_in[9];
    const float* sc3_wrt   = (const float*)d_in[10];
    const float* sc3_b     = (const float*)d_in[11];
    const float* sg1_wr    = (const float*)d_in[12];
    const float* sg1_wrt   = (const float*)d_in[13];
    const float* sg1_b     = (const float*)d_in[14];
    const float* sg2_wr    = (const float*)d_in[15];
    const float* sg2_wrt   = (const float*)d_in[16];
    const float* sg2_b     = (const float*)d_in[17];
    const float* pool0_w   = (const float*)d_in[18];
    const float* pool0_b   = (const float*)d_in[19];
    const float* pool1_w   = (const float*)d_in[20];
    const float* pool1_b   = (const float*)d_in[21];
    const float* p1        = (const float*)d_in[22];
    const float* p2        = (const float*)d_in[23];
    const float* p3        = (const float*)d_in[24];
    const float* l11_w     = (const float*)d_in[25];
    const float* l11_b     = (const float*)d_in[26];
    const float* l1_w      = (const float*)d_in[27];
    const float* l1_b      = (const float*)d_in[28];
    const float* l2_w      = (const float*)d_in[29];
    const float* l2_b      = (const float*)d_in[30];
    float* out = (float*)d_out;

    char* w = (char*)d_ws;
    const unsigned long long MBy = 1ull << 20;
    float* x0    = (float*)(w + 0);           // 16 MB
    float* BIG1  = (float*)(w + 16 * MBy);    // 32 MB
    float* BIG2  = (float*)(w + 48 * MBy);    // 32 MB
    float* agg   = (float*)(w + 80 * MBy);    // 16 MB
    float* adj1  = (float*)(w + 104 * MBy);   // 16 MB
    int*   s1    = (int*)(w + 120 * MBy);
    int*   d1    = (int*)(w + 122 * MBy);
    float* m1    = (float*)(w + 124 * MBy);
    char*  misc  = w + 132 * MBy;
    float* rowq2  = (float*)(misc);                 // 128 KB (32768 f32)
    float* rowdq2 = (float*)(misc + 128 * 1024);    // 128 KB
    float* deg   = (float*)(misc + 384 * 1024);
    float* rowsum2 = (float*)(misc + 576 * 1024);
    float* rscale2 = (float*)(misc + 640 * 1024);
    float* rowsum3 = (float*)(misc + 736 * 1024);
    float* rscale3 = (float*)(misc + 768 * 1024);
    float* accs    = (float*)(misc + 800 * 1024);
    float* sxsum   = (float*)(misc + 900 * 1024);

    unsigned short* wt_sg1h   = (unsigned short*)(misc + 1024 * 1024);
    unsigned short* wt_sg1l   = wt_sg1h + 32768;
    unsigned short* wt_sg2h   = wt_sg1l + 32768;
    unsigned short* wt_sg2l   = wt_sg2h + 32768;
    unsigned short* wt_pool0h = wt_sg2l + 32768;
    unsigned short* wt_pool0l = wt_pool0h + 32768;
    unsigned short* wt_pool1h = wt_pool0l + 32768;
    unsigned short* wt_pool1l = wt_pool1h + 32768;
    unsigned short* wt_c0h    = wt_pool1l + 32768;
    unsigned short* wt_c0l    = wt_c0h + 32768;
    unsigned short* wt_sc2h   = wt_c0l + 32768;
    unsigned short* wt_sc2l   = wt_sc2h + 32768;
    unsigned short* wt_sc3h   = wt_sc2l + 32768;
    unsigned short* wt_sc3l   = wt_sc3h + 32768;

    // adj row stats (zeroed each iteration)
    float* rsum1  = (float*)(misc + 2048 * 1024);   // 64 KB (64*256)
    float* rdiag1 = (float*)(misc + 2112 * 1024);   // 64 KB
    float* rsum2  = (float*)(misc + 2176 * 1024);   // 32 KB (64*128)
    float* rdiag2 = (float*)(misc + 2208 * 1024);   // 32 KB

    float* s_sm  = BIG1;                      // f32 softmax input (pre-softmax scores)
    unsigned int* Tbp = (unsigned int*)BIG2;  // phase A; dead after adj1 GEMM
    float* s2sm  = BIG2 + 4 * 1024 * 1024;                       // +16..24 MiB
    unsigned int* T2p = (unsigned int*)((char*)BIG2 + 24 * MBy); // +24..32 MiB
    float* adj2b = BIG1 + 1024 * 1024;
    float* xd2   = BIG1 + 2 * 1024 * 1024;
    float* sxA   = BIG1 + 3 * 1024 * 1024;
    float* sxE   = BIG1 + 5 * 1024 * 1024;
    float* sxB   = x0;
    float* sxC   = x0 + 2 * 1024 * 1024;
    float* sxD   = x0 + 3 * 1024 * 1024;

    // packed split-bf16 planes (region 136..244 MiB of the workspace)
    unsigned int* s_smp = (unsigned int*)(w + 136 * MBy);  // 32 MiB
    unsigned int* x0p   = (unsigned int*)(w + 168 * MBy);  // 16 MiB
    unsigned int* ox1p  = (unsigned int*)(w + 184 * MBy);  // 8 MiB
    unsigned int* xd1p  = (unsigned int*)(w + 192 * MBy);  // 8 MiB
    unsigned int* s2p   = (unsigned int*)(w + 200 * MBy);  // 8 MiB
    unsigned int* ox2p  = (unsigned int*)(w + 208 * MBy);  // 4 MiB
    unsigned short* a1h = (unsigned short*)(w + 212 * MBy); // 8 MiB
    unsigned short* a1l = (unsigned short*)(w + 220 * MBy); // 8 MiB
    unsigned short* a2h = (unsigned short*)(w + 228 * MBy); // 2 MiB
    unsigned short* a2l = (unsigned short*)(w + 230 * MBy); // 2 MiB
    unsigned int* AXp   = (unsigned int*)(w + 232 * MBy);  // 8 MiB
    unsigned int* AXp2  = (unsigned int*)(w + 240 * MBy);  // 4 MiB

    unsigned int* aggp  = (unsigned int*)agg;
    unsigned int* agg2p = (unsigned int*)agg;
    unsigned int* agg3p = (unsigned int*)agg;

    char* adjc = (char*)adj1;
    int* elA  = (int*)(adjc + 0);
    int* elB  = (int*)(adjc + 2 * MBy);
    int* cntA = (int*)(adjc + 4 * MBy);                  // 128 KB
    int* cntB = (int*)(adjc + 4 * MBy + 128 * 1024);     // contiguous -> one memset
    int* offA = (int*)(adjc + 4 * MBy + 256 * 1024);
    int* curA = (int*)(adjc + 4 * MBy + 384 * 1024);
    int* offB = (int*)(adjc + 4 * MBy + 512 * 1024);
    int* curB = (int*)(adjc + 4 * MBy + 640 * 1024);
    char* aggc = (char*)agg;
    int* elC  = (int*)(aggc + 8 * MBy);
    int* elD  = (int*)(aggc + 10 * MBy);
    int* cntC = (int*)(aggc + 12 * MBy);
    int* offC = (int*)(aggc + 12 * MBy + 256 * 1024);
    int* cntD = (int*)(aggc + 13 * MBy);
    int* offD = (int*)(aggc + 13 * MBy + 256 * 1024);

    hipMemsetAsync(accs, 0, 520 * sizeof(float), stream);
    hipMemsetAsync(sxsum, 0, 16384 * sizeof(float), stream);
    hipMemsetAsync(cntA, 0, 65536 * sizeof(int), stream);   // cntA + cntB
    hipMemsetAsync(rsum1, 0, 128 * 1024, stream);           // rsum1 + rdiag1
    hipMemsetAsync(rsum2, 0, 64 * 1024, stream);            // rsum2 + rdiag2

    {
        WSpec a{sg1_wr, sg1_wrt, 128, 128, 128, wt_sg1h, wt_sg1l};
        WSpec b{sg2_wr, sg2_wrt, 128, 128, 128, wt_sg2h, wt_sg2l};
        WSpec c{pool0_w, nullptr, 128, 0, 256, wt_pool0h, wt_pool0l};
        WSpec d{pool1_w, nullptr, 128, 0, 128, wt_pool1h, wt_pool1l};
        WSpec e{conv0_wr, conv0_wrt, 128, 128, 128, wt_c0h, wt_c0l};
        WSpec f{sc2_wr, sc2_wrt, 128, 128, 128, wt_sc2h, wt_sc2l};
        WSpec g{sc3_wr, sc3_wrt, 128, 128, 128, wt_sc3h, wt_sc3l};
        wconv_all<<<dim3(128, 7), 256, 0, stream>>>(a, b, c, d, e, f, g);
    }

    edge_count2<<<dim3(2048, 2), 256, 0, stream>>>(dst, cntA, src, cntB);
    scan_offsets2<<<dim3(64, 2), 512, 0, stream>>>(cntA, offA, curA, cntB, offB, curB, 512, deg);
    edge_fill2<<<dim3(2048, 2), 256, 0, stream>>>(dst, src, curA, elA, src, dst, curB, elB);

    // ---- conv0: gather (f32 in -> packed out), gemm emits x0 f32 (topk) + x0p packed ----
    gather_csr<<<4096, 256, 0, stream>>>(x, nullptr, 128, offA, cntA, elA, aggp, 32768, 512);
    gemm_aw<<<dim3(2, 512), 256, 0, stream>>>(aggp, nullptr, 128, nullptr, x, 128,
        wt_c0h, wt_c0l, conv0_b, x0, x0p, 128, 1);

    // ---- dense branch, pool 1 ----
    gemm_aw<<<dim3(4, 512), 256, 0, stream>>>(x0p, nullptr, 128, nullptr, nullptr, 0,
        wt_pool0h, wt_pool0l, pool0_b, s_sm, nullptr, 256, 0);
    softmax_rows_wave<<<8192, 256, 0, stream>>>(s_sm, 256, deg, rowq2, rowdq2, 32768, s_smp);
    reduce2_pergraph<<<64, 256, 0, stream>>>(rowq2, rowdq2, 512, accs + 128, accs + 64);
    gather_csr<<<8192, 256, 0, stream>>>(nullptr, s_smp, 256, offB, cntB, elB, Tbp, 32768, 512);
    {   // outx1 (z 0..1) + adj1 (z 2..5) in ONE launch; adj job emits row stats
        TTSet t0{x0p, nullptr, ox1p, nullptr, 128, 0, 512 * 128, 256 * 128, nullptr, nullptr};
        TTSet t1{Tbp, adj1, nullptr, accs + 192, 256, 1, 512 * 256, 256 * 256, rsum1, rdiag1};
        gemm_tt<<<dim3(64, 4, 6), 256, 0, stream>>>(s_smp, 512, 256, 512 * 256, 2, t0, t1);
    }
    adjnorm<<<64, 1024, 0, stream>>>(adj1, 256, rsum1, rdiag1, accs + 0,
        rowsum2, rscale2, a1h, a1l);
    // sage1 (rscale fused into gemm_nt epilogue -> AXp packed)
    gemm_nt<<<dim3(64, 4, 2), 256, 0, stream>>>(a1h, a1l, ox1p, nullptr, AXp, rscale2, 256,
        256, 128, 256 * 256, 256 * 128, 256 * 128);
    gemm_aw<<<dim3(2, 256), 256, 0, stream>>>(AXp, nullptr, 128, ox1p, nullptr, 128,
        wt_sg1h, wt_sg1l, sg1_b, nullptr, xd1p, 128, 1);
    // pool 2
    gemm_aw<<<dim3(2, 256), 256, 0, stream>>>(xd1p, nullptr, 128, nullptr, nullptr, 0,
        wt_pool1h, wt_pool1l, pool1_b, s2sm, nullptr, 128, 0);
    softmax_rows_wave<<<4096, 256, 0, stream>>>(s2sm, 128, rowsum2, rowq2, rowdq2, 16384, s2p);
    reduce2_pergraph<<<64, 256, 0, stream>>>(rowq2, rowdq2, 256, accs + 384, accs + 320);
    gemm_nt<<<dim3(64, 4, 2), 256, 0, stream>>>(a1h, a1l, s2p, nullptr, T2p, nullptr, 0,
        256, 128, 256 * 256, 256 * 128, 256 * 128);
    {   // outx2 (z 0..1) + adj2 (z 2..3) in ONE launch; adj job emits row stats
        TTSet t0{xd1p, nullptr, ox2p, nullptr, 128, 0, 256 * 128, 128 * 128, nullptr, nullptr};
        TTSet t1{T2p, adj2b, nullptr, accs + 448, 128, 1, 256 * 128, 128 * 128, rsum2, rdiag2};
        gemm_tt<<<dim3(64, 2, 4), 256, 0, stream>>>(s2p, 256, 128, 256 * 128, 2, t0, t1);
    }
    adjnorm<<<64, 1024, 0, stream>>>(adj2b, 128, rsum2, rdiag2, accs + 256,
        rowsum3, rscale3, a2h, a2l);
    // sage2 + head
    gemm_nt<<<dim3(64, 2, 2), 256, 0, stream>>>(a2h, a2l, ox2p, nullptr, AXp2, rscale3, 128,
        128, 128, 128 * 128, 128 * 128, 128 * 128);
    gemm_aw<<<dim3(2, 128), 256, 0, stream>>>(AXp2, nullptr, 128, ox2p, nullptr, 128,
        wt_sg2h, wt_sg2l, sg2_b, xd2, nullptr, 128, 0);

    // ---- sparse branch: topk_fused builds the next-level CSR block-locally ----
    topk_fused<<<64, 512, 0, stream>>>(x0, p1, 512, 256, sxA, sxsum,
        src, dst, nullptr, s1, d1, m1, elC, offC, cntC);
    gather_csr<<<2048, 256, 0, stream>>>(sxA, nullptr, 128, offC, cntC, elC, agg2p, 16384, 256);
    gemm_aw<<<dim3(2, 256), 256, 0, stream>>>(agg2p, nullptr, 128, nullptr, sxA, 128,
        wt_sc2h, wt_sc2l, sc2_b, sxB, nullptr, 128, 1);
    topk_fused<<<64, 512, 0, stream>>>(sxB, p2, 256, 128, sxC, sxsum,
        s1, d1, m1, nullptr, nullptr, nullptr, elD, offD, cntD);
    gather_csr<<<1024, 256, 0, stream>>>(sxC, nullptr, 128, offD, cntD, elD, agg3p, 8192, 128);
    gemm_aw<<<dim3(2, 128), 256, 0, stream>>>(agg3p, nullptr, 128, nullptr, sxC, 128,
        wt_sc3h, wt_sc3l, sc3_b, sxD, nullptr, 128, 1);
    topk_fused<<<64, 512, 0, stream>>>(sxD, p3, 128, 64, sxE, sxsum,
        nullptr, nullptr, nullptr, nullptr, nullptr, nullptr, nullptr, nullptr, nullptr);

    final_head<<<64, 128, 0, stream>>>(sxsum, l11_w, l11_b, xd2, l1_w, l1_b,
        l2_w, l2_b, accs, out);
}